// Round 1
// baseline (2278.392 us; speedup 1.0000x reference)
//
#include <hip/hip_runtime.h>
#include <math.h>

// ---- dims ----
static constexpr int kB = 8, kS = 512, kENC = 7, kMARK = 4;
static constexpr int kD = 512, kI = 1024, kNH = 8, kDH = 128;
static constexpr int kL = 4, kPRED = 96, kCOUT = 7;
static constexpr int kM = kB * kS; // 4096 rows

// ======================= embedding =======================
__global__ __launch_bounds__(256) void embed_kernel(
    const float* __restrict__ xe, const float* __restrict__ xme,
    const float* __restrict__ W, const float* __restrict__ bias,
    float* __restrict__ x) {
  int m = blockIdx.x;
  int tid = threadIdx.x;
  __shared__ float f[11];
  if (tid < 7) f[tid] = xe[m * 7 + tid];
  else if (tid < 11) f[tid] = xme[m * 4 + (tid - 7)];
  __syncthreads();
  for (int d = tid; d < kD; d += 256) {
    float acc = bias[d];
#pragma unroll
    for (int e = 0; e < 11; ++e) acc += f[e] * W[e * kD + d];
    x[(size_t)m * kD + d] = acc;
  }
}

// ======================= layernorm (D=512, scale only) =======================
__global__ __launch_bounds__(256) void ln_kernel(
    const float* __restrict__ x, const float* __restrict__ w, float* __restrict__ h) {
  int m = blockIdx.x, tid = threadIdx.x;
  float v0 = x[(size_t)m * kD + tid];
  float v1 = x[(size_t)m * kD + 256 + tid];
  float s1 = v0 + v1, s2 = v0 * v0 + v1 * v1;
#pragma unroll
  for (int o = 1; o < 64; o <<= 1) { s1 += __shfl_xor(s1, o, 64); s2 += __shfl_xor(s2, o, 64); }
  __shared__ float a1[4], a2[4];
  if ((tid & 63) == 0) { a1[tid >> 6] = s1; a2[tid >> 6] = s2; }
  __syncthreads();
  float t1 = a1[0] + a1[1] + a1[2] + a1[3];
  float t2 = a2[0] + a2[1] + a2[2] + a2[3];
  float mu = t1 * (1.f / kD);
  float var = t2 * (1.f / kD) - mu * mu;
  float rs = rsqrtf(var + 1e-5f);
  h[(size_t)m * kD + tid] = (v0 - mu) * rs * w[tid];
  h[(size_t)m * kD + 256 + tid] = (v1 - mu) * rs * w[256 + tid];
}

// ======================= fp32 tiled GEMM: C[M,N] = A[M,K]@B[K,N] + bias (+C) =======================
template <int RESID>
__global__ __launch_bounds__(256) void gemm_kernel(
    const float* __restrict__ A, const float* __restrict__ Bm,
    const float* __restrict__ bias, float* __restrict__ C,
    int M, int N, int Kd) {
  __shared__ float As[16][65];
  __shared__ float Bs[16][64];
  int tid = threadIdx.x;
  int bm = blockIdx.y, bn = blockIdx.x;
  int tr = tid >> 4, tc = tid & 15;
  float acc[4][4] = {};
  int aR = (tid * 4) >> 4;  // row in A tile (0..63)
  int aC = (tid * 4) & 15;  // k in A tile (0,4,8,12)
  int bK = (tid * 4) >> 6;  // k row in B tile (0..15)
  int bN = (tid * 4) & 63;  // n in B tile
  const float* Ap = A + (size_t)(bm * 64 + aR) * Kd + aC;
  const float* Bp = Bm + (size_t)bK * N + bn * 64 + bN;
  for (int kt = 0; kt < Kd; kt += 16) {
    float4 av = *(const float4*)(Ap + kt);
    float4 bv = *(const float4*)(Bp + (size_t)kt * N);
    As[aC + 0][aR] = av.x; As[aC + 1][aR] = av.y;
    As[aC + 2][aR] = av.z; As[aC + 3][aR] = av.w;
    *(float4*)&Bs[bK][bN] = bv;
    __syncthreads();
#pragma unroll
    for (int kk = 0; kk < 16; ++kk) {
      float a0 = As[kk][tr * 4 + 0], a1 = As[kk][tr * 4 + 1];
      float a2 = As[kk][tr * 4 + 2], a3 = As[kk][tr * 4 + 3];
      float4 b4 = *(const float4*)&Bs[kk][tc * 4];
      acc[0][0] += a0 * b4.x; acc[0][1] += a0 * b4.y; acc[0][2] += a0 * b4.z; acc[0][3] += a0 * b4.w;
      acc[1][0] += a1 * b4.x; acc[1][1] += a1 * b4.y; acc[1][2] += a1 * b4.z; acc[1][3] += a1 * b4.w;
      acc[2][0] += a2 * b4.x; acc[2][1] += a2 * b4.y; acc[2][2] += a2 * b4.z; acc[2][3] += a2 * b4.w;
      acc[3][0] += a3 * b4.x; acc[3][1] += a3 * b4.y; acc[3][2] += a3 * b4.z; acc[3][3] += a3 * b4.w;
    }
    __syncthreads();
  }
  float4 bb = *(const float4*)&bias[bn * 64 + tc * 4];
#pragma unroll
  for (int i = 0; i < 4; ++i) {
    int row = bm * 64 + tr * 4 + i;
    float4* cp = (float4*)&C[(size_t)row * N + bn * 64 + tc * 4];
    float4 o;
    o.x = acc[i][0] + bb.x; o.y = acc[i][1] + bb.y;
    o.z = acc[i][2] + bb.z; o.w = acc[i][3] + bb.w;
    if (RESID) { float4 r = *cp; o.x += r.x; o.y += r.y; o.z += r.z; o.w += r.w; }
    *cp = o;
  }
}

// ======================= causal depthwise conv (K=4) + silu =======================
__global__ __launch_bounds__(256) void conv_silu_kernel(
    const float* __restrict__ u, const float* __restrict__ cw,
    const float* __restrict__ cb, float* __restrict__ xc) {
  int m = blockIdx.x;
  int b = m >> 9, s = m & 511;
  int tid = threadIdx.x;
  for (int c = tid; c < kI; c += 256) {
    float acc = cb[c];
#pragma unroll
    for (int j = 0; j < 4; ++j) {
      int sp = s - 3 + j;
      if (sp >= 0) acc += u[((size_t)(b * kS + sp)) * (2 * kI) + c] * cw[c * 4 + j];
    }
    xc[(size_t)m * kI + c] = acc / (1.f + expf(-acc));
  }
}

// ======================= block-diagonal headwise q,k,v =======================
__global__ __launch_bounds__(256) void headwise_kernel(
    const float* __restrict__ u, const float* __restrict__ xc,
    const float* __restrict__ Wq, const float* __restrict__ Wk, const float* __restrict__ Wv,
    float* __restrict__ q, float* __restrict__ k, float* __restrict__ v) {
  int m = blockIdx.x;
  int tid = threadIdx.x;
  __shared__ float xcs[kI], xms[kI];
  for (int i = tid; i < kI; i += 256) {
    xcs[i] = xc[(size_t)m * kI + i];
    xms[i] = u[(size_t)m * (2 * kI) + i];
  }
  __syncthreads();
  for (int c = tid; c < kI; c += 256) {
    int n = c >> 2, o = c & 3;
    const float* wq = Wq + n * 16 + o * 4;
    const float* wk = Wk + n * 16 + o * 4;
    const float* wv = Wv + n * 16 + o * 4;
    float aq = 0, ak = 0, av = 0;
#pragma unroll
    for (int i2 = 0; i2 < 4; ++i2) {
      float xcv = xcs[n * 4 + i2], xmv = xms[n * 4 + i2];
      aq += xcv * wq[i2]; ak += xcv * wk[i2]; av += xmv * wv[i2];
    }
    q[(size_t)m * kI + c] = aq;
    k[(size_t)m * kI + c] = ak;
    v[(size_t)m * kI + c] = av;
  }
}

// ======================= input/forget gate projections =======================
__global__ __launch_bounds__(256) void gates_kernel(
    const float* __restrict__ q, const float* __restrict__ k, const float* __restrict__ v,
    const float* __restrict__ igW, const float* __restrict__ igb,
    const float* __restrict__ fgW, const float* __restrict__ fgb,
    float* __restrict__ ig, float* __restrict__ fg) {
  int m = blockIdx.x;
  int b = m >> 9, s = m & 511;
  int tid = threadIdx.x;
  float accI[8] = {}, accF[8] = {};
  const float* rows[3] = {q + (size_t)m * kI, k + (size_t)m * kI, v + (size_t)m * kI};
  for (int src = 0; src < 3; ++src) {
    const float* r = rows[src];
    const float* wI = igW + (size_t)src * kI * 8;
    const float* wF = fgW + (size_t)src * kI * 8;
    for (int kk = tid; kk < kI; kk += 256) {
      float g = r[kk];
      const float* wi = wI + kk * 8;
      const float* wf = wF + kk * 8;
#pragma unroll
      for (int n = 0; n < 8; ++n) { accI[n] += g * wi[n]; accF[n] += g * wf[n]; }
    }
  }
  __shared__ float red[256 * 17];
#pragma unroll
  for (int n = 0; n < 8; ++n) { red[tid * 17 + n] = accI[n]; red[tid * 17 + 8 + n] = accF[n]; }
  __syncthreads();
  for (int off = 128; off >= 1; off >>= 1) {
    if (tid < off) {
#pragma unroll
      for (int n = 0; n < 16; ++n) red[tid * 17 + n] += red[(tid + off) * 17 + n];
    }
    __syncthreads();
  }
  if (tid < 8) {
    ig[((size_t)b * kNH + tid) * kS + s] = red[tid] + igb[tid];
    fg[((size_t)b * kNH + tid) * kS + s] = red[8 + tid] + fgb[tid];
  }
}

// ======================= per-(b,nh) scan: inc, a, pmax =======================
__global__ __launch_bounds__(512) void scan_kernel(
    const float* __restrict__ ig, const float* __restrict__ fg,
    float* __restrict__ inc, float* __restrict__ a, float* __restrict__ pmax) {
  int bh = blockIdx.x;
  int t = threadIdx.x;
  __shared__ float buf[512];
  float x = fg[(size_t)bh * kS + t];
  float lf = fminf(x, 0.f) - log1pf(expf(-fabsf(x)));  // log_sigmoid
  buf[t] = lf;
  __syncthreads();
  for (int off = 1; off < 512; off <<= 1) {
    float p = (t >= off) ? buf[t - off] : 0.f;
    __syncthreads();
    buf[t] += p;
    __syncthreads();
  }
  float inct = buf[t];
  inc[(size_t)bh * kS + t] = inct;
  float av = ig[(size_t)bh * kS + t] - inct;
  a[(size_t)bh * kS + t] = av;
  buf[t] = av;
  __syncthreads();
  for (int off = 1; off < 512; off <<= 1) {
    float p = (t >= off) ? buf[t - off] : -1e30f;
    __syncthreads();
    buf[t] = fmaxf(buf[t], p);
    __syncthreads();
  }
  pmax[(size_t)bh * kS + t] = buf[t];
}

// ======================= mLSTM parallel (tiled, 16 rows per block) =======================
__global__ __launch_bounds__(256) void mlstm_kernel(
    const float* __restrict__ q, const float* __restrict__ k, const float* __restrict__ v,
    const float* __restrict__ inc, const float* __restrict__ a, const float* __restrict__ pmax,
    float* __restrict__ out) {
  int rt = blockIdx.x;   // row tile 0..31
  int bh = blockIdx.y;   // 0..63
  int b = bh >> 3, nh = bh & 7;
  int tid = threadIdx.x;
  int r = tid >> 4, c = tid & 15;
  __shared__ float Qs[16][132];
  __shared__ float Ks[16][132];
  __shared__ float Vs[16][136];
  __shared__ float Sc[16][17];
  __shared__ float Avs[16];
  __shared__ float Rs[16][17];
  __shared__ float Ninv[16];
  const size_t head_off = (size_t)nh * kDH;
  for (int idx = tid; idx < 16 * 128; idx += 256) {
    int rr = idx >> 7, d = idx & 127;
    Qs[rr][d] = q[((size_t)(b * kS) + rt * 16 + rr) * kI + head_off + d];
  }
  int rg = rt * 16 + r;
  float my_pmax = pmax[(size_t)bh * kS + rg];
  float rs_part = 0.f;
  float acc0[4] = {}, acc1[4] = {};
  for (int ct = 0; ct <= rt; ++ct) {
    __syncthreads();
    for (int idx = tid; idx < 16 * 128; idx += 256) {
      int rr = idx >> 7, d = idx & 127;
      size_t g = ((size_t)(b * kS) + ct * 16 + rr) * kI + head_off + d;
      Ks[rr][d] = k[g];
      Vs[rr][d] = v[g];
    }
    if (tid < 16) Avs[tid] = a[(size_t)bh * kS + ct * 16 + tid];
    __syncthreads();
    int cg = ct * 16 + c;
    float sc = 0.f;
    if (cg <= rg) {
      float dot = 0.f;
#pragma unroll
      for (int d = 0; d < 128; ++d) dot += Qs[r][d] * Ks[c][d];
      sc = dot * 0.08838834764831845f * expf(Avs[c] - my_pmax);
    }
    rs_part += sc;
    Sc[r][c] = sc;
    __syncthreads();
#pragma unroll
    for (int cc = 0; cc < 16; ++cc) {
      float w = Sc[r][cc];
      float4 v0 = *(const float4*)&Vs[cc][c * 4];
      float4 v1 = *(const float4*)&Vs[cc][64 + c * 4];
      acc0[0] += w * v0.x; acc0[1] += w * v0.y; acc0[2] += w * v0.z; acc0[3] += w * v0.w;
      acc1[0] += w * v1.x; acc1[1] += w * v1.y; acc1[2] += w * v1.z; acc1[3] += w * v1.w;
    }
  }
  __syncthreads();
  Rs[r][c] = rs_part;
  __syncthreads();
  if (tid < 16) {
    float ssum = 0.f;
#pragma unroll
    for (int cc = 0; cc < 16; ++cc) ssum += Rs[tid][cc];
    int rg2 = rt * 16 + tid;
    float e0 = expf(-inc[(size_t)bh * kS + rg2] - pmax[(size_t)bh * kS + rg2]);
    float n = fmaxf(fabsf(ssum), e0);
    Ninv[tid] = 1.f / (n + 1e-6f);
  }
  __syncthreads();
  float ninv = Ninv[r];
  float* orow = out + ((size_t)(b * kS) + rg) * kI + head_off;
  float4 o0 = make_float4(acc0[0] * ninv, acc0[1] * ninv, acc0[2] * ninv, acc0[3] * ninv);
  float4 o1 = make_float4(acc1[0] * ninv, acc1[1] * ninv, acc1[2] * ninv, acc1[3] * ninv);
  *(float4*)&orow[c * 4] = o0;
  *(float4*)&orow[64 + c * 4] = o1;
}

// ======================= per-head norm + skip + output gate =======================
__global__ __launch_bounds__(128) void mhnorm_gate_kernel(
    const float* __restrict__ hh_in, const float* __restrict__ u, const float* __restrict__ xc,
    const float* __restrict__ onw, const float* __restrict__ skw, float* __restrict__ hh_out) {
  int mb = blockIdx.x;
  int m = mb >> 3, nh = mb & 7;
  int d = threadIdx.x;
  int cidx = nh * kDH + d;
  float val = hh_in[(size_t)m * kI + cidx];
  float s1 = val, s2 = val * val;
#pragma unroll
  for (int o = 1; o < 64; o <<= 1) { s1 += __shfl_xor(s1, o, 64); s2 += __shfl_xor(s2, o, 64); }
  __shared__ float w1[2], w2[2];
  if ((d & 63) == 0) { w1[d >> 6] = s1; w2[d >> 6] = s2; }
  __syncthreads();
  float mu = (w1[0] + w1[1]) * (1.f / 128.f);
  float m2 = (w2[0] + w2[1]) * (1.f / 128.f);
  float var = m2 - mu * mu;
  float nv = (val - mu) * rsqrtf(var + 1e-5f) * onw[cidx];
  float zc = u[(size_t)m * (2 * kI) + kI + cidx];
  float sz = zc / (1.f + expf(-zc));
  hh_out[(size_t)m * kI + cidx] = (nv + skw[cidx] * xc[(size_t)m * kI + cidx]) * sz;
}

// ======================= post-norm + head projection (last 96 rows/batch) =======================
__global__ __launch_bounds__(256) void head_kernel(
    const float* __restrict__ x, const float* __restrict__ pw,
    const float* __restrict__ hW, const float* __restrict__ hb, float* __restrict__ out) {
  int row = blockIdx.x;  // 0..767
  int b = row / kPRED, p = row % kPRED;
  int m = b * kS + (kS - kPRED) + p;
  int tid = threadIdx.x;
  float v0 = x[(size_t)m * kD + tid];
  float v1 = x[(size_t)m * kD + 256 + tid];
  float s1 = v0 + v1, s2 = v0 * v0 + v1 * v1;
#pragma unroll
  for (int o = 1; o < 64; o <<= 1) { s1 += __shfl_xor(s1, o, 64); s2 += __shfl_xor(s2, o, 64); }
  __shared__ float a1[4], a2[4];
  if ((tid & 63) == 0) { a1[tid >> 6] = s1; a2[tid >> 6] = s2; }
  __syncthreads();
  float t1 = a1[0] + a1[1] + a1[2] + a1[3];
  float t2 = a2[0] + a2[1] + a2[2] + a2[3];
  float mu = t1 * (1.f / kD);
  float var = t2 * (1.f / kD) - mu * mu;
  float rs = rsqrtf(var + 1e-5f);
  __shared__ float buf[512];
  buf[tid] = (v0 - mu) * rs * pw[tid];
  buf[256 + tid] = (v1 - mu) * rs * pw[256 + tid];
  __syncthreads();
  float acc[7] = {};
  for (int kk = tid; kk < 512; kk += 256) {
    float g = buf[kk];
#pragma unroll
    for (int n = 0; n < 7; ++n) acc[n] += g * hW[kk * 7 + n];
  }
  __shared__ float red[256 * 9];
#pragma unroll
  for (int n = 0; n < 7; ++n) red[tid * 9 + n] = acc[n];
  __syncthreads();
  for (int off = 128; off >= 1; off >>= 1) {
    if (tid < off) {
#pragma unroll
      for (int n = 0; n < 7; ++n) red[tid * 9 + n] += red[(tid + off) * 9 + n];
    }
    __syncthreads();
  }
  if (tid < 7) out[(size_t)row * 7 + tid] = red[tid] + hb[tid];
}

// ======================= host launch =======================
extern "C" void kernel_launch(void* const* d_in, const int* in_sizes, int n_in,
                              void* d_out, int out_size, void* d_ws, size_t ws_size,
                              hipStream_t stream) {
  const float* x_enc    = (const float*)d_in[0];
  const float* x_mark   = (const float*)d_in[1];
  // d_in[2], d_in[3] (x_dec, x_mark_dec) unused by the reference
  const float* emb_W    = (const float*)d_in[4];
  const float* emb_b    = (const float*)d_in[5];
  const float* blk_ln_w = (const float*)d_in[6];
  const float* up_W     = (const float*)d_in[7];
  const float* up_b     = (const float*)d_in[8];
  const float* conv_w   = (const float*)d_in[9];
  const float* conv_b   = (const float*)d_in[10];
  const float* Wq       = (const float*)d_in[11];
  const float* Wk       = (const float*)d_in[12];
  const float* Wv       = (const float*)d_in[13];
  const float* ig_W     = (const float*)d_in[14];
  const float* ig_b     = (const float*)d_in[15];
  const float* fg_W     = (const float*)d_in[16];
  const float* fg_b     = (const float*)d_in[17];
  const float* onorm_w  = (const float*)d_in[18];
  const float* skip_w   = (const float*)d_in[19];
  const float* down_W   = (const float*)d_in[20];
  const float* down_b   = (const float*)d_in[21];
  const float* post_w   = (const float*)d_in[22];
  const float* head_W   = (const float*)d_in[23];
  const float* head_b   = (const float*)d_in[24];
  float* out = (float*)d_out;

  float* ws = (float*)d_ws;
  float* X   = ws;                          // [4096,512]
  float* H   = X + (size_t)kM * kD;         // [4096,512]
  float* U   = H + (size_t)kM * kD;         // [4096,2048]
  float* XC  = U + (size_t)kM * 2 * kI;     // [4096,1024]
  float* Q   = XC + (size_t)kM * kI;        // [4096,1024]
  float* Kb  = Q + (size_t)kM * kI;         // [4096,1024]
  float* V   = Kb + (size_t)kM * kI;        // [4096,1024]
  float* HH  = V + (size_t)kM * kI;         // [4096,1024]
  float* IG  = HH + (size_t)kM * kI;        // [64,512]
  float* FG  = IG + (size_t)kB * kNH * kS;
  float* INC = FG + (size_t)kB * kNH * kS;
  float* AV  = INC + (size_t)kB * kNH * kS;
  float* PM  = AV + (size_t)kB * kNH * kS;

  embed_kernel<<<kM, 256, 0, stream>>>(x_enc, x_mark, emb_W, emb_b, X);

  for (int l = 0; l < kL; ++l) {
    const float* lnw  = blk_ln_w + (size_t)l * kD;
    const float* upWl = up_W + (size_t)l * kD * 2 * kI;
    const float* upbl = up_b + (size_t)l * 2 * kI;
    const float* cwl  = conv_w + (size_t)l * kI * 4;
    const float* cbl  = conv_b + (size_t)l * kI;
    const float* wql  = Wq + (size_t)l * 256 * 16;
    const float* wkl  = Wk + (size_t)l * 256 * 16;
    const float* wvl  = Wv + (size_t)l * 256 * 16;
    const float* igWl = ig_W + (size_t)l * 3 * kI * kNH;
    const float* igbl = ig_b + (size_t)l * kNH;
    const float* fgWl = fg_W + (size_t)l * 3 * kI * kNH;
    const float* fgbl = fg_b + (size_t)l * kNH;
    const float* onwl = onorm_w + (size_t)l * kI;
    const float* skwl = skip_w + (size_t)l * kI;
    const float* dWl  = down_W + (size_t)l * kI * kD;
    const float* dbl  = down_b + (size_t)l * kD;

    ln_kernel<<<kM, 256, 0, stream>>>(X, lnw, H);
    gemm_kernel<0><<<dim3(2 * kI / 64, kM / 64), 256, 0, stream>>>(H, upWl, upbl, U, kM, 2 * kI, kD);
    conv_silu_kernel<<<kM, 256, 0, stream>>>(U, cwl, cbl, XC);
    headwise_kernel<<<kM, 256, 0, stream>>>(U, XC, wql, wkl, wvl, Q, Kb, V);
    gates_kernel<<<kM, 256, 0, stream>>>(Q, Kb, V, igWl, igbl, fgWl, fgbl, IG, FG);
    scan_kernel<<<kB * kNH, 512, 0, stream>>>(IG, FG, INC, AV, PM);
    mlstm_kernel<<<dim3(kS / 16, kB * kNH), 256, 0, stream>>>(Q, Kb, V, INC, AV, PM, HH);
    mhnorm_gate_kernel<<<kM * kNH, 128, 0, stream>>>(HH, U, XC, onwl, skwl, HH);
    gemm_kernel<1><<<dim3(kD / 64, kM / 64), 256, 0, stream>>>(HH, dWl, dbl, X, kM, kD, kI);
  }

  head_kernel<<<kB * kPRED, 256, 0, stream>>>(X, post_w, head_W, head_b, out);
}

// Round 2
// 778.284 us; speedup vs baseline: 2.9275x; 2.9275x over previous
//
#include <hip/hip_runtime.h>
#include <math.h>

// ---- dims ----
static constexpr int kB = 8, kS = 512;
static constexpr int kD = 512, kI = 1024, kNH = 8, kDH = 128;
static constexpr int kL = 4, kPRED = 96, kCOUT = 7;
static constexpr int kM = kB * kS; // 4096 rows

typedef __bf16 bf16x8 __attribute__((ext_vector_type(8)));
typedef float f32x4 __attribute__((ext_vector_type(4)));

#define MFMA_BF16(a, b, c) __builtin_amdgcn_mfma_f32_16x16x32_bf16((a), (b), (c), 0, 0, 0)

typedef __attribute__((address_space(1))) const unsigned char* as1cp;
typedef __attribute__((address_space(3))) unsigned char* as3p;
__device__ __forceinline__ void gload16(const void* g, void* l) {
  __builtin_amdgcn_global_load_lds((as1cp)g, (as3p)l, 16, 0, 0);
}

__device__ __forceinline__ unsigned short f2bf(float f) {
  union { float f; unsigned u; } v; v.f = f;
  unsigned r = v.u + 0x7fffu + ((v.u >> 16) & 1u);
  return (unsigned short)(r >> 16);
}

// ======================= embedding =======================
__global__ __launch_bounds__(256) void embed_kernel(
    const float* __restrict__ xe, const float* __restrict__ xme,
    const float* __restrict__ W, const float* __restrict__ bias,
    float* __restrict__ x) {
  int m = blockIdx.x;
  int tid = threadIdx.x;
  __shared__ float f[11];
  if (tid < 7) f[tid] = xe[m * 7 + tid];
  else if (tid < 11) f[tid] = xme[m * 4 + (tid - 7)];
  __syncthreads();
  for (int d = tid; d < kD; d += 256) {
    float acc = bias[d];
#pragma unroll
    for (int e = 0; e < 11; ++e) acc += f[e] * W[e * kD + d];
    x[(size_t)m * kD + d] = acc;
  }
}

// ======================= layernorm (D=512, scale only) -> bf16 =======================
__global__ __launch_bounds__(256) void ln_kernel(
    const float* __restrict__ x, const float* __restrict__ w, unsigned short* __restrict__ h) {
  int m = blockIdx.x, tid = threadIdx.x;
  float v0 = x[(size_t)m * kD + tid];
  float v1 = x[(size_t)m * kD + 256 + tid];
  float s1 = v0 + v1, s2 = v0 * v0 + v1 * v1;
#pragma unroll
  for (int o = 1; o < 64; o <<= 1) { s1 += __shfl_xor(s1, o, 64); s2 += __shfl_xor(s2, o, 64); }
  __shared__ float a1[4], a2[4];
  if ((tid & 63) == 0) { a1[tid >> 6] = s1; a2[tid >> 6] = s2; }
  __syncthreads();
  float t1 = a1[0] + a1[1] + a1[2] + a1[3];
  float t2 = a2[0] + a2[1] + a2[2] + a2[3];
  float mu = t1 * (1.f / kD);
  float var = t2 * (1.f / kD) - mu * mu;
  float rs = rsqrtf(var + 1e-5f);
  h[(size_t)m * kD + tid] = f2bf((v0 - mu) * rs * w[tid]);
  h[(size_t)m * kD + 256 + tid] = f2bf((v1 - mu) * rs * w[256 + tid]);
}

// ======================= weight transpose+cast: W[Kd][N] f32 -> WT[N][Kd] bf16 ============
__global__ __launch_bounds__(256) void tpose_w_kernel(
    const float* __restrict__ W, unsigned short* __restrict__ WT, int N, int Kd) {
  int n0 = blockIdx.x * 64, k0 = blockIdx.y * 64;
  __shared__ float t[64][65];
  int tid = threadIdx.x;
  for (int idx = tid; idx < 4096; idx += 256) {
    int r = idx >> 6, c = idx & 63;
    t[r][c] = W[(size_t)(k0 + r) * N + n0 + c];
  }
  __syncthreads();
  for (int idx = tid; idx < 4096; idx += 256) {
    int r = idx >> 6, c = idx & 63;
    WT[(size_t)(n0 + r) * Kd + k0 + c] = f2bf(t[c][r]);
  }
}

// ======================= bf16 MFMA GEMM: C[M,N] = A[M,Kd] @ BT[N,Kd]^T + bias (+C) ========
// 128x128 tile, BK=64, 4 waves (2x2), swizzled LDS, global_load_lds staging.
template <int RESID>
__global__ __launch_bounds__(256) void gemm_mfma_kernel(
    const unsigned short* __restrict__ A, const unsigned short* __restrict__ BT,
    const float* __restrict__ bias, float* __restrict__ C, int N, int Kd) {
  __shared__ __align__(16) char As[16384];
  __shared__ __align__(16) char Bs[16384];
  int tid = threadIdx.x, w = tid >> 6, l = tid & 63;
  int lr = l & 15, lg = l >> 4;
  int bm = blockIdx.y, bn = blockIdx.x;
  int wrow = (w >> 1) * 64, wcol = (w & 1) * 64;
  f32x4 acc[4][4] = {};
  for (int kt = 0; kt < Kd; kt += 64) {
    __syncthreads();
#pragma unroll
    for (int j = 0; j < 8; ++j) {
      int g = w * 8 + j;
      bool isA = g < 16;
      int ii = isA ? g : g - 16;
      int row = ii * 8 + (l >> 3);
      int chunk = (l & 7) ^ (row & 7);
      const unsigned short* src = isA
          ? A + ((size_t)(bm * 128 + row) * Kd + kt) + chunk * 8
          : BT + ((size_t)(bn * 128 + row) * Kd + kt) + chunk * 8;
      char* dst = (isA ? As : Bs) + ii * 1024;
      gload16(src, dst);
    }
    __syncthreads();
#pragma unroll
    for (int kk = 0; kk < 2; ++kk) {
      bf16x8 af[4], bfr[4];
#pragma unroll
      for (int m = 0; m < 4; ++m) {
        int row = wrow + m * 16 + lr;
        int ch = (kk * 4 + lg) ^ (row & 7);
        af[m] = *(const bf16x8*)(As + row * 128 + ch * 16);
      }
#pragma unroll
      for (int n = 0; n < 4; ++n) {
        int row = wcol + n * 16 + lr;
        int ch = (kk * 4 + lg) ^ (row & 7);
        bfr[n] = *(const bf16x8*)(Bs + row * 128 + ch * 16);
      }
#pragma unroll
      for (int m = 0; m < 4; ++m)
#pragma unroll
        for (int n = 0; n < 4; ++n)
          acc[m][n] = MFMA_BF16(af[m], bfr[n], acc[m][n]);
    }
  }
#pragma unroll
  for (int n = 0; n < 4; ++n) {
    int col = bn * 128 + wcol + n * 16 + lr;
    float bv = bias[col];
#pragma unroll
    for (int m = 0; m < 4; ++m)
#pragma unroll
      for (int i = 0; i < 4; ++i) {
        int row = bm * 128 + wrow + m * 16 + lg * 4 + i;
        float v = acc[m][n][i] + bv;
        if (RESID) v += C[(size_t)row * N + col];
        C[(size_t)row * N + col] = v;
      }
  }
}

// ======================= causal depthwise conv (K=4) + silu =======================
__global__ __launch_bounds__(256) void conv_silu_kernel(
    const float* __restrict__ u, const float* __restrict__ cw,
    const float* __restrict__ cb, float* __restrict__ xc) {
  int m = blockIdx.x;
  int b = m >> 9, s = m & 511;
  int tid = threadIdx.x;
  for (int c = tid; c < kI; c += 256) {
    float acc = cb[c];
#pragma unroll
    for (int j = 0; j < 4; ++j) {
      int sp = s - 3 + j;
      if (sp >= 0) acc += u[((size_t)(b * kS + sp)) * (2 * kI) + c] * cw[c * 4 + j];
    }
    xc[(size_t)m * kI + c] = acc / (1.f + expf(-acc));
  }
}

// ======================= headwise q,k,v -> bf16 head-major [bh][s][d] =======================
__global__ __launch_bounds__(256) void headwise_qkv_kernel(
    const float* __restrict__ u, const float* __restrict__ xc,
    const float* __restrict__ Wq, const float* __restrict__ Wk, const float* __restrict__ Wv,
    unsigned short* __restrict__ qb, unsigned short* __restrict__ kb,
    unsigned short* __restrict__ vb) {
  int m = blockIdx.x;
  int b = m >> 9, s = m & 511;
  int tid = threadIdx.x;
  __shared__ float xcs[kI], xms[kI];
  for (int i = tid; i < kI; i += 256) {
    xcs[i] = xc[(size_t)m * kI + i];
    xms[i] = u[(size_t)m * (2 * kI) + i];
  }
  __syncthreads();
  int n = tid;  // block index 0..255
  float xq[4], xm4[4];
#pragma unroll
  for (int i = 0; i < 4; ++i) { xq[i] = xcs[n * 4 + i]; xm4[i] = xms[n * 4 + i]; }
  const float* wq = Wq + n * 16;
  const float* wk = Wk + n * 16;
  const float* wv = Wv + n * 16;
  unsigned long long qv = 0, kv = 0, vv = 0;
#pragma unroll
  for (int o = 0; o < 4; ++o) {
    float aq = 0, ak = 0, av = 0;
#pragma unroll
    for (int i = 0; i < 4; ++i) {
      aq += xq[i] * wq[o * 4 + i];
      ak += xq[i] * wk[o * 4 + i];
      av += xm4[i] * wv[o * 4 + i];
    }
    qv |= (unsigned long long)f2bf(aq) << (o * 16);
    kv |= (unsigned long long)f2bf(ak) << (o * 16);
    vv |= (unsigned long long)f2bf(av) << (o * 16);
  }
  size_t base = ((size_t)(b * 8 + (n >> 5)) * kS + s) * kDH + (n & 31) * 4;
  *(unsigned long long*)&qb[base] = qv;
  *(unsigned long long*)&kb[base] = kv;
  *(unsigned long long*)&vb[base] = vv;
}

// ======================= gate weight transpose: [3072][8]x2 -> gWT[16][3072] bf16 =========
__global__ __launch_bounds__(256) void tpose_gates_kernel(
    const float* __restrict__ igW, const float* __restrict__ fgW,
    unsigned short* __restrict__ gWT) {
  int k = blockIdx.x * 256 + threadIdx.x;
#pragma unroll
  for (int h = 0; h < 8; ++h) {
    gWT[(size_t)h * 3072 + k] = f2bf(igW[(size_t)k * 8 + h]);
    gWT[(size_t)(8 + h) * 3072 + k] = f2bf(fgW[(size_t)k * 8 + h]);
  }
}

// ======================= gates via MFMA: [64 rows] x [3072] x [16] =======================
__global__ __launch_bounds__(256) void gates_mfma_kernel(
    const unsigned short* __restrict__ qb, const unsigned short* __restrict__ kb,
    const unsigned short* __restrict__ vb, const unsigned short* __restrict__ gWT,
    const float* __restrict__ igb, const float* __restrict__ fgb,
    float* __restrict__ IG, float* __restrict__ FG) {
  int blk = blockIdx.x;
  int b = blk >> 3, s0 = (blk & 7) * 64;
  int tid = threadIdx.x, w = tid >> 6, l = tid & 63;
  int lr = l & 15, lg = l >> 4;
  __shared__ __align__(16) char Ts[16384];  // [64 s][128 k] bf16, RB=256, swizzled
  f32x4 acc = {};
  for (int kc = 0; kc < 24; ++kc) {
    const unsigned short* srcbase;
    if (kc < 8) srcbase = qb + ((size_t)(b * 8 + kc) * kS + s0) * kDH;
    else if (kc < 16) srcbase = kb + ((size_t)(b * 8 + kc - 8) * kS + s0) * kDH;
    else srcbase = vb + ((size_t)(b * 8 + kc - 16) * kS + s0) * kDH;
    __syncthreads();
#pragma unroll
    for (int j = 0; j < 4; ++j) {
      int issue = w * 4 + j;
      int row = issue * 4 + (l >> 4);
      int chunk = (l & 15) ^ (row & 7);
      gload16(srcbase + row * 128 + chunk * 8, Ts + issue * 1024);
    }
    __syncthreads();
#pragma unroll
    for (int kk = 0; kk < 4; ++kk) {
      int arow = w * 16 + lr;
      int ch = (kk * 4 + lg) ^ (arow & 7);
      bf16x8 af = *(const bf16x8*)(Ts + arow * 256 + ch * 16);
      bf16x8 bfv = *(const bf16x8*)(gWT + (size_t)lr * 3072 + kc * 128 + kk * 32 + lg * 8);
      acc = MFMA_BF16(af, bfv, acc);
    }
  }
#pragma unroll
  for (int i = 0; i < 4; ++i) {
    int s = s0 + w * 16 + lg * 4 + i;
    if (lr < 8) IG[((size_t)(b * 8) + lr) * kS + s] = acc[i] + igb[lr];
    else FG[((size_t)(b * 8) + lr - 8) * kS + s] = acc[i] + fgb[lr - 8];
  }
}

// ======================= per-(b,nh) scan: inc, a, pmax =======================
__global__ __launch_bounds__(512) void scan_kernel(
    const float* __restrict__ ig, const float* __restrict__ fg,
    float* __restrict__ inc, float* __restrict__ a, float* __restrict__ pmax) {
  int bh = blockIdx.x;
  int t = threadIdx.x;
  __shared__ float buf[512];
  float x = fg[(size_t)bh * kS + t];
  float lf = fminf(x, 0.f) - log1pf(expf(-fabsf(x)));  // log_sigmoid
  buf[t] = lf;
  __syncthreads();
  for (int off = 1; off < 512; off <<= 1) {
    float p = (t >= off) ? buf[t - off] : 0.f;
    __syncthreads();
    buf[t] += p;
    __syncthreads();
  }
  float inct = buf[t];
  inc[(size_t)bh * kS + t] = inct;
  float av = ig[(size_t)bh * kS + t] - inct;
  a[(size_t)bh * kS + t] = av;
  buf[t] = av;
  __syncthreads();
  for (int off = 1; off < 512; off <<= 1) {
    float p = (t >= off) ? buf[t - off] : -1e30f;
    __syncthreads();
    buf[t] = fmaxf(buf[t], p);
    __syncthreads();
  }
  pmax[(size_t)bh * kS + t] = buf[t];
}

// ======================= V transpose: vb[bh][s][d] -> vt[bh][d][s] (bf16) ================
__global__ __launch_bounds__(256) void tpose_v_kernel(
    const unsigned short* __restrict__ vb, unsigned short* __restrict__ vt) {
  int bh = blockIdx.y, s0 = blockIdx.x * 64;
  __shared__ unsigned short t[64][130];
  int tid = threadIdx.x;
  for (int idx = tid; idx < 64 * 128; idx += 256) {
    int sl = idx >> 7, d = idx & 127;
    t[sl][d] = vb[((size_t)bh * kS + s0 + sl) * kDH + d];
  }
  __syncthreads();
  for (int idx = tid; idx < 64 * 128; idx += 256) {
    int dl = idx >> 6, sl = idx & 63;
    vt[((size_t)bh * kDH + dl) * kS + s0 + sl] = t[sl][dl];
  }
}

// ======================= mLSTM parallel via MFMA =======================
// block: (rt 0..7, bh 0..63), 4 waves x 16 rows = 64 Q rows.
__global__ __launch_bounds__(256) void mlstm_mfma_kernel(
    const unsigned short* __restrict__ qb, const unsigned short* __restrict__ kb,
    const unsigned short* __restrict__ vt,
    const float* __restrict__ INC, const float* __restrict__ AV, const float* __restrict__ PM,
    float* __restrict__ out) {
  int rt = blockIdx.x;
  int bh = blockIdx.y;
  int b = bh >> 3, nh = bh & 7;
  int tid = threadIdx.x, w = tid >> 6, l = tid & 63;
  int lr = l & 15, lg = l >> 4;
  __shared__ __align__(16) char Ks[16384];     // [64 s][128 d] bf16, RB=256
  __shared__ __align__(16) char Vs[16384];     // [128 d][64 s] bf16, RB=128
  __shared__ __align__(16) char Ps[4][2048];   // per-wave [16][64] bf16, RB=128

  // Q fragments in registers
  bf16x8 qf[4];
  int qrow = rt * 64 + w * 16 + lr;
  const unsigned short* qrp = qb + ((size_t)bh * kS + qrow) * kDH + lg * 8;
#pragma unroll
  for (int kk = 0; kk < 4; ++kk) qf[kk] = *(const bf16x8*)(qrp + kk * 32);

  float pm_r[4];
#pragma unroll
  for (int i = 0; i < 4; ++i)
    pm_r[i] = PM[(size_t)bh * kS + rt * 64 + w * 16 + lg * 4 + i];

  f32x4 oacc[8] = {};
  float rs[4] = {};

  for (int ct = 0; ct <= rt; ++ct) {
    __syncthreads();
    // stage K tile [64][128] (rows contiguous in global)
    {
      const unsigned short* kbase = kb + ((size_t)bh * kS + ct * 64) * kDH;
#pragma unroll
      for (int j = 0; j < 4; ++j) {
        int issue = w * 4 + j;
        int row = issue * 4 + (l >> 4);
        int chunk = (l & 15) ^ (row & 7);
        gload16(kbase + row * 128 + chunk * 8, Ks + issue * 1024);
      }
    }
    // stage V^T tile [128 d][64 s] (rows stride 512 in global)
    {
      const unsigned short* vbase = vt + (size_t)bh * kDH * kS + ct * 64;
#pragma unroll
      for (int j = 0; j < 4; ++j) {
        int issue = w * 4 + j + 16;  // reuse issue numbering 0..15 for V
        int vi = issue - 16;
        int row = vi * 8 + (l >> 3);
        int chunk = (l & 7) ^ (row & 7);
        gload16(vbase + (size_t)row * kS + chunk * 8, Vs + vi * 1024);
      }
    }
    __syncthreads();
    // QK^T: 16 MFMAs
    f32x4 sacc[4] = {};
#pragma unroll
    for (int n = 0; n < 4; ++n) {
#pragma unroll
      for (int kk = 0; kk < 4; ++kk) {
        int krow = n * 16 + lr;
        int ch = (kk * 4 + lg) ^ (krow & 7);
        bf16x8 kf = *(const bf16x8*)(Ks + krow * 256 + ch * 16);
        sacc[n] = MFMA_BF16(qf[kk], kf, sacc[n]);
      }
    }
    // transform scores -> P (bf16 in LDS), accumulate row sums
#pragma unroll
    for (int n = 0; n < 4; ++n) {
      float av = AV[(size_t)bh * kS + ct * 64 + n * 16 + lr];
      int cg = ct * 64 + n * 16 + lr;
#pragma unroll
      for (int i = 0; i < 4; ++i) {
        int rg = rt * 64 + w * 16 + lg * 4 + i;
        float s = 0.f;
        if (ct < rt || cg <= rg)
          s = sacc[n][i] * 0.08838834764831845f * expf(av - pm_r[i]);
        rs[i] += s;
        int prow = lg * 4 + i, pcol = n * 16 + lr;
        int byte = prow * 128 + ((((pcol >> 3) ^ (prow & 7))) << 4) + (pcol & 7) * 2;
        *(unsigned short*)(Ps[w] + byte) = f2bf(s);
      }
    }
    // PV: 16 MFMAs
#pragma unroll
    for (int kk = 0; kk < 2; ++kk) {
      int prow = lr;
      int pch = (kk * 4 + lg) ^ (prow & 7);
      bf16x8 pf = *(const bf16x8*)(Ps[w] + prow * 128 + pch * 16);
#pragma unroll
      for (int nb = 0; nb < 8; ++nb) {
        int vrow = nb * 16 + lr;
        int vch = (kk * 4 + lg) ^ (vrow & 7);
        bf16x8 vf = *(const bf16x8*)(Vs + vrow * 128 + vch * 16);
        oacc[nb] = MFMA_BF16(pf, vf, oacc[nb]);
      }
    }
  }
  // reduce row sums across the 16-lane group
#pragma unroll
  for (int i = 0; i < 4; ++i)
#pragma unroll
    for (int off = 1; off < 16; off <<= 1) rs[i] += __shfl_xor(rs[i], off, 16);
  float ninv[4];
#pragma unroll
  for (int i = 0; i < 4; ++i) {
    int rg = rt * 64 + w * 16 + lg * 4 + i;
    float e0 = expf(-INC[(size_t)bh * kS + rg] - pm_r[i]);
    float nn = fmaxf(fabsf(rs[i]), e0);
    ninv[i] = 1.f / (nn + 1e-6f);
  }
#pragma unroll
  for (int nb = 0; nb < 8; ++nb)
#pragma unroll
    for (int i = 0; i < 4; ++i) {
      int rg = rt * 64 + w * 16 + lg * 4 + i;
      out[((size_t)(b * kS) + rg) * kI + nh * kDH + nb * 16 + lr] = oacc[nb][i] * ninv[i];
    }
}

// ======================= per-head norm + skip + output gate -> bf16 =======================
__global__ __launch_bounds__(128) void mhnorm_gate_kernel(
    const float* __restrict__ hh_in, const float* __restrict__ u, const float* __restrict__ xc,
    const float* __restrict__ onw, const float* __restrict__ skw,
    unsigned short* __restrict__ hh_out) {
  int mb = blockIdx.x;
  int m = mb >> 3, nh = mb & 7;
  int d = threadIdx.x;
  int cidx = nh * kDH + d;
  float val = hh_in[(size_t)m * kI + cidx];
  float s1 = val, s2 = val * val;
#pragma unroll
  for (int o = 1; o < 64; o <<= 1) { s1 += __shfl_xor(s1, o, 64); s2 += __shfl_xor(s2, o, 64); }
  __shared__ float w1[2], w2[2];
  if ((d & 63) == 0) { w1[d >> 6] = s1; w2[d >> 6] = s2; }
  __syncthreads();
  float mu = (w1[0] + w1[1]) * (1.f / 128.f);
  float m2 = (w2[0] + w2[1]) * (1.f / 128.f);
  float var = m2 - mu * mu;
  float nv = (val - mu) * rsqrtf(var + 1e-5f) * onw[cidx];
  float zc = u[(size_t)m * (2 * kI) + kI + cidx];
  float sz = zc / (1.f + expf(-zc));
  hh_out[(size_t)m * kI + cidx] = f2bf((nv + skw[cidx] * xc[(size_t)m * kI + cidx]) * sz);
}

// ======================= post-norm + head projection (last 96 rows/batch) =======================
__global__ __launch_bounds__(256) void head_kernel(
    const float* __restrict__ x, const float* __restrict__ pw,
    const float* __restrict__ hW, const float* __restrict__ hb, float* __restrict__ out) {
  int row = blockIdx.x;  // 0..767
  int b = row / kPRED, p = row % kPRED;
  int m = b * kS + (kS - kPRED) + p;
  int tid = threadIdx.x;
  float v0 = x[(size_t)m * kD + tid];
  float v1 = x[(size_t)m * kD + 256 + tid];
  float s1 = v0 + v1, s2 = v0 * v0 + v1 * v1;
#pragma unroll
  for (int o = 1; o < 64; o <<= 1) { s1 += __shfl_xor(s1, o, 64); s2 += __shfl_xor(s2, o, 64); }
  __shared__ float a1[4], a2[4];
  if ((tid & 63) == 0) { a1[tid >> 6] = s1; a2[tid >> 6] = s2; }
  __syncthreads();
  float t1 = a1[0] + a1[1] + a1[2] + a1[3];
  float t2 = a2[0] + a2[1] + a2[2] + a2[3];
  float mu = t1 * (1.f / kD);
  float var = t2 * (1.f / kD) - mu * mu;
  float rs = rsqrtf(var + 1e-5f);
  __shared__ float buf[512];
  buf[tid] = (v0 - mu) * rs * pw[tid];
  buf[256 + tid] = (v1 - mu) * rs * pw[256 + tid];
  __syncthreads();
  float acc[7] = {};
  for (int kk = tid; kk < 512; kk += 256) {
    float g = buf[kk];
#pragma unroll
    for (int n = 0; n < 7; ++n) acc[n] += g * hW[kk * 7 + n];
  }
  __shared__ float red[256 * 9];
#pragma unroll
  for (int n = 0; n < 7; ++n) red[tid * 9 + n] = acc[n];
  __syncthreads();
  for (int off = 128; off >= 1; off >>= 1) {
    if (tid < off) {
#pragma unroll
      for (int n = 0; n < 7; ++n) red[tid * 9 + n] += red[(tid + off) * 9 + n];
    }
    __syncthreads();
  }
  if (tid < 7) out[(size_t)row * 7 + tid] = red[tid] + hb[tid];
}

// ======================= host launch =======================
extern "C" void kernel_launch(void* const* d_in, const int* in_sizes, int n_in,
                              void* d_out, int out_size, void* d_ws, size_t ws_size,
                              hipStream_t stream) {
  const float* x_enc    = (const float*)d_in[0];
  const float* x_mark   = (const float*)d_in[1];
  const float* emb_W    = (const float*)d_in[4];
  const float* emb_b    = (const float*)d_in[5];
  const float* blk_ln_w = (const float*)d_in[6];
  const float* up_W     = (const float*)d_in[7];
  const float* up_b     = (const float*)d_in[8];
  const float* conv_w   = (const float*)d_in[9];
  const float* conv_b   = (const float*)d_in[10];
  const float* Wq       = (const float*)d_in[11];
  const float* Wk       = (const float*)d_in[12];
  const float* Wv       = (const float*)d_in[13];
  const float* ig_W     = (const float*)d_in[14];
  const float* ig_b     = (const float*)d_in[15];
  const float* fg_W     = (const float*)d_in[16];
  const float* fg_b     = (const float*)d_in[17];
  const float* onorm_w  = (const float*)d_in[18];
  const float* skip_w   = (const float*)d_in[19];
  const float* down_W   = (const float*)d_in[20];
  const float* down_b   = (const float*)d_in[21];
  const float* post_w   = (const float*)d_in[22];
  const float* head_W   = (const float*)d_in[23];
  const float* head_b   = (const float*)d_in[24];
  float* out = (float*)d_out;

  char* ws = (char*)d_ws;
  float* X  = (float*)ws;                 ws += (size_t)kM * kD * 4;        // 8 MB
  float* U  = (float*)ws;                 ws += (size_t)kM * 2 * kI * 4;    // 32 MB
  float* XC = (float*)ws;                 ws += (size_t)kM * kI * 4;        // 16 MB
  float* HH = (float*)ws;                 ws += (size_t)kM * kI * 4;        // 16 MB
  unsigned short* Hb   = (unsigned short*)ws; ws += (size_t)kM * kD * 2;    // 4 MB
  unsigned short* HHb  = (unsigned short*)ws; ws += (size_t)kM * kI * 2;    // 8 MB
  unsigned short* qb   = (unsigned short*)ws; ws += (size_t)kM * kI * 2;    // 8 MB
  unsigned short* kbuf = (unsigned short*)ws; ws += (size_t)kM * kI * 2;    // 8 MB
  unsigned short* vb   = (unsigned short*)ws; ws += (size_t)kM * kI * 2;    // 8 MB
  unsigned short* vt   = (unsigned short*)ws; ws += (size_t)kM * kI * 2;    // 8 MB
  unsigned short* upWT = (unsigned short*)ws; ws += (size_t)2 * kI * kD * 2; // 2 MB
  unsigned short* dnWT = (unsigned short*)ws; ws += (size_t)kD * kI * 2;    // 1 MB
  unsigned short* gWT  = (unsigned short*)ws; ws += (size_t)16 * 3072 * 2;  // 96 KB
  float* IG  = (float*)ws; ws += (size_t)64 * kS * 4;
  float* FG  = (float*)ws; ws += (size_t)64 * kS * 4;
  float* INC = (float*)ws; ws += (size_t)64 * kS * 4;
  float* AV  = (float*)ws; ws += (size_t)64 * kS * 4;
  float* PM  = (float*)ws; ws += (size_t)64 * kS * 4;

  embed_kernel<<<kM, 256, 0, stream>>>(x_enc, x_mark, emb_W, emb_b, X);

  for (int l = 0; l < kL; ++l) {
    const float* lnw  = blk_ln_w + (size_t)l * kD;
    const float* upWl = up_W + (size_t)l * kD * 2 * kI;
    const float* upbl = up_b + (size_t)l * 2 * kI;
    const float* cwl  = conv_w + (size_t)l * kI * 4;
    const float* cbl  = conv_b + (size_t)l * kI;
    const float* wql  = Wq + (size_t)l * 256 * 16;
    const float* wkl  = Wk + (size_t)l * 256 * 16;
    const float* wvl  = Wv + (size_t)l * 256 * 16;
    const float* igWl = ig_W + (size_t)l * 3 * kI * kNH;
    const float* igbl = ig_b + (size_t)l * kNH;
    const float* fgWl = fg_W + (size_t)l * 3 * kI * kNH;
    const float* fgbl = fg_b + (size_t)l * kNH;
    const float* onwl = onorm_w + (size_t)l * kI;
    const float* skwl = skip_w + (size_t)l * kI;
    const float* dWl  = down_W + (size_t)l * kI * kD;
    const float* dbl  = down_b + (size_t)l * kD;

    ln_kernel<<<kM, 256, 0, stream>>>(X, lnw, Hb);
    tpose_w_kernel<<<dim3(32, 8), 256, 0, stream>>>(upWl, upWT, 2 * kI, kD);
    gemm_mfma_kernel<0><<<dim3(16, 32), 256, 0, stream>>>(Hb, upWT, upbl, U, 2 * kI, kD);
    conv_silu_kernel<<<kM, 256, 0, stream>>>(U, cwl, cbl, XC);
    headwise_qkv_kernel<<<kM, 256, 0, stream>>>(U, XC, wql, wkl, wvl, qb, kbuf, vb);
    tpose_gates_kernel<<<12, 256, 0, stream>>>(igWl, fgWl, gWT);
    gates_mfma_kernel<<<64, 256, 0, stream>>>(qb, kbuf, vb, gWT, igbl, fgbl, IG, FG);
    scan_kernel<<<64, 512, 0, stream>>>(IG, FG, INC, AV, PM);
    tpose_v_kernel<<<dim3(8, 64), 256, 0, stream>>>(vb, vt);
    mlstm_mfma_kernel<<<dim3(8, 64), 256, 0, stream>>>(qb, kbuf, vt, INC, AV, PM, HH);
    mhnorm_gate_kernel<<<kM * kNH, 128, 0, stream>>>(HH, U, XC, onwl, skwl, HHb);
    tpose_w_kernel<<<dim3(8, 16), 256, 0, stream>>>(dWl, dnWT, kD, kI);
    gemm_mfma_kernel<1><<<dim3(4, 32), 256, 0, stream>>>(HHb, dnWT, dbl, X, kD, kI);
  }

  head_kernel<<<kB * kPRED, 256, 0, stream>>>(X, post_w, head_W, head_b, out);
}

// Round 3
// 649.793 us; speedup vs baseline: 3.5063x; 1.1977x over previous
//
#include <hip/hip_runtime.h>
#include <math.h>

// ---- dims ----
static constexpr int kB = 8, kS = 512;
static constexpr int kD = 512, kI = 1024, kNH = 8, kDH = 128;
static constexpr int kL = 4, kPRED = 96, kCOUT = 7;
static constexpr int kM = kB * kS; // 4096 rows

typedef __bf16 bf16x8 __attribute__((ext_vector_type(8)));
typedef float f32x4 __attribute__((ext_vector_type(4)));

#define MFMA_BF16(a, b, c) __builtin_amdgcn_mfma_f32_16x16x32_bf16((a), (b), (c), 0, 0, 0)

typedef __attribute__((address_space(1))) const unsigned char* as1cp;
typedef __attribute__((address_space(3))) unsigned char* as3p;
__device__ __forceinline__ void gload16(const void* g, void* l) {
  __builtin_amdgcn_global_load_lds((as1cp)g, (as3p)l, 16, 0, 0);
}

__device__ __forceinline__ unsigned short f2bf(float f) {
  union { float f; unsigned u; } v; v.f = f;
  unsigned r = v.u + 0x7fffu + ((v.u >> 16) & 1u);
  return (unsigned short)(r >> 16);
}
__device__ __forceinline__ float bf2f(unsigned short h) {
  union { unsigned u; float f; } v; v.u = (unsigned)h << 16; return v.f;
}

// ======================= embedding =======================
__global__ __launch_bounds__(256) void embed_kernel(
    const float* __restrict__ xe, const float* __restrict__ xme,
    const float* __restrict__ W, const float* __restrict__ bias,
    float* __restrict__ x) {
  int m = blockIdx.x;
  int tid = threadIdx.x;
  __shared__ float f[11];
  if (tid < 7) f[tid] = xe[m * 7 + tid];
  else if (tid < 11) f[tid] = xme[m * 4 + (tid - 7)];
  __syncthreads();
  for (int d = tid; d < kD; d += 256) {
    float acc = bias[d];
#pragma unroll
    for (int e = 0; e < 11; ++e) acc += f[e] * W[e * kD + d];
    x[(size_t)m * kD + d] = acc;
  }
}

// ======================= layernorm (D=512, scale only) -> bf16 =======================
__global__ __launch_bounds__(256) void ln_kernel(
    const float* __restrict__ x, const float* __restrict__ w, unsigned short* __restrict__ h) {
  int m = blockIdx.x, tid = threadIdx.x;
  float v0 = x[(size_t)m * kD + tid];
  float v1 = x[(size_t)m * kD + 256 + tid];
  float s1 = v0 + v1, s2 = v0 * v0 + v1 * v1;
#pragma unroll
  for (int o = 1; o < 64; o <<= 1) { s1 += __shfl_xor(s1, o, 64); s2 += __shfl_xor(s2, o, 64); }
  __shared__ float a1[4], a2[4];
  if ((tid & 63) == 0) { a1[tid >> 6] = s1; a2[tid >> 6] = s2; }
  __syncthreads();
  float t1 = a1[0] + a1[1] + a1[2] + a1[3];
  float t2 = a2[0] + a2[1] + a2[2] + a2[3];
  float mu = t1 * (1.f / kD);
  float var = t2 * (1.f / kD) - mu * mu;
  float rs = rsqrtf(var + 1e-5f);
  h[(size_t)m * kD + tid] = f2bf((v0 - mu) * rs * w[tid]);
  h[(size_t)m * kD + 256 + tid] = f2bf((v1 - mu) * rs * w[256 + tid]);
}

// ============ weight transpose+cast (all layers): W[l][Kd][N] f32 -> WT[l][N][Kd] bf16 ====
__global__ __launch_bounds__(256) void tpose_w_kernel(
    const float* __restrict__ W, unsigned short* __restrict__ WT, int N, int Kd) {
  int l = blockIdx.z;
  const float* Wl = W + (size_t)l * N * Kd;
  unsigned short* WTl = WT + (size_t)l * N * Kd;
  int n0 = blockIdx.x * 64, k0 = blockIdx.y * 64;
  __shared__ float t[64][65];
  int tid = threadIdx.x;
  for (int idx = tid; idx < 4096; idx += 256) {
    int r = idx >> 6, c = idx & 63;
    t[r][c] = Wl[(size_t)(k0 + r) * N + n0 + c];
  }
  __syncthreads();
  for (int idx = tid; idx < 4096; idx += 256) {
    int r = idx >> 6, c = idx & 63;
    WTl[(size_t)(n0 + r) * Kd + k0 + c] = f2bf(t[c][r]);
  }
}

// ===== gate weight transpose (all layers): [l][3072][8]x2 -> gWT[l][16][3072] bf16 ======
__global__ __launch_bounds__(256) void tpose_gates_kernel(
    const float* __restrict__ igW, const float* __restrict__ fgW,
    unsigned short* __restrict__ gWT) {
  int l = blockIdx.y;
  int k = blockIdx.x * 256 + threadIdx.x;
  const float* igl = igW + (size_t)l * 3072 * 8;
  const float* fgl = fgW + (size_t)l * 3072 * 8;
  unsigned short* gl = gWT + (size_t)l * 16 * 3072;
#pragma unroll
  for (int h = 0; h < 8; ++h) {
    gl[(size_t)h * 3072 + k] = f2bf(igl[(size_t)k * 8 + h]);
    gl[(size_t)(8 + h) * 3072 + k] = f2bf(fgl[(size_t)k * 8 + h]);
  }
}

// ======================= bf16 MFMA GEMM: C[M,N] = A[M,Kd] @ BT[N,Kd]^T + bias (+C) ========
// 128x128 tile, BK=64, 4 waves (2x2), swizzled LDS, global_load_lds staging.
// TO = unsigned short (bf16 out, no resid) or float (fp32 out, resid if RESID).
template <int RESID, typename TO>
__global__ __launch_bounds__(256) void gemm_mfma_kernel(
    const unsigned short* __restrict__ A, const unsigned short* __restrict__ BT,
    const float* __restrict__ bias, TO* __restrict__ C, int N, int Kd) {
  __shared__ __align__(16) char As[16384];
  __shared__ __align__(16) char Bs[16384];
  int tid = threadIdx.x, w = tid >> 6, l = tid & 63;
  int lr = l & 15, lg = l >> 4;
  int bm = blockIdx.y, bn = blockIdx.x;
  int wrow = (w >> 1) * 64, wcol = (w & 1) * 64;
  f32x4 acc[4][4] = {};
  for (int kt = 0; kt < Kd; kt += 64) {
    __syncthreads();
#pragma unroll
    for (int j = 0; j < 8; ++j) {
      int g = w * 8 + j;
      bool isA = g < 16;
      int ii = isA ? g : g - 16;
      int row = ii * 8 + (l >> 3);
      int chunk = (l & 7) ^ (row & 7);
      const unsigned short* src = isA
          ? A + ((size_t)(bm * 128 + row) * Kd + kt) + chunk * 8
          : BT + ((size_t)(bn * 128 + row) * Kd + kt) + chunk * 8;
      char* dst = (isA ? As : Bs) + ii * 1024;
      gload16(src, dst);
    }
    __syncthreads();
#pragma unroll
    for (int kk = 0; kk < 2; ++kk) {
      bf16x8 af[4], bfr[4];
#pragma unroll
      for (int m = 0; m < 4; ++m) {
        int row = wrow + m * 16 + lr;
        int ch = (kk * 4 + lg) ^ (row & 7);
        af[m] = *(const bf16x8*)(As + row * 128 + ch * 16);
      }
#pragma unroll
      for (int n = 0; n < 4; ++n) {
        int row = wcol + n * 16 + lr;
        int ch = (kk * 4 + lg) ^ (row & 7);
        bfr[n] = *(const bf16x8*)(Bs + row * 128 + ch * 16);
      }
#pragma unroll
      for (int m = 0; m < 4; ++m)
#pragma unroll
        for (int n = 0; n < 4; ++n)
          acc[m][n] = MFMA_BF16(af[m], bfr[n], acc[m][n]);
    }
  }
#pragma unroll
  for (int n = 0; n < 4; ++n) {
    int col = bn * 128 + wcol + n * 16 + lr;
    float bv = bias[col];
#pragma unroll
    for (int m = 0; m < 4; ++m)
#pragma unroll
      for (int i = 0; i < 4; ++i) {
        int row = bm * 128 + wrow + m * 16 + lg * 4 + i;
        float v = acc[m][n][i] + bv;
        if constexpr (sizeof(TO) == 2) {
          C[(size_t)row * N + col] = (TO)f2bf(v);
        } else {
          if (RESID) v += C[(size_t)row * N + col];
          C[(size_t)row * N + col] = v;
        }
      }
  }
}

// ============ fused causal conv(K=4)+silu + headwise q,k,v (register-only) ============
// u bf16 [4096][2048]; writes xcb bf16 [4096][1024], q/k/v bf16 head-major [bh][s][128]
__global__ __launch_bounds__(256) void convhead_kernel(
    const unsigned short* __restrict__ u, const float* __restrict__ cw,
    const float* __restrict__ cb,
    const float* __restrict__ Wq, const float* __restrict__ Wk, const float* __restrict__ Wv,
    unsigned short* __restrict__ xcb, unsigned short* __restrict__ qb,
    unsigned short* __restrict__ kb, unsigned short* __restrict__ vb) {
  int m = blockIdx.x;
  int b = m >> 9, s = m & 511;
  int n = threadIdx.x;  // channels n*4 .. n*4+3
  float xm[4][4];
#pragma unroll
  for (int j = 0; j < 4; ++j) {
    int sp = s - 3 + j;
    if (sp >= 0) {
      unsigned long long raw = *(const unsigned long long*)&u[((size_t)(b * kS + sp)) * (2 * kI) + n * 4];
#pragma unroll
      for (int i = 0; i < 4; ++i) xm[j][i] = bf2f((unsigned short)(raw >> (i * 16)));
    } else {
#pragma unroll
      for (int i = 0; i < 4; ++i) xm[j][i] = 0.f;
    }
  }
  float xc[4];
  unsigned long long xcv = 0;
#pragma unroll
  for (int i = 0; i < 4; ++i) {
    int c = n * 4 + i;
    float acc = cb[c];
#pragma unroll
    for (int j = 0; j < 4; ++j) acc += xm[j][i] * cw[c * 4 + j];
    xc[i] = acc / (1.f + expf(-acc));
    xcv |= (unsigned long long)f2bf(xc[i]) << (i * 16);
  }
  *(unsigned long long*)&xcb[(size_t)m * kI + n * 4] = xcv;
  const float* wq = Wq + n * 16;
  const float* wk = Wk + n * 16;
  const float* wv = Wv + n * 16;
  unsigned long long qv = 0, kv = 0, vv = 0;
#pragma unroll
  for (int o = 0; o < 4; ++o) {
    float aq = 0, ak = 0, av = 0;
#pragma unroll
    for (int i = 0; i < 4; ++i) {
      aq += xc[i] * wq[o * 4 + i];
      ak += xc[i] * wk[o * 4 + i];
      av += xm[3][i] * wv[o * 4 + i];
    }
    qv |= (unsigned long long)f2bf(aq) << (o * 16);
    kv |= (unsigned long long)f2bf(ak) << (o * 16);
    vv |= (unsigned long long)f2bf(av) << (o * 16);
  }
  size_t base = ((size_t)(b * 8 + (n >> 5)) * kS + s) * kDH + (n & 31) * 4;
  *(unsigned long long*)&qb[base] = qv;
  *(unsigned long long*)&kb[base] = kv;
  *(unsigned long long*)&vb[base] = vv;
}

// ======================= gates via MFMA: [64 rows] x [3072] x [16] =======================
__global__ __launch_bounds__(256) void gates_mfma_kernel(
    const unsigned short* __restrict__ qb, const unsigned short* __restrict__ kb,
    const unsigned short* __restrict__ vb, const unsigned short* __restrict__ gWT,
    const float* __restrict__ igb, const float* __restrict__ fgb,
    float* __restrict__ IG, float* __restrict__ FG) {
  int blk = blockIdx.x;
  int b = blk >> 3, s0 = (blk & 7) * 64;
  int tid = threadIdx.x, w = tid >> 6, l = tid & 63;
  int lr = l & 15, lg = l >> 4;
  __shared__ __align__(16) char Ts[16384];  // [64 s][128 k] bf16, RB=256, swizzled
  f32x4 acc = {};
  for (int kc = 0; kc < 24; ++kc) {
    const unsigned short* srcbase;
    if (kc < 8) srcbase = qb + ((size_t)(b * 8 + kc) * kS + s0) * kDH;
    else if (kc < 16) srcbase = kb + ((size_t)(b * 8 + kc - 8) * kS + s0) * kDH;
    else srcbase = vb + ((size_t)(b * 8 + kc - 16) * kS + s0) * kDH;
    __syncthreads();
#pragma unroll
    for (int j = 0; j < 4; ++j) {
      int issue = w * 4 + j;
      int row = issue * 4 + (l >> 4);
      int chunk = (l & 15) ^ (row & 7);
      gload16(srcbase + row * 128 + chunk * 8, Ts + issue * 1024);
    }
    __syncthreads();
#pragma unroll
    for (int kk = 0; kk < 4; ++kk) {
      int arow = w * 16 + lr;
      int ch = (kk * 4 + lg) ^ (arow & 7);
      bf16x8 af = *(const bf16x8*)(Ts + arow * 256 + ch * 16);
      bf16x8 bfv = *(const bf16x8*)(gWT + (size_t)lr * 3072 + kc * 128 + kk * 32 + lg * 8);
      acc = MFMA_BF16(af, bfv, acc);
    }
  }
#pragma unroll
  for (int i = 0; i < 4; ++i) {
    int s = s0 + w * 16 + lg * 4 + i;
    if (lr < 8) IG[((size_t)(b * 8) + lr) * kS + s] = acc[i] + igb[lr];
    else FG[((size_t)(b * 8) + lr - 8) * kS + s] = acc[i] + fgb[lr - 8];
  }
}

// ======================= per-(b,nh) scan: inc, a, pmax =======================
__global__ __launch_bounds__(512) void scan_kernel(
    const float* __restrict__ ig, const float* __restrict__ fg,
    float* __restrict__ inc, float* __restrict__ a, float* __restrict__ pmax) {
  int bh = blockIdx.x;
  int t = threadIdx.x;
  __shared__ float buf[512];
  float x = fg[(size_t)bh * kS + t];
  float lf = fminf(x, 0.f) - log1pf(expf(-fabsf(x)));  // log_sigmoid
  buf[t] = lf;
  __syncthreads();
  for (int off = 1; off < 512; off <<= 1) {
    float p = (t >= off) ? buf[t - off] : 0.f;
    __syncthreads();
    buf[t] += p;
    __syncthreads();
  }
  float inct = buf[t];
  inc[(size_t)bh * kS + t] = inct;
  float av = ig[(size_t)bh * kS + t] - inct;
  a[(size_t)bh * kS + t] = av;
  buf[t] = av;
  __syncthreads();
  for (int off = 1; off < 512; off <<= 1) {
    float p = (t >= off) ? buf[t - off] : -1e30f;
    __syncthreads();
    buf[t] = fmaxf(buf[t], p);
    __syncthreads();
  }
  pmax[(size_t)bh * kS + t] = buf[t];
}

// ======================= V transpose: vb[bh][s][d] -> vt[bh][d][s] (bf16) ================
__global__ __launch_bounds__(256) void tpose_v_kernel(
    const unsigned short* __restrict__ vb, unsigned short* __restrict__ vt) {
  int bh = blockIdx.y, s0 = blockIdx.x * 64;
  __shared__ unsigned short t[64][130];
  int tid = threadIdx.x;
  for (int idx = tid; idx < 64 * 128; idx += 256) {
    int sl = idx >> 7, d = idx & 127;
    t[sl][d] = vb[((size_t)bh * kS + s0 + sl) * kDH + d];
  }
  __syncthreads();
  for (int idx = tid; idx < 64 * 128; idx += 256) {
    int dl = idx >> 6, sl = idx & 63;
    vt[((size_t)bh * kDH + dl) * kS + s0 + sl] = t[sl][dl];
  }
}

// ======================= mLSTM parallel via MFMA + fused mh_norm/skip/gate ===============
// block: (rt 0..7, bh 0..63), 4 waves x 16 rows = 64 Q rows.
__global__ __launch_bounds__(256) void mlstm_mfma_kernel(
    const unsigned short* __restrict__ qb, const unsigned short* __restrict__ kb,
    const unsigned short* __restrict__ vt,
    const float* __restrict__ INC, const float* __restrict__ AV, const float* __restrict__ PM,
    const unsigned short* __restrict__ u, const unsigned short* __restrict__ xcb,
    const float* __restrict__ onw, const float* __restrict__ skw,
    unsigned short* __restrict__ hhb) {
  int rt = blockIdx.x;
  int bh = blockIdx.y;
  int b = bh >> 3, nh = bh & 7;
  int tid = threadIdx.x, w = tid >> 6, l = tid & 63;
  int lr = l & 15, lg = l >> 4;
  __shared__ __align__(16) char Ks[16384];     // [64 s][128 d] bf16, RB=256
  __shared__ __align__(16) char Vs[16384];     // [128 d][64 s] bf16, RB=128
  __shared__ __align__(16) char Ps[4][2048];   // per-wave [16][64] bf16, RB=128

  bf16x8 qf[4];
  int qrow = rt * 64 + w * 16 + lr;
  const unsigned short* qrp = qb + ((size_t)bh * kS + qrow) * kDH + lg * 8;
#pragma unroll
  for (int kk = 0; kk < 4; ++kk) qf[kk] = *(const bf16x8*)(qrp + kk * 32);

  float pm_r[4];
#pragma unroll
  for (int i = 0; i < 4; ++i)
    pm_r[i] = PM[(size_t)bh * kS + rt * 64 + w * 16 + lg * 4 + i];

  f32x4 oacc[8] = {};
  float rsum[4] = {};

  for (int ct = 0; ct <= rt; ++ct) {
    __syncthreads();
    {
      const unsigned short* kbase = kb + ((size_t)bh * kS + ct * 64) * kDH;
#pragma unroll
      for (int j = 0; j < 4; ++j) {
        int issue = w * 4 + j;
        int row = issue * 4 + (l >> 4);
        int chunk = (l & 15) ^ (row & 7);
        gload16(kbase + row * 128 + chunk * 8, Ks + issue * 1024);
      }
    }
    {
      const unsigned short* vbase = vt + (size_t)bh * kDH * kS + ct * 64;
#pragma unroll
      for (int j = 0; j < 4; ++j) {
        int vi = w * 4 + j;
        int row = vi * 8 + (l >> 3);
        int chunk = (l & 7) ^ (row & 7);
        gload16(vbase + (size_t)row * kS + chunk * 8, Vs + vi * 1024);
      }
    }
    __syncthreads();
    f32x4 sacc[4] = {};
#pragma unroll
    for (int n = 0; n < 4; ++n) {
#pragma unroll
      for (int kk = 0; kk < 4; ++kk) {
        int krow = n * 16 + lr;
        int ch = (kk * 4 + lg) ^ (krow & 7);
        bf16x8 kf = *(const bf16x8*)(Ks + krow * 256 + ch * 16);
        sacc[n] = MFMA_BF16(qf[kk], kf, sacc[n]);
      }
    }
#pragma unroll
    for (int n = 0; n < 4; ++n) {
      float av = AV[(size_t)bh * kS + ct * 64 + n * 16 + lr];
      int cg = ct * 64 + n * 16 + lr;
#pragma unroll
      for (int i = 0; i < 4; ++i) {
        int rg = rt * 64 + w * 16 + lg * 4 + i;
        float s = 0.f;
        if (ct < rt || cg <= rg)
          s = sacc[n][i] * 0.08838834764831845f * expf(av - pm_r[i]);
        rsum[i] += s;
        int prow = lg * 4 + i, pcol = n * 16 + lr;
        int byte = prow * 128 + ((((pcol >> 3) ^ (prow & 7))) << 4) + (pcol & 7) * 2;
        *(unsigned short*)(Ps[w] + byte) = f2bf(s);
      }
    }
#pragma unroll
    for (int kk = 0; kk < 2; ++kk) {
      int prow = lr;
      int pch = (kk * 4 + lg) ^ (prow & 7);
      bf16x8 pf = *(const bf16x8*)(Ps[w] + prow * 128 + pch * 16);
#pragma unroll
      for (int nb = 0; nb < 8; ++nb) {
        int vrow = nb * 16 + lr;
        int vch = (kk * 4 + lg) ^ (vrow & 7);
        bf16x8 vf = *(const bf16x8*)(Vs + vrow * 128 + vch * 16);
        oacc[nb] = MFMA_BF16(pf, vf, oacc[nb]);
      }
    }
  }
#pragma unroll
  for (int i = 0; i < 4; ++i)
#pragma unroll
    for (int off = 1; off < 16; off <<= 1) rsum[i] += __shfl_xor(rsum[i], off, 16);
  float ninv[4];
#pragma unroll
  for (int i = 0; i < 4; ++i) {
    int rg = rt * 64 + w * 16 + lg * 4 + i;
    float e0 = expf(-INC[(size_t)bh * kS + rg] - pm_r[i]);
    float nn = fmaxf(fabsf(rsum[i]), e0);
    ninv[i] = 1.f / (nn + 1e-6f);
  }
  // ---- fused mh_norm (LN over DH=128 within 16-lane groups) + skip + output gate ----
  float val[8][4];
  float s1[4] = {}, s2[4] = {};
#pragma unroll
  for (int nb = 0; nb < 8; ++nb)
#pragma unroll
    for (int i = 0; i < 4; ++i) {
      float v = oacc[nb][i] * ninv[i];
      val[nb][i] = v;
      s1[i] += v; s2[i] += v * v;
    }
#pragma unroll
  for (int i = 0; i < 4; ++i) {
#pragma unroll
    for (int off = 1; off < 16; off <<= 1) {
      s1[i] += __shfl_xor(s1[i], off, 16);
      s2[i] += __shfl_xor(s2[i], off, 16);
    }
  }
#pragma unroll
  for (int i = 0; i < 4; ++i) {
    int rg = rt * 64 + w * 16 + lg * 4 + i;
    float mu = s1[i] * (1.f / 128.f);
    float var = s2[i] * (1.f / 128.f) - mu * mu;
    float rstd = rsqrtf(var + 1e-5f);
    size_t rowbase = (size_t)(b * kS + rg);
#pragma unroll
    for (int nb = 0; nb < 8; ++nb) {
      int c = nh * kDH + nb * 16 + lr;
      float nv = (val[nb][i] - mu) * rstd * onw[c];
      float z = bf2f(u[rowbase * (2 * kI) + kI + c]);
      float sz = z / (1.f + expf(-z));
      float xcv = bf2f(xcb[rowbase * kI + c]);
      hhb[rowbase * kI + c] = f2bf((nv + skw[c] * xcv) * sz);
    }
  }
}

// ======================= post-norm + head projection (last 96 rows/batch) =======================
__global__ __launch_bounds__(256) void head_kernel(
    const float* __restrict__ x, const float* __restrict__ pw,
    const float* __restrict__ hW, const float* __restrict__ hb, float* __restrict__ out) {
  int row = blockIdx.x;  // 0..767
  int b = row / kPRED, p = row % kPRED;
  int m = b * kS + (kS - kPRED) + p;
  int tid = threadIdx.x;
  float v0 = x[(size_t)m * kD + tid];
  float v1 = x[(size_t)m * kD + 256 + tid];
  float s1 = v0 + v1, s2 = v0 * v0 + v1 * v1;
#pragma unroll
  for (int o = 1; o < 64; o <<= 1) { s1 += __shfl_xor(s1, o, 64); s2 += __shfl_xor(s2, o, 64); }
  __shared__ float a1[4], a2[4];
  if ((tid & 63) == 0) { a1[tid >> 6] = s1; a2[tid >> 6] = s2; }
  __syncthreads();
  float t1 = a1[0] + a1[1] + a1[2] + a1[3];
  float t2 = a2[0] + a2[1] + a2[2] + a2[3];
  float mu = t1 * (1.f / kD);
  float var = t2 * (1.f / kD) - mu * mu;
  float rs = rsqrtf(var + 1e-5f);
  __shared__ float buf[512];
  buf[tid] = (v0 - mu) * rs * pw[tid];
  buf[256 + tid] = (v1 - mu) * rs * pw[256 + tid];
  __syncthreads();
  float acc[7] = {};
  for (int kk = tid; kk < 512; kk += 256) {
    float g = buf[kk];
#pragma unroll
    for (int n = 0; n < 7; ++n) acc[n] += g * hW[kk * 7 + n];
  }
  __shared__ float red[256 * 9];
#pragma unroll
  for (int n = 0; n < 7; ++n) red[tid * 9 + n] = acc[n];
  __syncthreads();
  for (int off = 128; off >= 1; off >>= 1) {
    if (tid < off) {
#pragma unroll
      for (int n = 0; n < 7; ++n) red[tid * 9 + n] += red[(tid + off) * 9 + n];
    }
    __syncthreads();
  }
  if (tid < 7) out[(size_t)row * 7 + tid] = red[tid] + hb[tid];
}

// ======================= host launch =======================
extern "C" void kernel_launch(void* const* d_in, const int* in_sizes, int n_in,
                              void* d_out, int out_size, void* d_ws, size_t ws_size,
                              hipStream_t stream) {
  const float* x_enc    = (const float*)d_in[0];
  const float* x_mark   = (const float*)d_in[1];
  const float* emb_W    = (const float*)d_in[4];
  const float* emb_b    = (const float*)d_in[5];
  const float* blk_ln_w = (const float*)d_in[6];
  const float* up_W     = (const float*)d_in[7];
  const float* up_b     = (const float*)d_in[8];
  const float* conv_w   = (const float*)d_in[9];
  const float* conv_b   = (const float*)d_in[10];
  const float* Wq       = (const float*)d_in[11];
  const float* Wk       = (const float*)d_in[12];
  const float* Wv       = (const float*)d_in[13];
  const float* ig_W     = (const float*)d_in[14];
  const float* ig_b     = (const float*)d_in[15];
  const float* fg_W     = (const float*)d_in[16];
  const float* fg_b     = (const float*)d_in[17];
  const float* onorm_w  = (const float*)d_in[18];
  const float* skip_w   = (const float*)d_in[19];
  const float* down_W   = (const float*)d_in[20];
  const float* down_b   = (const float*)d_in[21];
  const float* post_w   = (const float*)d_in[22];
  const float* head_W   = (const float*)d_in[23];
  const float* head_b   = (const float*)d_in[24];
  float* out = (float*)d_out;

  char* ws = (char*)d_ws;
  float* X  = (float*)ws;                     ws += (size_t)kM * kD * 4;        // 8 MB
  unsigned short* U    = (unsigned short*)ws; ws += (size_t)kM * 2 * kI * 2;    // 16 MB
  unsigned short* XCb  = (unsigned short*)ws; ws += (size_t)kM * kI * 2;        // 8 MB
  unsigned short* Hb   = (unsigned short*)ws; ws += (size_t)kM * kD * 2;        // 4 MB
  unsigned short* HHb  = (unsigned short*)ws; ws += (size_t)kM * kI * 2;        // 8 MB
  unsigned short* qb   = (unsigned short*)ws; ws += (size_t)kM * kI * 2;        // 8 MB
  unsigned short* kbuf = (unsigned short*)ws; ws += (size_t)kM * kI * 2;        // 8 MB
  unsigned short* vb   = (unsigned short*)ws; ws += (size_t)kM * kI * 2;        // 8 MB
  unsigned short* vt   = (unsigned short*)ws; ws += (size_t)kM * kI * 2;        // 8 MB
  unsigned short* upWT = (unsigned short*)ws; ws += (size_t)kL * 2 * kI * kD * 2; // 8 MB
  unsigned short* dnWT = (unsigned short*)ws; ws += (size_t)kL * kD * kI * 2;   // 4 MB
  unsigned short* gWT  = (unsigned short*)ws; ws += (size_t)kL * 16 * 3072 * 2; // 384 KB
  float* IG  = (float*)ws; ws += (size_t)64 * kS * 4;
  float* FG  = (float*)ws; ws += (size_t)64 * kS * 4;
  float* INC = (float*)ws; ws += (size_t)64 * kS * 4;
  float* AV  = (float*)ws; ws += (size_t)64 * kS * 4;
  float* PM  = (float*)ws; ws += (size_t)64 * kS * 4;

  embed_kernel<<<kM, 256, 0, stream>>>(x_enc, x_mark, emb_W, emb_b, X);
  tpose_w_kernel<<<dim3(32, 8, 4), 256, 0, stream>>>(up_W, upWT, 2 * kI, kD);
  tpose_w_kernel<<<dim3(8, 16, 4), 256, 0, stream>>>(down_W, dnWT, kD, kI);
  tpose_gates_kernel<<<dim3(12, 4), 256, 0, stream>>>(ig_W, fg_W, gWT);

  for (int l = 0; l < kL; ++l) {
    const float* lnw  = blk_ln_w + (size_t)l * kD;
    const float* upbl = up_b + (size_t)l * 2 * kI;
    const float* cwl  = conv_w + (size_t)l * kI * 4;
    const float* cbl  = conv_b + (size_t)l * kI;
    const float* wql  = Wq + (size_t)l * 256 * 16;
    const float* wkl  = Wk + (size_t)l * 256 * 16;
    const float* wvl  = Wv + (size_t)l * 256 * 16;
    const float* igbl = ig_b + (size_t)l * kNH;
    const float* fgbl = fg_b + (size_t)l * kNH;
    const float* onwl = onorm_w + (size_t)l * kI;
    const float* skwl = skip_w + (size_t)l * kI;
    const float* dbl  = down_b + (size_t)l * kD;
    const unsigned short* upWTl = upWT + (size_t)l * 2 * kI * kD;
    const unsigned short* dnWTl = dnWT + (size_t)l * kD * kI;
    const unsigned short* gWTl  = gWT + (size_t)l * 16 * 3072;

    ln_kernel<<<kM, 256, 0, stream>>>(X, lnw, Hb);
    gemm_mfma_kernel<0, unsigned short><<<dim3(16, 32), 256, 0, stream>>>(
        Hb, upWTl, upbl, U, 2 * kI, kD);
    convhead_kernel<<<kM, 256, 0, stream>>>(U, cwl, cbl, wql, wkl, wvl, XCb, qb, kbuf, vb);
    gates_mfma_kernel<<<64, 256, 0, stream>>>(qb, kbuf, vb, gWTl, igbl, fgbl, IG, FG);
    scan_kernel<<<64, 512, 0, stream>>>(IG, FG, INC, AV, PM);
    tpose_v_kernel<<<dim3(8, 64), 256, 0, stream>>>(vb, vt);
    mlstm_mfma_kernel<<<dim3(8, 64), 256, 0, stream>>>(
        qb, kbuf, vt, INC, AV, PM, U, XCb, onwl, skwl, HHb);
    gemm_mfma_kernel<1, float><<<dim3(4, 32), 256, 0, stream>>>(
        HHb, dnWTl, dbl, X, kD, kI);
  }

  head_kernel<<<kB * kPRED, 256, 0, stream>>>(X, post_w, head_W, head_b, out);
}

// Round 4
// 580.036 us; speedup vs baseline: 3.9280x; 1.1203x over previous
//
#include <hip/hip_runtime.h>
#include <math.h>

// ---- dims ----
static constexpr int kB = 8, kS = 512;
static constexpr int kD = 512, kI = 1024, kNH = 8, kDH = 128;
static constexpr int kL = 4, kPRED = 96, kCOUT = 7;
static constexpr int kM = kB * kS; // 4096 rows

typedef __bf16 bf16x8 __attribute__((ext_vector_type(8)));
typedef float f32x4 __attribute__((ext_vector_type(4)));

#define MFMA_BF16(a, b, c) __builtin_amdgcn_mfma_f32_16x16x32_bf16((a), (b), (c), 0, 0, 0)

typedef __attribute__((address_space(1))) const unsigned char* as1cp;
typedef __attribute__((address_space(3))) unsigned char* as3p;
__device__ __forceinline__ void gload16(const void* g, void* l) {
  __builtin_amdgcn_global_load_lds((as1cp)g, (as3p)l, 16, 0, 0);
}

__device__ __forceinline__ unsigned short f2bf(float f) {
  union { float f; unsigned u; } v; v.f = f;
  unsigned r = v.u + 0x7fffu + ((v.u >> 16) & 1u);
  return (unsigned short)(r >> 16);
}
__device__ __forceinline__ float bf2f(unsigned short h) {
  union { unsigned u; float f; } v; v.u = (unsigned)h << 16; return v.f;
}

// ======================= embedding =======================
__global__ __launch_bounds__(256) void embed_kernel(
    const float* __restrict__ xe, const float* __restrict__ xme,
    const float* __restrict__ W, const float* __restrict__ bias,
    float* __restrict__ x) {
  int m = blockIdx.x;
  int tid = threadIdx.x;
  __shared__ float f[11];
  if (tid < 7) f[tid] = xe[m * 7 + tid];
  else if (tid < 11) f[tid] = xme[m * 4 + (tid - 7)];
  __syncthreads();
  for (int d = tid; d < kD; d += 256) {
    float acc = bias[d];
#pragma unroll
    for (int e = 0; e < 11; ++e) acc += f[e] * W[e * kD + d];
    x[(size_t)m * kD + d] = acc;
  }
}

// ======================= layernorm (D=512, scale only) -> bf16 =======================
__global__ __launch_bounds__(256) void ln_kernel(
    const float* __restrict__ x, const float* __restrict__ w, unsigned short* __restrict__ h) {
  int m = blockIdx.x, tid = threadIdx.x;
  float v0 = x[(size_t)m * kD + tid];
  float v1 = x[(size_t)m * kD + 256 + tid];
  float s1 = v0 + v1, s2 = v0 * v0 + v1 * v1;
#pragma unroll
  for (int o = 1; o < 64; o <<= 1) { s1 += __shfl_xor(s1, o, 64); s2 += __shfl_xor(s2, o, 64); }
  __shared__ float a1[4], a2[4];
  if ((tid & 63) == 0) { a1[tid >> 6] = s1; a2[tid >> 6] = s2; }
  __syncthreads();
  float t1 = a1[0] + a1[1] + a1[2] + a1[3];
  float t2 = a2[0] + a2[1] + a2[2] + a2[3];
  float mu = t1 * (1.f / kD);
  float var = t2 * (1.f / kD) - mu * mu;
  float rs = rsqrtf(var + 1e-5f);
  h[(size_t)m * kD + tid] = f2bf((v0 - mu) * rs * w[tid]);
  h[(size_t)m * kD + 256 + tid] = f2bf((v1 - mu) * rs * w[256 + tid]);
}

// ============ weight transpose+cast (all layers): W[l][Kd][N] f32 -> WT[l][N][Kd] bf16 ====
__global__ __launch_bounds__(256) void tpose_w_kernel(
    const float* __restrict__ W, unsigned short* __restrict__ WT, int N, int Kd) {
  int l = blockIdx.z;
  const float* Wl = W + (size_t)l * N * Kd;
  unsigned short* WTl = WT + (size_t)l * N * Kd;
  int n0 = blockIdx.x * 64, k0 = blockIdx.y * 64;
  __shared__ float t[64][65];
  int tid = threadIdx.x;
  for (int idx = tid; idx < 4096; idx += 256) {
    int r = idx >> 6, c = idx & 63;
    t[r][c] = Wl[(size_t)(k0 + r) * N + n0 + c];
  }
  __syncthreads();
  for (int idx = tid; idx < 4096; idx += 256) {
    int r = idx >> 6, c = idx & 63;
    WTl[(size_t)(n0 + r) * Kd + k0 + c] = f2bf(t[c][r]);
  }
}

// ===== gate weight transpose (all layers): [l][3072][8]x2 -> gWT[l][16][3072] bf16 ======
__global__ __launch_bounds__(256) void tpose_gates_kernel(
    const float* __restrict__ igW, const float* __restrict__ fgW,
    unsigned short* __restrict__ gWT) {
  int l = blockIdx.y;
  int k = blockIdx.x * 256 + threadIdx.x;
  const float* igl = igW + (size_t)l * 3072 * 8;
  const float* fgl = fgW + (size_t)l * 3072 * 8;
  unsigned short* gl = gWT + (size_t)l * 16 * 3072;
#pragma unroll
  for (int h = 0; h < 8; ++h) {
    gl[(size_t)h * 3072 + k] = f2bf(igl[(size_t)k * 8 + h]);
    gl[(size_t)(8 + h) * 3072 + k] = f2bf(fgl[(size_t)k * 8 + h]);
  }
}

// ======================= bf16 MFMA GEMM: C[M,N] = A[M,Kd] @ BT[N,Kd]^T + bias (+C) ========
template <int RESID, typename TO>
__global__ __launch_bounds__(256) void gemm_mfma_kernel(
    const unsigned short* __restrict__ A, const unsigned short* __restrict__ BT,
    const float* __restrict__ bias, TO* __restrict__ C, int N, int Kd) {
  __shared__ __align__(16) char As[16384];
  __shared__ __align__(16) char Bs[16384];
  int tid = threadIdx.x, w = tid >> 6, l = tid & 63;
  int lr = l & 15, lg = l >> 4;
  int bm = blockIdx.y, bn = blockIdx.x;
  int wrow = (w >> 1) * 64, wcol = (w & 1) * 64;
  f32x4 acc[4][4] = {};
  for (int kt = 0; kt < Kd; kt += 64) {
    __syncthreads();
#pragma unroll
    for (int j = 0; j < 8; ++j) {
      int g = w * 8 + j;
      bool isA = g < 16;
      int ii = isA ? g : g - 16;
      int row = ii * 8 + (l >> 3);
      int chunk = (l & 7) ^ (row & 7);
      const unsigned short* src = isA
          ? A + ((size_t)(bm * 128 + row) * Kd + kt) + chunk * 8
          : BT + ((size_t)(bn * 128 + row) * Kd + kt) + chunk * 8;
      char* dst = (isA ? As : Bs) + ii * 1024;
      gload16(src, dst);
    }
    __syncthreads();
#pragma unroll
    for (int kk = 0; kk < 2; ++kk) {
      bf16x8 af[4], bfr[4];
#pragma unroll
      for (int m = 0; m < 4; ++m) {
        int row = wrow + m * 16 + lr;
        int ch = (kk * 4 + lg) ^ (row & 7);
        af[m] = *(const bf16x8*)(As + row * 128 + ch * 16);
      }
#pragma unroll
      for (int n = 0; n < 4; ++n) {
        int row = wcol + n * 16 + lr;
        int ch = (kk * 4 + lg) ^ (row & 7);
        bfr[n] = *(const bf16x8*)(Bs + row * 128 + ch * 16);
      }
#pragma unroll
      for (int m = 0; m < 4; ++m)
#pragma unroll
        for (int n = 0; n < 4; ++n)
          acc[m][n] = MFMA_BF16(af[m], bfr[n], acc[m][n]);
    }
  }
#pragma unroll
  for (int n = 0; n < 4; ++n) {
    int col = bn * 128 + wcol + n * 16 + lr;
    float bv = bias[col];
#pragma unroll
    for (int m = 0; m < 4; ++m)
#pragma unroll
      for (int i = 0; i < 4; ++i) {
        int row = bm * 128 + wrow + m * 16 + lg * 4 + i;
        float v = acc[m][n][i] + bv;
        if constexpr (sizeof(TO) == 2) {
          C[(size_t)row * N + col] = (TO)f2bf(v);
        } else {
          if (RESID) v += C[(size_t)row * N + col];
          C[(size_t)row * N + col] = v;
        }
      }
  }
}

// ============ fused causal conv(K=4)+silu + headwise q,k,v (register-only) ============
__global__ __launch_bounds__(256) void convhead_kernel(
    const unsigned short* __restrict__ u, const float* __restrict__ cw,
    const float* __restrict__ cb,
    const float* __restrict__ Wq, const float* __restrict__ Wk, const float* __restrict__ Wv,
    unsigned short* __restrict__ xcb, unsigned short* __restrict__ qb,
    unsigned short* __restrict__ kb, unsigned short* __restrict__ vb) {
  int m = blockIdx.x;
  int b = m >> 9, s = m & 511;
  int n = threadIdx.x;  // channels n*4 .. n*4+3
  float xm[4][4];
#pragma unroll
  for (int j = 0; j < 4; ++j) {
    int sp = s - 3 + j;
    if (sp >= 0) {
      unsigned long long raw = *(const unsigned long long*)&u[((size_t)(b * kS + sp)) * (2 * kI) + n * 4];
#pragma unroll
      for (int i = 0; i < 4; ++i) xm[j][i] = bf2f((unsigned short)(raw >> (i * 16)));
    } else {
#pragma unroll
      for (int i = 0; i < 4; ++i) xm[j][i] = 0.f;
    }
  }
  float xc[4];
  unsigned long long xcv = 0;
#pragma unroll
  for (int i = 0; i < 4; ++i) {
    int c = n * 4 + i;
    float acc = cb[c];
#pragma unroll
    for (int j = 0; j < 4; ++j) acc += xm[j][i] * cw[c * 4 + j];
    xc[i] = acc / (1.f + __expf(-acc));
    xcv |= (unsigned long long)f2bf(xc[i]) << (i * 16);
  }
  *(unsigned long long*)&xcb[(size_t)m * kI + n * 4] = xcv;
  const float* wq = Wq + n * 16;
  const float* wk = Wk + n * 16;
  const float* wv = Wv + n * 16;
  unsigned long long qv = 0, kv = 0, vv = 0;
#pragma unroll
  for (int o = 0; o < 4; ++o) {
    float aq = 0, ak = 0, av = 0;
#pragma unroll
    for (int i = 0; i < 4; ++i) {
      aq += xc[i] * wq[o * 4 + i];
      ak += xc[i] * wk[o * 4 + i];
      av += xm[3][i] * wv[o * 4 + i];
    }
    qv |= (unsigned long long)f2bf(aq) << (o * 16);
    kv |= (unsigned long long)f2bf(ak) << (o * 16);
    vv |= (unsigned long long)f2bf(av) << (o * 16);
  }
  size_t base = ((size_t)(b * 8 + (n >> 5)) * kS + s) * kDH + (n & 31) * 4;
  *(unsigned long long*)&qb[base] = qv;
  *(unsigned long long*)&kb[base] = kv;
  *(unsigned long long*)&vb[base] = vv;
}

// ============ gates via MFMA, split by source: partial[src] = rows @ W_src ============
// grid (64, 3): 64 (b,s0) row-tiles x 3 sources (q,k,v). Partials summed in scan_kernel.
__global__ __launch_bounds__(256) void gates_mfma_kernel(
    const unsigned short* __restrict__ qb, const unsigned short* __restrict__ kb,
    const unsigned short* __restrict__ vb, const unsigned short* __restrict__ gWT,
    float* __restrict__ IGp, float* __restrict__ FGp) {
  int blk = blockIdx.x;
  int src = blockIdx.y;
  int b = blk >> 3, s0 = (blk & 7) * 64;
  int tid = threadIdx.x, w = tid >> 6, l = tid & 63;
  int lr = l & 15, lg = l >> 4;
  __shared__ __align__(16) char Ts[16384];  // [64 s][128 k] bf16, RB=256, swizzled
  const unsigned short* srcb = (src == 0) ? qb : (src == 1) ? kb : vb;
  f32x4 acc = {};
  for (int kc8 = 0; kc8 < 8; ++kc8) {
    const unsigned short* srcbase = srcb + ((size_t)(b * 8 + kc8) * kS + s0) * kDH;
    __syncthreads();
#pragma unroll
    for (int j = 0; j < 4; ++j) {
      int issue = w * 4 + j;
      int row = issue * 4 + (l >> 4);
      int chunk = (l & 15) ^ (row & 7);
      gload16(srcbase + row * 128 + chunk * 8, Ts + issue * 1024);
    }
    __syncthreads();
#pragma unroll
    for (int kk = 0; kk < 4; ++kk) {
      int arow = w * 16 + lr;
      int ch = (kk * 4 + lg) ^ (arow & 7);
      bf16x8 af = *(const bf16x8*)(Ts + arow * 256 + ch * 16);
      bf16x8 bfv = *(const bf16x8*)(gWT + (size_t)lr * 3072 + (src * 8 + kc8) * 128 + kk * 32 + lg * 8);
      acc = MFMA_BF16(af, bfv, acc);
    }
  }
  float* IGo = IGp + (size_t)src * 64 * kS;
  float* FGo = FGp + (size_t)src * 64 * kS;
#pragma unroll
  for (int i = 0; i < 4; ++i) {
    int s = s0 + w * 16 + lg * 4 + i;
    if (lr < 8) IGo[((size_t)(b * 8) + lr) * kS + s] = acc[i];
    else FGo[((size_t)(b * 8) + lr - 8) * kS + s] = acc[i];
  }
}

// ======================= per-(b,nh) scan: sum partials + bias, inc, a, pmax ==============
__global__ __launch_bounds__(512) void scan_kernel(
    const float* __restrict__ IGp, const float* __restrict__ FGp,
    const float* __restrict__ igb, const float* __restrict__ fgb,
    float* __restrict__ inc, float* __restrict__ a, float* __restrict__ pmax) {
  int bh = blockIdx.x;
  int h = bh & 7;
  int t = threadIdx.x;
  const size_t ss = (size_t)64 * kS;
  size_t o = (size_t)bh * kS + t;
  float igv = IGp[o] + IGp[ss + o] + IGp[2 * ss + o] + igb[h];
  float fgv = FGp[o] + FGp[ss + o] + FGp[2 * ss + o] + fgb[h];
  __shared__ float buf[512];
  float lf = fminf(fgv, 0.f) - log1pf(expf(-fabsf(fgv)));  // log_sigmoid
  buf[t] = lf;
  __syncthreads();
  for (int off = 1; off < 512; off <<= 1) {
    float p = (t >= off) ? buf[t - off] : 0.f;
    __syncthreads();
    buf[t] += p;
    __syncthreads();
  }
  float inct = buf[t];
  inc[o] = inct;
  float av = igv - inct;
  a[o] = av;
  buf[t] = av;
  __syncthreads();
  for (int off = 1; off < 512; off <<= 1) {
    float p = (t >= off) ? buf[t - off] : -1e30f;
    __syncthreads();
    buf[t] = fmaxf(buf[t], p);
    __syncthreads();
  }
  pmax[o] = buf[t];
}

// ======================= V transpose: vb[bh][s][d] -> vt[bh][d][s] (bf16) ================
__global__ __launch_bounds__(256) void tpose_v_kernel(
    const unsigned short* __restrict__ vb, unsigned short* __restrict__ vt) {
  int bh = blockIdx.y, s0 = blockIdx.x * 64;
  __shared__ unsigned short t[64][130];
  int tid = threadIdx.x;
  for (int idx = tid; idx < 64 * 128; idx += 256) {
    int sl = idx >> 7, d = idx & 127;
    t[sl][d] = vb[((size_t)bh * kS + s0 + sl) * kDH + d];
  }
  __syncthreads();
  for (int idx = tid; idx < 64 * 128; idx += 256) {
    int dl = idx >> 6, sl = idx & 63;
    vt[((size_t)bh * kDH + dl) * kS + s0 + sl] = t[sl][dl];
  }
}

// ======================= mLSTM parallel via MFMA + fused mh_norm/skip/gate ===============
// 1-D grid 512, XCD-swizzled: bh = (id&7)*8 + (id>>6)  (each XCD sees only 8 heads),
// rt = 7 - ((id>>3)&7) (big tiles first). 4 waves x 16 rows = 64 Q rows.
__global__ __launch_bounds__(256) void mlstm_mfma_kernel(
    const unsigned short* __restrict__ qb, const unsigned short* __restrict__ kb,
    const unsigned short* __restrict__ vt,
    const float* __restrict__ INC, const float* __restrict__ AV, const float* __restrict__ PM,
    const unsigned short* __restrict__ u, const unsigned short* __restrict__ xcb,
    const float* __restrict__ onw, const float* __restrict__ skw,
    unsigned short* __restrict__ hhb) {
  int id = blockIdx.x;
  int bh = (id & 7) * 8 + (id >> 6);
  int rt = 7 - ((id >> 3) & 7);
  int b = bh >> 3, nh = bh & 7;
  int tid = threadIdx.x, w = tid >> 6, l = tid & 63;
  int lr = l & 15, lg = l >> 4;
  __shared__ __align__(16) char Ks[16384];     // [64 s][128 d] bf16, RB=256
  __shared__ __align__(16) char Vs[16384];     // [128 d][64 s] bf16, RB=128
  __shared__ __align__(16) char Ps[4][2048];   // per-wave [16][64] bf16, RB=128

  bf16x8 qf[4];
  int qrow = rt * 64 + w * 16 + lr;
  const unsigned short* qrp = qb + ((size_t)bh * kS + qrow) * kDH + lg * 8;
#pragma unroll
  for (int kk = 0; kk < 4; ++kk) qf[kk] = *(const bf16x8*)(qrp + kk * 32);

  float pm_r[4];
#pragma unroll
  for (int i = 0; i < 4; ++i)
    pm_r[i] = PM[(size_t)bh * kS + rt * 64 + w * 16 + lg * 4 + i];

  f32x4 oacc[8] = {};
  float rsum[4] = {};

  for (int ct = 0; ct <= rt; ++ct) {
    __syncthreads();
    {
      const unsigned short* kbase = kb + ((size_t)bh * kS + ct * 64) * kDH;
#pragma unroll
      for (int j = 0; j < 4; ++j) {
        int issue = w * 4 + j;
        int row = issue * 4 + (l >> 4);
        int chunk = (l & 15) ^ (row & 7);
        gload16(kbase + row * 128 + chunk * 8, Ks + issue * 1024);
      }
    }
    {
      const unsigned short* vbase = vt + (size_t)bh * kDH * kS + ct * 64;
#pragma unroll
      for (int j = 0; j < 4; ++j) {
        int vi = w * 4 + j;
        int row = vi * 8 + (l >> 3);
        int chunk = (l & 7) ^ (row & 7);
        gload16(vbase + (size_t)row * kS + chunk * 8, Vs + vi * 1024);
      }
    }
    __syncthreads();
    f32x4 sacc[4] = {};
#pragma unroll
    for (int n = 0; n < 4; ++n) {
#pragma unroll
      for (int kk = 0; kk < 4; ++kk) {
        int krow = n * 16 + lr;
        int ch = (kk * 4 + lg) ^ (krow & 7);
        bf16x8 kf = *(const bf16x8*)(Ks + krow * 256 + ch * 16);
        sacc[n] = MFMA_BF16(qf[kk], kf, sacc[n]);
      }
    }
#pragma unroll
    for (int n = 0; n < 4; ++n) {
      float av = AV[(size_t)bh * kS + ct * 64 + n * 16 + lr];
      int cg = ct * 64 + n * 16 + lr;
#pragma unroll
      for (int i = 0; i < 4; ++i) {
        int rg = rt * 64 + w * 16 + lg * 4 + i;
        float s = 0.f;
        if (ct < rt || cg <= rg)
          s = sacc[n][i] * 0.08838834764831845f * __expf(av - pm_r[i]);
        rsum[i] += s;
        int prow = lg * 4 + i, pcol = n * 16 + lr;
        int byte = prow * 128 + ((((pcol >> 3) ^ (prow & 7))) << 4) + (pcol & 7) * 2;
        *(unsigned short*)(Ps[w] + byte) = f2bf(s);
      }
    }
#pragma unroll
    for (int kk = 0; kk < 2; ++kk) {
      int prow = lr;
      int pch = (kk * 4 + lg) ^ (prow & 7);
      bf16x8 pf = *(const bf16x8*)(Ps[w] + prow * 128 + pch * 16);
#pragma unroll
      for (int nb = 0; nb < 8; ++nb) {
        int vrow = nb * 16 + lr;
        int vch = (kk * 4 + lg) ^ (vrow & 7);
        bf16x8 vf = *(const bf16x8*)(Vs + vrow * 128 + vch * 16);
        oacc[nb] = MFMA_BF16(pf, vf, oacc[nb]);
      }
    }
  }
#pragma unroll
  for (int i = 0; i < 4; ++i)
#pragma unroll
    for (int off = 1; off < 16; off <<= 1) rsum[i] += __shfl_xor(rsum[i], off, 16);
  float ninv[4];
#pragma unroll
  for (int i = 0; i < 4; ++i) {
    int rg = rt * 64 + w * 16 + lg * 4 + i;
    float e0 = __expf(-INC[(size_t)bh * kS + rg] - pm_r[i]);
    float nn = fmaxf(fabsf(rsum[i]), e0);
    ninv[i] = 1.f / (nn + 1e-6f);
  }
  // ---- fused mh_norm (LN over DH=128 within 16-lane groups) + skip + output gate ----
  float val[8][4];
  float s1[4] = {}, s2[4] = {};
#pragma unroll
  for (int nb = 0; nb < 8; ++nb)
#pragma unroll
    for (int i = 0; i < 4; ++i) {
      float v = oacc[nb][i] * ninv[i];
      val[nb][i] = v;
      s1[i] += v; s2[i] += v * v;
    }
#pragma unroll
  for (int i = 0; i < 4; ++i) {
#pragma unroll
    for (int off = 1; off < 16; off <<= 1) {
      s1[i] += __shfl_xor(s1[i], off, 16);
      s2[i] += __shfl_xor(s2[i], off, 16);
    }
  }
#pragma unroll
  for (int i = 0; i < 4; ++i) {
    int rg = rt * 64 + w * 16 + lg * 4 + i;
    float mu = s1[i] * (1.f / 128.f);
    float var = s2[i] * (1.f / 128.f) - mu * mu;
    float rstd = rsqrtf(var + 1e-5f);
    size_t rowbase = (size_t)(b * kS + rg);
#pragma unroll
    for (int nb = 0; nb < 8; ++nb) {
      int c = nh * kDH + nb * 16 + lr;
      float nv = (val[nb][i] - mu) * rstd * onw[c];
      float z = bf2f(u[rowbase * (2 * kI) + kI + c]);
      float sz = z / (1.f + __expf(-z));
      float xcv = bf2f(xcb[rowbase * kI + c]);
      hhb[rowbase * kI + c] = f2bf((nv + skw[c] * xcv) * sz);
    }
  }
}

// ======================= post-norm + head projection (last 96 rows/batch) =======================
__global__ __launch_bounds__(256) void head_kernel(
    const float* __restrict__ x, const float* __restrict__ pw,
    const float* __restrict__ hW, const float* __restrict__ hb, float* __restrict__ out) {
  int row = blockIdx.x;  // 0..767
  int b = row / kPRED, p = row % kPRED;
  int m = b * kS + (kS - kPRED) + p;
  int tid = threadIdx.x;
  float v0 = x[(size_t)m * kD + tid];
  float v1 = x[(size_t)m * kD + 256 + tid];
  float s1 = v0 + v1, s2 = v0 * v0 + v1 * v1;
#pragma unroll
  for (int o = 1; o < 64; o <<= 1) { s1 += __shfl_xor(s1, o, 64); s2 += __shfl_xor(s2, o, 64); }
  __shared__ float a1[4], a2[4];
  if ((tid & 63) == 0) { a1[tid >> 6] = s1; a2[tid >> 6] = s2; }
  __syncthreads();
  float t1 = a1[0] + a1[1] + a1[2] + a1[3];
  float t2 = a2[0] + a2[1] + a2[2] + a2[3];
  float mu = t1 * (1.f / kD);
  float var = t2 * (1.f / kD) - mu * mu;
  float rs = rsqrtf(var + 1e-5f);
  __shared__ float buf[512];
  buf[tid] = (v0 - mu) * rs * pw[tid];
  buf[256 + tid] = (v1 - mu) * rs * pw[256 + tid];
  __syncthreads();
  float acc[7] = {};
  for (int kk = tid; kk < 512; kk += 256) {
    float g = buf[kk];
#pragma unroll
    for (int n = 0; n < 7; ++n) acc[n] += g * hW[kk * 7 + n];
  }
  __shared__ float red[256 * 9];
#pragma unroll
  for (int n = 0; n < 7; ++n) red[tid * 9 + n] = acc[n];
  __syncthreads();
  for (int off = 128; off >= 1; off >>= 1) {
    if (tid < off) {
#pragma unroll
      for (int n = 0; n < 7; ++n) red[tid * 9 + n] += red[(tid + off) * 9 + n];
    }
    __syncthreads();
  }
  if (tid < 7) out[(size_t)row * 7 + tid] = red[tid] + hb[tid];
}

// ======================= host launch =======================
extern "C" void kernel_launch(void* const* d_in, const int* in_sizes, int n_in,
                              void* d_out, int out_size, void* d_ws, size_t ws_size,
                              hipStream_t stream) {
  const float* x_enc    = (const float*)d_in[0];
  const float* x_mark   = (const float*)d_in[1];
  const float* emb_W    = (const float*)d_in[4];
  const float* emb_b    = (const float*)d_in[5];
  const float* blk_ln_w = (const float*)d_in[6];
  const float* up_W     = (const float*)d_in[7];
  const float* up_b     = (const float*)d_in[8];
  const float* conv_w   = (const float*)d_in[9];
  const float* conv_b   = (const float*)d_in[10];
  const float* Wq       = (const float*)d_in[11];
  const float* Wk       = (const float*)d_in[12];
  const float* Wv       = (const float*)d_in[13];
  const float* ig_W     = (const float*)d_in[14];
  const float* ig_b     = (const float*)d_in[15];
  const float* fg_W     = (const float*)d_in[16];
  const float* fg_b     = (const float*)d_in[17];
  const float* onorm_w  = (const float*)d_in[18];
  const float* skip_w   = (const float*)d_in[19];
  const float* down_W   = (const float*)d_in[20];
  const float* down_b   = (const float*)d_in[21];
  const float* post_w   = (const float*)d_in[22];
  const float* head_W   = (const float*)d_in[23];
  const float* head_b   = (const float*)d_in[24];
  float* out = (float*)d_out;

  char* ws = (char*)d_ws;
  float* X  = (float*)ws;                     ws += (size_t)kM * kD * 4;        // 8 MB
  unsigned short* U    = (unsigned short*)ws; ws += (size_t)kM * 2 * kI * 2;    // 16 MB
  unsigned short* XCb  = (unsigned short*)ws; ws += (size_t)kM * kI * 2;        // 8 MB
  unsigned short* Hb   = (unsigned short*)ws; ws += (size_t)kM * kD * 2;        // 4 MB
  unsigned short* HHb  = (unsigned short*)ws; ws += (size_t)kM * kI * 2;        // 8 MB
  unsigned short* qb   = (unsigned short*)ws; ws += (size_t)kM * kI * 2;        // 8 MB
  unsigned short* kbuf = (unsigned short*)ws; ws += (size_t)kM * kI * 2;        // 8 MB
  unsigned short* vb   = (unsigned short*)ws; ws += (size_t)kM * kI * 2;        // 8 MB
  unsigned short* vt   = (unsigned short*)ws; ws += (size_t)kM * kI * 2;        // 8 MB
  unsigned short* upWT = (unsigned short*)ws; ws += (size_t)kL * 2 * kI * kD * 2; // 8 MB
  unsigned short* dnWT = (unsigned short*)ws; ws += (size_t)kL * kD * kI * 2;   // 4 MB
  unsigned short* gWT  = (unsigned short*)ws; ws += (size_t)kL * 16 * 3072 * 2; // 384 KB
  float* IGp = (float*)ws; ws += (size_t)3 * 64 * kS * 4;
  float* FGp = (float*)ws; ws += (size_t)3 * 64 * kS * 4;
  float* INC = (float*)ws; ws += (size_t)64 * kS * 4;
  float* AV  = (float*)ws; ws += (size_t)64 * kS * 4;
  float* PM  = (float*)ws; ws += (size_t)64 * kS * 4;

  embed_kernel<<<kM, 256, 0, stream>>>(x_enc, x_mark, emb_W, emb_b, X);
  tpose_w_kernel<<<dim3(32, 8, 4), 256, 0, stream>>>(up_W, upWT, 2 * kI, kD);
  tpose_w_kernel<<<dim3(8, 16, 4), 256, 0, stream>>>(down_W, dnWT, kD, kI);
  tpose_gates_kernel<<<dim3(12, 4), 256, 0, stream>>>(ig_W, fg_W, gWT);

  for (int l = 0; l < kL; ++l) {
    const float* lnw  = blk_ln_w + (size_t)l * kD;
    const float* upbl = up_b + (size_t)l * 2 * kI;
    const float* cwl  = conv_w + (size_t)l * kI * 4;
    const float* cbl  = conv_b + (size_t)l * kI;
    const float* wql  = Wq + (size_t)l * 256 * 16;
    const float* wkl  = Wk + (size_t)l * 256 * 16;
    const float* wvl  = Wv + (size_t)l * 256 * 16;
    const float* igbl = ig_b + (size_t)l * kNH;
    const float* fgbl = fg_b + (size_t)l * kNH;
    const float* onwl = onorm_w + (size_t)l * kI;
    const float* skwl = skip_w + (size_t)l * kI;
    const float* dbl  = down_b + (size_t)l * kD;
    const unsigned short* upWTl = upWT + (size_t)l * 2 * kI * kD;
    const unsigned short* dnWTl = dnWT + (size_t)l * kD * kI;
    const unsigned short* gWTl  = gWT + (size_t)l * 16 * 3072;

    ln_kernel<<<kM, 256, 0, stream>>>(X, lnw, Hb);
    gemm_mfma_kernel<0, unsigned short><<<dim3(16, 32), 256, 0, stream>>>(
        Hb, upWTl, upbl, U, 2 * kI, kD);
    convhead_kernel<<<kM, 256, 0, stream>>>(U, cwl, cbl, wql, wkl, wvl, XCb, qb, kbuf, vb);
    gates_mfma_kernel<<<dim3(64, 3), 256, 0, stream>>>(qb, kbuf, vb, gWTl, IGp, FGp);
    scan_kernel<<<64, 512, 0, stream>>>(IGp, FGp, igbl, fgbl, INC, AV, PM);
    tpose_v_kernel<<<dim3(8, 64), 256, 0, stream>>>(vb, vt);
    mlstm_mfma_kernel<<<512, 256, 0, stream>>>(
        qb, kbuf, vt, INC, AV, PM, U, XCb, onwl, skwl, HHb);
    gemm_mfma_kernel<1, float><<<dim3(4, 32), 256, 0, stream>>>(
        HHb, dnWTl, dbl, X, kD, kI);
  }

  head_kernel<<<kB * kPRED, 256, 0, stream>>>(X, post_w, head_W, head_b, out);
}

// Round 5
// 561.085 us; speedup vs baseline: 4.0607x; 1.0338x over previous
//
#include <hip/hip_runtime.h>
#include <math.h>

// ---- dims ----
static constexpr int kB = 8, kS = 512;
static constexpr int kD = 512, kI = 1024, kNH = 8, kDH = 128;
static constexpr int kL = 4, kPRED = 96, kCOUT = 7;
static constexpr int kM = kB * kS; // 4096 rows

typedef __bf16 bf16x8 __attribute__((ext_vector_type(8)));
typedef float f32x4 __attribute__((ext_vector_type(4)));

#define MFMA_BF16(a, b, c) __builtin_amdgcn_mfma_f32_16x16x32_bf16((a), (b), (c), 0, 0, 0)

typedef __attribute__((address_space(1))) const unsigned char* as1cp;
typedef __attribute__((address_space(3))) unsigned char* as3p;
__device__ __forceinline__ void gload16(const void* g, void* l) {
  __builtin_amdgcn_global_load_lds((as1cp)g, (as3p)l, 16, 0, 0);
}

__device__ __forceinline__ unsigned short f2bf(float f) {
  union { float f; unsigned u; } v; v.f = f;
  unsigned r = v.u + 0x7fffu + ((v.u >> 16) & 1u);
  return (unsigned short)(r >> 16);
}
__device__ __forceinline__ float bf2f(unsigned short h) {
  union { unsigned u; float f; } v; v.u = (unsigned)h << 16; return v.f;
}

// ======================= embedding =======================
__global__ __launch_bounds__(256) void embed_kernel(
    const float* __restrict__ xe, const float* __restrict__ xme,
    const float* __restrict__ W, const float* __restrict__ bias,
    float* __restrict__ x) {
  int m = blockIdx.x;
  int tid = threadIdx.x;
  __shared__ float f[11];
  if (tid < 7) f[tid] = xe[m * 7 + tid];
  else if (tid < 11) f[tid] = xme[m * 4 + (tid - 7)];
  __syncthreads();
  for (int d = tid; d < kD; d += 256) {
    float acc = bias[d];
#pragma unroll
    for (int e = 0; e < 11; ++e) acc += f[e] * W[e * kD + d];
    x[(size_t)m * kD + d] = acc;
  }
}

// ======================= layernorm (D=512, scale only) -> bf16 =======================
__global__ __launch_bounds__(256) void ln_kernel(
    const float* __restrict__ x, const float* __restrict__ w, unsigned short* __restrict__ h) {
  int m = blockIdx.x, tid = threadIdx.x;
  float v0 = x[(size_t)m * kD + tid];
  float v1 = x[(size_t)m * kD + 256 + tid];
  float s1 = v0 + v1, s2 = v0 * v0 + v1 * v1;
#pragma unroll
  for (int o = 1; o < 64; o <<= 1) { s1 += __shfl_xor(s1, o, 64); s2 += __shfl_xor(s2, o, 64); }
  __shared__ float a1[4], a2[4];
  if ((tid & 63) == 0) { a1[tid >> 6] = s1; a2[tid >> 6] = s2; }
  __syncthreads();
  float t1 = a1[0] + a1[1] + a1[2] + a1[3];
  float t2 = a2[0] + a2[1] + a2[2] + a2[3];
  float mu = t1 * (1.f / kD);
  float var = t2 * (1.f / kD) - mu * mu;
  float rs = rsqrtf(var + 1e-5f);
  h[(size_t)m * kD + tid] = f2bf((v0 - mu) * rs * w[tid]);
  h[(size_t)m * kD + 256 + tid] = f2bf((v1 - mu) * rs * w[256 + tid]);
}

// ============ weight transpose+cast (all layers): W[l][Kd][N] f32 -> WT[l][N][Kd] bf16 ====
__global__ __launch_bounds__(256) void tpose_w_kernel(
    const float* __restrict__ W, unsigned short* __restrict__ WT, int N, int Kd) {
  int l = blockIdx.z;
  const float* Wl = W + (size_t)l * N * Kd;
  unsigned short* WTl = WT + (size_t)l * N * Kd;
  int n0 = blockIdx.x * 64, k0 = blockIdx.y * 64;
  __shared__ float t[64][65];
  int tid = threadIdx.x;
  for (int idx = tid; idx < 4096; idx += 256) {
    int r = idx >> 6, c = idx & 63;
    t[r][c] = Wl[(size_t)(k0 + r) * N + n0 + c];
  }
  __syncthreads();
  for (int idx = tid; idx < 4096; idx += 256) {
    int r = idx >> 6, c = idx & 63;
    WTl[(size_t)(n0 + r) * Kd + k0 + c] = f2bf(t[c][r]);
  }
}

// ===== gate weight transpose (all layers): [l][3072][8]x2 -> gWT[l][16][3072] bf16 ======
__global__ __launch_bounds__(256) void tpose_gates_kernel(
    const float* __restrict__ igW, const float* __restrict__ fgW,
    unsigned short* __restrict__ gWT) {
  int l = blockIdx.y;
  int k = blockIdx.x * 256 + threadIdx.x;
  const float* igl = igW + (size_t)l * 3072 * 8;
  const float* fgl = fgW + (size_t)l * 3072 * 8;
  unsigned short* gl = gWT + (size_t)l * 16 * 3072;
#pragma unroll
  for (int h = 0; h < 8; ++h) {
    gl[(size_t)h * 3072 + k] = f2bf(igl[(size_t)k * 8 + h]);
    gl[(size_t)(8 + h) * 3072 + k] = f2bf(fgl[(size_t)k * 8 + h]);
  }
}

// ======================= bf16 MFMA GEMM: C[M,N] = A[M,Kd] @ BT[N,Kd]^T + bias (+C) ========
template <int RESID, typename TO>
__global__ __launch_bounds__(256) void gemm_mfma_kernel(
    const unsigned short* __restrict__ A, const unsigned short* __restrict__ BT,
    const float* __restrict__ bias, TO* __restrict__ C, int N, int Kd) {
  __shared__ __align__(16) char As[16384];
  __shared__ __align__(16) char Bs[16384];
  int tid = threadIdx.x, w = tid >> 6, l = tid & 63;
  int lr = l & 15, lg = l >> 4;
  int bm = blockIdx.y, bn = blockIdx.x;
  int wrow = (w >> 1) * 64, wcol = (w & 1) * 64;
  f32x4 acc[4][4] = {};
  for (int kt = 0; kt < Kd; kt += 64) {
    __syncthreads();
#pragma unroll
    for (int j = 0; j < 8; ++j) {
      int g = w * 8 + j;
      bool isA = g < 16;
      int ii = isA ? g : g - 16;
      int row = ii * 8 + (l >> 3);
      int chunk = (l & 7) ^ (row & 7);
      const unsigned short* src = isA
          ? A + ((size_t)(bm * 128 + row) * Kd + kt) + chunk * 8
          : BT + ((size_t)(bn * 128 + row) * Kd + kt) + chunk * 8;
      char* dst = (isA ? As : Bs) + ii * 1024;
      gload16(src, dst);
    }
    __syncthreads();
#pragma unroll
    for (int kk = 0; kk < 2; ++kk) {
      bf16x8 af[4], bfr[4];
#pragma unroll
      for (int m = 0; m < 4; ++m) {
        int row = wrow + m * 16 + lr;
        int ch = (kk * 4 + lg) ^ (row & 7);
        af[m] = *(const bf16x8*)(As + row * 128 + ch * 16);
      }
#pragma unroll
      for (int n = 0; n < 4; ++n) {
        int row = wcol + n * 16 + lr;
        int ch = (kk * 4 + lg) ^ (row & 7);
        bfr[n] = *(const bf16x8*)(Bs + row * 128 + ch * 16);
      }
#pragma unroll
      for (int m = 0; m < 4; ++m)
#pragma unroll
        for (int n = 0; n < 4; ++n)
          acc[m][n] = MFMA_BF16(af[m], bfr[n], acc[m][n]);
    }
  }
#pragma unroll
  for (int n = 0; n < 4; ++n) {
    int col = bn * 128 + wcol + n * 16 + lr;
    float bv = bias[col];
#pragma unroll
    for (int m = 0; m < 4; ++m)
#pragma unroll
      for (int i = 0; i < 4; ++i) {
        int row = bm * 128 + wrow + m * 16 + lg * 4 + i;
        float v = acc[m][n][i] + bv;
        if constexpr (sizeof(TO) == 2) {
          C[(size_t)row * N + col] = (TO)f2bf(v);
        } else {
          if (RESID) v += C[(size_t)row * N + col];
          C[(size_t)row * N + col] = v;
        }
      }
  }
}

// ============ fused causal conv(K=4)+silu + headwise q,k,v (register-only) ============
__global__ __launch_bounds__(256) void convhead_kernel(
    const unsigned short* __restrict__ u, const float* __restrict__ cw,
    const float* __restrict__ cb,
    const float* __restrict__ Wq, const float* __restrict__ Wk, const float* __restrict__ Wv,
    unsigned short* __restrict__ xcb, unsigned short* __restrict__ qb,
    unsigned short* __restrict__ kb, unsigned short* __restrict__ vb) {
  int m = blockIdx.x;
  int b = m >> 9, s = m & 511;
  int n = threadIdx.x;  // channels n*4 .. n*4+3
  float xm[4][4];
#pragma unroll
  for (int j = 0; j < 4; ++j) {
    int sp = s - 3 + j;
    if (sp >= 0) {
      unsigned long long raw = *(const unsigned long long*)&u[((size_t)(b * kS + sp)) * (2 * kI) + n * 4];
#pragma unroll
      for (int i = 0; i < 4; ++i) xm[j][i] = bf2f((unsigned short)(raw >> (i * 16)));
    } else {
#pragma unroll
      for (int i = 0; i < 4; ++i) xm[j][i] = 0.f;
    }
  }
  float xc[4];
  unsigned long long xcv = 0;
#pragma unroll
  for (int i = 0; i < 4; ++i) {
    int c = n * 4 + i;
    float acc = cb[c];
#pragma unroll
    for (int j = 0; j < 4; ++j) acc += xm[j][i] * cw[c * 4 + j];
    xc[i] = acc / (1.f + __expf(-acc));
    xcv |= (unsigned long long)f2bf(xc[i]) << (i * 16);
  }
  *(unsigned long long*)&xcb[(size_t)m * kI + n * 4] = xcv;
  const float* wq = Wq + n * 16;
  const float* wk = Wk + n * 16;
  const float* wv = Wv + n * 16;
  unsigned long long qv = 0, kv = 0, vv = 0;
#pragma unroll
  for (int o = 0; o < 4; ++o) {
    float aq = 0, ak = 0, av = 0;
#pragma unroll
    for (int i = 0; i < 4; ++i) {
      aq += xc[i] * wq[o * 4 + i];
      ak += xc[i] * wk[o * 4 + i];
      av += xm[3][i] * wv[o * 4 + i];
    }
    qv |= (unsigned long long)f2bf(aq) << (o * 16);
    kv |= (unsigned long long)f2bf(ak) << (o * 16);
    vv |= (unsigned long long)f2bf(av) << (o * 16);
  }
  size_t base = ((size_t)(b * 8 + (n >> 5)) * kS + s) * kDH + (n & 31) * 4;
  *(unsigned long long*)&qb[base] = qv;
  *(unsigned long long*)&kb[base] = kv;
  *(unsigned long long*)&vb[base] = vv;
}

// ============ gates via MFMA, split by source: partial[src] = rows @ W_src ============
__global__ __launch_bounds__(256) void gates_mfma_kernel(
    const unsigned short* __restrict__ qb, const unsigned short* __restrict__ kb,
    const unsigned short* __restrict__ vb, const unsigned short* __restrict__ gWT,
    float* __restrict__ IGp, float* __restrict__ FGp) {
  int blk = blockIdx.x;
  int src = blockIdx.y;
  int b = blk >> 3, s0 = (blk & 7) * 64;
  int tid = threadIdx.x, w = tid >> 6, l = tid & 63;
  int lr = l & 15, lg = l >> 4;
  __shared__ __align__(16) char Ts[16384];  // [64 s][128 k] bf16, RB=256, swizzled
  const unsigned short* srcb = (src == 0) ? qb : (src == 1) ? kb : vb;
  f32x4 acc = {};
  for (int kc8 = 0; kc8 < 8; ++kc8) {
    const unsigned short* srcbase = srcb + ((size_t)(b * 8 + kc8) * kS + s0) * kDH;
    __syncthreads();
#pragma unroll
    for (int j = 0; j < 4; ++j) {
      int issue = w * 4 + j;
      int row = issue * 4 + (l >> 4);
      int chunk = (l & 15) ^ (row & 7);
      gload16(srcbase + row * 128 + chunk * 8, Ts + issue * 1024);
    }
    __syncthreads();
#pragma unroll
    for (int kk = 0; kk < 4; ++kk) {
      int arow = w * 16 + lr;
      int ch = (kk * 4 + lg) ^ (arow & 7);
      bf16x8 af = *(const bf16x8*)(Ts + arow * 256 + ch * 16);
      bf16x8 bfv = *(const bf16x8*)(gWT + (size_t)lr * 3072 + (src * 8 + kc8) * 128 + kk * 32 + lg * 8);
      acc = MFMA_BF16(af, bfv, acc);
    }
  }
  float* IGo = IGp + (size_t)src * 64 * kS;
  float* FGo = FGp + (size_t)src * 64 * kS;
#pragma unroll
  for (int i = 0; i < 4; ++i) {
    int s = s0 + w * 16 + lg * 4 + i;
    if (lr < 8) IGo[((size_t)(b * 8) + lr) * kS + s] = acc[i];
    else FGo[((size_t)(b * 8) + lr - 8) * kS + s] = acc[i];
  }
}

// ======================= per-(b,nh) scan: sum partials + bias, inc, a, pmax ==============
__global__ __launch_bounds__(512) void scan_kernel(
    const float* __restrict__ IGp, const float* __restrict__ FGp,
    const float* __restrict__ igb, const float* __restrict__ fgb,
    float* __restrict__ inc, float* __restrict__ a, float* __restrict__ pmax) {
  int bh = blockIdx.x;
  int h = bh & 7;
  int t = threadIdx.x;
  const size_t ss = (size_t)64 * kS;
  size_t o = (size_t)bh * kS + t;
  float igv = IGp[o] + IGp[ss + o] + IGp[2 * ss + o] + igb[h];
  float fgv = FGp[o] + FGp[ss + o] + FGp[2 * ss + o] + fgb[h];
  __shared__ float buf[512];
  float lf = fminf(fgv, 0.f) - log1pf(expf(-fabsf(fgv)));  // log_sigmoid
  buf[t] = lf;
  __syncthreads();
  for (int off = 1; off < 512; off <<= 1) {
    float p = (t >= off) ? buf[t - off] : 0.f;
    __syncthreads();
    buf[t] += p;
    __syncthreads();
  }
  float inct = buf[t];
  inc[o] = inct;
  float av = igv - inct;
  a[o] = av;
  buf[t] = av;
  __syncthreads();
  for (int off = 1; off < 512; off <<= 1) {
    float p = (t >= off) ? buf[t - off] : -1e30f;
    __syncthreads();
    buf[t] = fmaxf(buf[t], p);
    __syncthreads();
  }
  pmax[o] = buf[t];
}

// ======================= V transpose: vb[bh][s][d] -> vt[bh][d][s] (bf16) ================
__global__ __launch_bounds__(256) void tpose_v_kernel(
    const unsigned short* __restrict__ vb, unsigned short* __restrict__ vt) {
  int bh = blockIdx.y, s0 = blockIdx.x * 64;
  __shared__ unsigned short t[64][130];
  int tid = threadIdx.x;
  for (int idx = tid; idx < 64 * 128; idx += 256) {
    int sl = idx >> 7, d = idx & 127;
    t[sl][d] = vb[((size_t)bh * kS + s0 + sl) * kDH + d];
  }
  __syncthreads();
  for (int idx = tid; idx < 64 * 128; idx += 256) {
    int dl = idx >> 6, sl = idx & 63;
    vt[((size_t)bh * kDH + dl) * kS + s0 + sl] = t[sl][dl];
  }
}

// ======================= mLSTM parallel via MFMA + fused mh_norm/skip/gate ===============
// grid 256, XCD-swizzled; each block does a PAIR of row tiles (rt = 7-pr, then pr)
// so every block runs exactly 9 K-tile iterations. Double-buffered K/V staging.
__global__ __launch_bounds__(256) void mlstm_mfma_kernel(
    const unsigned short* __restrict__ qb, const unsigned short* __restrict__ kb,
    const unsigned short* __restrict__ vt,
    const float* __restrict__ INC, const float* __restrict__ AV, const float* __restrict__ PM,
    const unsigned short* __restrict__ u, const unsigned short* __restrict__ xcb,
    const float* __restrict__ onw, const float* __restrict__ skw,
    unsigned short* __restrict__ hhb) {
  int id = blockIdx.x;
  int bh = (id & 7) * 8 + (id >> 5);   // each XCD sees only 8 heads
  int pr = (id >> 3) & 3;              // pair index: (7-pr, pr)
  int b = bh >> 3, nh = bh & 7;
  int tid = threadIdx.x, w = tid >> 6, l = tid & 63;
  int lr = l & 15, lg = l >> 4;
  __shared__ __align__(16) char Ks[2][16384];  // [64 s][128 d] bf16, RB=256
  __shared__ __align__(16) char Vs[2][16384];  // [128 d][64 s] bf16, RB=128
  __shared__ __align__(16) char Ps[4][2048];   // per-wave [16][64] bf16, RB=128

  const unsigned short* kbh = kb + (size_t)bh * kS * kDH;
  const unsigned short* vbh = vt + (size_t)bh * kDH * kS;

#pragma unroll 1
  for (int pass = 0; pass < 2; ++pass) {
    int rt = pass == 0 ? 7 - pr : pr;

    bf16x8 qf[4];
    int qrow = rt * 64 + w * 16 + lr;
    const unsigned short* qrp = qb + ((size_t)bh * kS + qrow) * kDH + lg * 8;
#pragma unroll
    for (int kk = 0; kk < 4; ++kk) qf[kk] = *(const bf16x8*)(qrp + kk * 32);

    float pm_r[4];
#pragma unroll
    for (int i = 0; i < 4; ++i)
      pm_r[i] = PM[(size_t)bh * kS + rt * 64 + w * 16 + lg * 4 + i];

    f32x4 oacc[8] = {};
    float rsum[4] = {};

    // prologue: stage tile 0 into buffer 0
    __syncthreads();  // previous pass done reading LDS
    {
      const unsigned short* kbase = kbh;
#pragma unroll
      for (int j = 0; j < 4; ++j) {
        int issue = w * 4 + j;
        int row = issue * 4 + (l >> 4);
        int chunk = (l & 15) ^ (row & 7);
        gload16(kbase + row * 128 + chunk * 8, Ks[0] + issue * 1024);
      }
#pragma unroll
      for (int j = 0; j < 4; ++j) {
        int vi = w * 4 + j;
        int row = vi * 8 + (l >> 3);
        int chunk = (l & 7) ^ (row & 7);
        gload16(vbh + (size_t)row * kS + chunk * 8, Vs[0] + vi * 1024);
      }
    }
    __syncthreads();

    int cur = 0;
#pragma unroll 1
    for (int ct = 0; ct <= rt; ++ct) {
      // issue next-tile staging into the other buffer (hidden under compute)
      if (ct < rt) {
        const unsigned short* kbase = kbh + (size_t)(ct + 1) * 64 * kDH;
        const unsigned short* vbase = vbh + (size_t)(ct + 1) * 64;
#pragma unroll
        for (int j = 0; j < 4; ++j) {
          int issue = w * 4 + j;
          int row = issue * 4 + (l >> 4);
          int chunk = (l & 15) ^ (row & 7);
          gload16(kbase + row * 128 + chunk * 8, Ks[cur ^ 1] + issue * 1024);
        }
#pragma unroll
        for (int j = 0; j < 4; ++j) {
          int vi = w * 4 + j;
          int row = vi * 8 + (l >> 3);
          int chunk = (l & 7) ^ (row & 7);
          gload16(vbase + (size_t)row * kS + chunk * 8, Vs[cur ^ 1] + vi * 1024);
        }
      }
      // QK^T
      f32x4 sacc[4] = {};
#pragma unroll
      for (int n = 0; n < 4; ++n) {
#pragma unroll
        for (int kk = 0; kk < 4; ++kk) {
          int krow = n * 16 + lr;
          int ch = (kk * 4 + lg) ^ (krow & 7);
          bf16x8 kf = *(const bf16x8*)(Ks[cur] + krow * 256 + ch * 16);
          sacc[n] = MFMA_BF16(qf[kk], kf, sacc[n]);
        }
      }
      // transform scores -> P (bf16 in per-wave LDS), accumulate row sums
#pragma unroll
      for (int n = 0; n < 4; ++n) {
        float av = AV[(size_t)bh * kS + ct * 64 + n * 16 + lr];
        int cg = ct * 64 + n * 16 + lr;
#pragma unroll
        for (int i = 0; i < 4; ++i) {
          int rg = rt * 64 + w * 16 + lg * 4 + i;
          float s = 0.f;
          if (ct < rt || cg <= rg)
            s = sacc[n][i] * 0.08838834764831845f * __expf(av - pm_r[i]);
          rsum[i] += s;
          int prow = lg * 4 + i, pcol = n * 16 + lr;
          int byte = prow * 128 + ((((pcol >> 3) ^ (prow & 7))) << 4) + (pcol & 7) * 2;
          *(unsigned short*)(Ps[w] + byte) = f2bf(s);
        }
      }
      // PV
#pragma unroll
      for (int kk = 0; kk < 2; ++kk) {
        int prow = lr;
        int pch = (kk * 4 + lg) ^ (prow & 7);
        bf16x8 pf = *(const bf16x8*)(Ps[w] + prow * 128 + pch * 16);
#pragma unroll
        for (int nb = 0; nb < 8; ++nb) {
          int vrow = nb * 16 + lr;
          int vch = (kk * 4 + lg) ^ (vrow & 7);
          bf16x8 vf = *(const bf16x8*)(Vs[cur] + vrow * 128 + vch * 16);
          oacc[nb] = MFMA_BF16(pf, vf, oacc[nb]);
        }
      }
      __syncthreads();  // drains staging DMA + protects buffer swap
      cur ^= 1;
    }

#pragma unroll
    for (int i = 0; i < 4; ++i)
#pragma unroll
      for (int off = 1; off < 16; off <<= 1) rsum[i] += __shfl_xor(rsum[i], off, 16);
    float ninv[4];
#pragma unroll
    for (int i = 0; i < 4; ++i) {
      int rg = rt * 64 + w * 16 + lg * 4 + i;
      float e0 = __expf(-INC[(size_t)bh * kS + rg] - pm_r[i]);
      float nn = fmaxf(fabsf(rsum[i]), e0);
      ninv[i] = 1.f / (nn + 1e-6f);
    }
    // ---- fused mh_norm (LN over DH=128 within 16-lane groups) + skip + output gate ----
    float val[8][4];
    float s1[4] = {}, s2[4] = {};
#pragma unroll
    for (int nb = 0; nb < 8; ++nb)
#pragma unroll
      for (int i = 0; i < 4; ++i) {
        float v = oacc[nb][i] * ninv[i];
        val[nb][i] = v;
        s1[i] += v; s2[i] += v * v;
      }
#pragma unroll
    for (int i = 0; i < 4; ++i) {
#pragma unroll
      for (int off = 1; off < 16; off <<= 1) {
        s1[i] += __shfl_xor(s1[i], off, 16);
        s2[i] += __shfl_xor(s2[i], off, 16);
      }
    }
#pragma unroll
    for (int i = 0; i < 4; ++i) {
      int rg = rt * 64 + w * 16 + lg * 4 + i;
      float mu = s1[i] * (1.f / 128.f);
      float var = s2[i] * (1.f / 128.f) - mu * mu;
      float rstd = rsqrtf(var + 1e-5f);
      size_t rowbase = (size_t)(b * kS + rg);
#pragma unroll
      for (int nb = 0; nb < 8; ++nb) {
        int c = nh * kDH + nb * 16 + lr;
        float nv = (val[nb][i] - mu) * rstd * onw[c];
        float z = bf2f(u[rowbase * (2 * kI) + kI + c]);
        float sz = z / (1.f + __expf(-z));
        float xcv = bf2f(xcb[rowbase * kI + c]);
        hhb[rowbase * kI + c] = f2bf((nv + skw[c] * xcv) * sz);
      }
    }
  }
}

// ======================= post-norm + head projection (last 96 rows/batch) =======================
__global__ __launch_bounds__(256) void head_kernel(
    const float* __restrict__ x, const float* __restrict__ pw,
    const float* __restrict__ hW, const float* __restrict__ hb, float* __restrict__ out) {
  int row = blockIdx.x;  // 0..767
  int b = row / kPRED, p = row % kPRED;
  int m = b * kS + (kS - kPRED) + p;
  int tid = threadIdx.x;
  float v0 = x[(size_t)m * kD + tid];
  float v1 = x[(size_t)m * kD + 256 + tid];
  float s1 = v0 + v1, s2 = v0 * v0 + v1 * v1;
#pragma unroll
  for (int o = 1; o < 64; o <<= 1) { s1 += __shfl_xor(s1, o, 64); s2 += __shfl_xor(s2, o, 64); }
  __shared__ float a1[4], a2[4];
  if ((tid & 63) == 0) { a1[tid >> 6] = s1; a2[tid >> 6] = s2; }
  __syncthreads();
  float t1 = a1[0] + a1[1] + a1[2] + a1[3];
  float t2 = a2[0] + a2[1] + a2[2] + a2[3];
  float mu = t1 * (1.f / kD);
  float var = t2 * (1.f / kD) - mu * mu;
  float rs = rsqrtf(var + 1e-5f);
  __shared__ float buf[512];
  buf[tid] = (v0 - mu) * rs * pw[tid];
  buf[256 + tid] = (v1 - mu) * rs * pw[256 + tid];
  __syncthreads();
  float acc[7] = {};
  for (int kk = tid; kk < 512; kk += 256) {
    float g = buf[kk];
#pragma unroll
    for (int n = 0; n < 7; ++n) acc[n] += g * hW[kk * 7 + n];
  }
  __shared__ float red[256 * 9];
#pragma unroll
  for (int n = 0; n < 7; ++n) red[tid * 9 + n] = acc[n];
  __syncthreads();
  for (int off = 128; off >= 1; off >>= 1) {
    if (tid < off) {
#pragma unroll
      for (int n = 0; n < 7; ++n) red[tid * 9 + n] += red[(tid + off) * 9 + n];
    }
    __syncthreads();
  }
  if (tid < 7) out[(size_t)row * 7 + tid] = red[tid] + hb[tid];
}

// ======================= host launch =======================
extern "C" void kernel_launch(void* const* d_in, const int* in_sizes, int n_in,
                              void* d_out, int out_size, void* d_ws, size_t ws_size,
                              hipStream_t stream) {
  const float* x_enc    = (const float*)d_in[0];
  const float* x_mark   = (const float*)d_in[1];
  const float* emb_W    = (const float*)d_in[4];
  const float* emb_b    = (const float*)d_in[5];
  const float* blk_ln_w = (const float*)d_in[6];
  const float* up_W     = (const float*)d_in[7];
  const float* up_b     = (const float*)d_in[8];
  const float* conv_w   = (const float*)d_in[9];
  const float* conv_b   = (const float*)d_in[10];
  const float* Wq       = (const float*)d_in[11];
  const float* Wk       = (const float*)d_in[12];
  const float* Wv       = (const float*)d_in[13];
  const float* ig_W     = (const float*)d_in[14];
  const float* ig_b     = (const float*)d_in[15];
  const float* fg_W     = (const float*)d_in[16];
  const float* fg_b     = (const float*)d_in[17];
  const float* onorm_w  = (const float*)d_in[18];
  const float* skip_w   = (const float*)d_in[19];
  const float* down_W   = (const float*)d_in[20];
  const float* down_b   = (const float*)d_in[21];
  const float* post_w   = (const float*)d_in[22];
  const float* head_W   = (const float*)d_in[23];
  const float* head_b   = (const float*)d_in[24];
  float* out = (float*)d_out;

  char* ws = (char*)d_ws;
  float* X  = (float*)ws;                     ws += (size_t)kM * kD * 4;        // 8 MB
  unsigned short* U    = (unsigned short*)ws; ws += (size_t)kM * 2 * kI * 2;    // 16 MB
  unsigned short* XCb  = (unsigned short*)ws; ws += (size_t)kM * kI * 2;        // 8 MB
  unsigned short* Hb   = (unsigned short*)ws; ws += (size_t)kM * kD * 2;        // 4 MB
  unsigned short* HHb  = (unsigned short*)ws; ws += (size_t)kM * kI * 2;        // 8 MB
  unsigned short* qb   = (unsigned short*)ws; ws += (size_t)kM * kI * 2;        // 8 MB
  unsigned short* kbuf = (unsigned short*)ws; ws += (size_t)kM * kI * 2;        // 8 MB
  unsigned short* vb   = (unsigned short*)ws; ws += (size_t)kM * kI * 2;        // 8 MB
  unsigned short* vt   = (unsigned short*)ws; ws += (size_t)kM * kI * 2;        // 8 MB
  unsigned short* upWT = (unsigned short*)ws; ws += (size_t)kL * 2 * kI * kD * 2; // 8 MB
  unsigned short* dnWT = (unsigned short*)ws; ws += (size_t)kL * kD * kI * 2;   // 4 MB
  unsigned short* gWT  = (unsigned short*)ws; ws += (size_t)kL * 16 * 3072 * 2; // 384 KB
  float* IGp = (float*)ws; ws += (size_t)3 * 64 * kS * 4;
  float* FGp = (float*)ws; ws += (size_t)3 * 64 * kS * 4;
  float* INC = (float*)ws; ws += (size_t)64 * kS * 4;
  float* AV  = (float*)ws; ws += (size_t)64 * kS * 4;
  float* PM  = (float*)ws; ws += (size_t)64 * kS * 4;

  embed_kernel<<<kM, 256, 0, stream>>>(x_enc, x_mark, emb_W, emb_b, X);
  tpose_w_kernel<<<dim3(32, 8, 4), 256, 0, stream>>>(up_W, upWT, 2 * kI, kD);
  tpose_w_kernel<<<dim3(8, 16, 4), 256, 0, stream>>>(down_W, dnWT, kD, kI);
  tpose_gates_kernel<<<dim3(12, 4), 256, 0, stream>>>(ig_W, fg_W, gWT);

  for (int l = 0; l < kL; ++l) {
    const float* lnw  = blk_ln_w + (size_t)l * kD;
    const float* upbl = up_b + (size_t)l * 2 * kI;
    const float* cwl  = conv_w + (size_t)l * kI * 4;
    const float* cbl  = conv_b + (size_t)l * kI;
    const float* wql  = Wq + (size_t)l * 256 * 16;
    const float* wkl  = Wk + (size_t)l * 256 * 16;
    const float* wvl  = Wv + (size_t)l * 256 * 16;
    const float* igbl = ig_b + (size_t)l * kNH;
    const float* fgbl = fg_b + (size_t)l * kNH;
    const float* onwl = onorm_w + (size_t)l * kI;
    const float* skwl = skip_w + (size_t)l * kI;
    const float* dbl  = down_b + (size_t)l * kD;
    const unsigned short* upWTl = upWT + (size_t)l * 2 * kI * kD;
    const unsigned short* dnWTl = dnWT + (size_t)l * kD * kI;
    const unsigned short* gWTl  = gWT + (size_t)l * 16 * 3072;

    ln_kernel<<<kM, 256, 0, stream>>>(X, lnw, Hb);
    gemm_mfma_kernel<0, unsigned short><<<dim3(16, 32), 256, 0, stream>>>(
        Hb, upWTl, upbl, U, 2 * kI, kD);
    convhead_kernel<<<kM, 256, 0, stream>>>(U, cwl, cbl, wql, wkl, wvl, XCb, qb, kbuf, vb);
    gates_mfma_kernel<<<dim3(64, 3), 256, 0, stream>>>(qb, kbuf, vb, gWTl, IGp, FGp);
    scan_kernel<<<64, 512, 0, stream>>>(IGp, FGp, igbl, fgbl, INC, AV, PM);
    tpose_v_kernel<<<dim3(8, 64), 256, 0, stream>>>(vb, vt);
    mlstm_mfma_kernel<<<256, 256, 0, stream>>>(
        qb, kbuf, vt, INC, AV, PM, U, XCb, onwl, skwl, HHb);
    gemm_mfma_kernel<1, float><<<dim3(4, 32), 256, 0, stream>>>(
        HHb, dnWTl, dbl, X, kD, kI);
  }

  head_kernel<<<kB * kPRED, 256, 0, stream>>>(X, post_w, head_W, head_b, out);
}

// Round 6
// 481.576 us; speedup vs baseline: 4.7311x; 1.1651x over previous
//
#include <hip/hip_runtime.h>
#include <math.h>

// ---- dims ----
static constexpr int kB = 8, kS = 512;
static constexpr int kD = 512, kI = 1024, kNH = 8, kDH = 128;
static constexpr int kL = 4, kPRED = 96, kCOUT = 7;
static constexpr int kM = kB * kS; // 4096 rows

typedef __bf16 bf16x8 __attribute__((ext_vector_type(8)));
typedef float f32x4 __attribute__((ext_vector_type(4)));

#define MFMA_BF16(a, b, c) __builtin_amdgcn_mfma_f32_16x16x32_bf16((a), (b), (c), 0, 0, 0)

typedef __attribute__((address_space(1))) const unsigned char* as1cp;
typedef __attribute__((address_space(3))) unsigned char* as3p;
__device__ __forceinline__ void gload16(const void* g, void* l) {
  __builtin_amdgcn_global_load_lds((as1cp)g, (as3p)l, 16, 0, 0);
}

__device__ __forceinline__ unsigned short f2bf(float f) {
  union { float f; unsigned u; } v; v.f = f;
  unsigned r = v.u + 0x7fffu + ((v.u >> 16) & 1u);
  return (unsigned short)(r >> 16);
}
__device__ __forceinline__ float bf2f(unsigned short h) {
  union { unsigned u; float f; } v; v.u = (unsigned)h << 16; return v.f;
}

// ======================= embedding =======================
__global__ __launch_bounds__(256) void embed_kernel(
    const float* __restrict__ xe, const float* __restrict__ xme,
    const float* __restrict__ W, const float* __restrict__ bias,
    float* __restrict__ x) {
  int m = blockIdx.x;
  int tid = threadIdx.x;
  __shared__ float f[11];
  if (tid < 7) f[tid] = xe[m * 7 + tid];
  else if (tid < 11) f[tid] = xme[m * 4 + (tid - 7)];
  __syncthreads();
  for (int d = tid; d < kD; d += 256) {
    float acc = bias[d];
#pragma unroll
    for (int e = 0; e < 11; ++e) acc += f[e] * W[e * kD + d];
    x[(size_t)m * kD + d] = acc;
  }
}

// ======================= layernorm (D=512, scale only) -> bf16 =======================
__global__ __launch_bounds__(256) void ln_kernel(
    const float* __restrict__ x, const float* __restrict__ w, unsigned short* __restrict__ h) {
  int m = blockIdx.x, tid = threadIdx.x;
  float v0 = x[(size_t)m * kD + tid];
  float v1 = x[(size_t)m * kD + 256 + tid];
  float s1 = v0 + v1, s2 = v0 * v0 + v1 * v1;
#pragma unroll
  for (int o = 1; o < 64; o <<= 1) { s1 += __shfl_xor(s1, o, 64); s2 += __shfl_xor(s2, o, 64); }
  __shared__ float a1[4], a2[4];
  if ((tid & 63) == 0) { a1[tid >> 6] = s1; a2[tid >> 6] = s2; }
  __syncthreads();
  float t1 = a1[0] + a1[1] + a1[2] + a1[3];
  float t2 = a2[0] + a2[1] + a2[2] + a2[3];
  float mu = t1 * (1.f / kD);
  float var = t2 * (1.f / kD) - mu * mu;
  float rs = rsqrtf(var + 1e-5f);
  h[(size_t)m * kD + tid] = f2bf((v0 - mu) * rs * w[tid]);
  h[(size_t)m * kD + 256 + tid] = f2bf((v1 - mu) * rs * w[256 + tid]);
}

// ============ weight transpose+cast (all layers): W[l][Kd][N] f32 -> WT[l][N][Kd] bf16 ====
__global__ __launch_bounds__(256) void tpose_w_kernel(
    const float* __restrict__ W, unsigned short* __restrict__ WT, int N, int Kd) {
  int l = blockIdx.z;
  const float* Wl = W + (size_t)l * N * Kd;
  unsigned short* WTl = WT + (size_t)l * N * Kd;
  int n0 = blockIdx.x * 64, k0 = blockIdx.y * 64;
  __shared__ float t[64][65];
  int tid = threadIdx.x;
  for (int idx = tid; idx < 4096; idx += 256) {
    int r = idx >> 6, c = idx & 63;
    t[r][c] = Wl[(size_t)(k0 + r) * N + n0 + c];
  }
  __syncthreads();
  for (int idx = tid; idx < 4096; idx += 256) {
    int r = idx >> 6, c = idx & 63;
    WTl[(size_t)(n0 + r) * Kd + k0 + c] = f2bf(t[c][r]);
  }
}

// ===== gate weight transpose (all layers): [l][3072][8]x2 -> gWT[l][16][3072] bf16 ======
__global__ __launch_bounds__(256) void tpose_gates_kernel(
    const float* __restrict__ igW, const float* __restrict__ fgW,
    unsigned short* __restrict__ gWT) {
  int l = blockIdx.y;
  int k = blockIdx.x * 256 + threadIdx.x;
  const float* igl = igW + (size_t)l * 3072 * 8;
  const float* fgl = fgW + (size_t)l * 3072 * 8;
  unsigned short* gl = gWT + (size_t)l * 16 * 3072;
#pragma unroll
  for (int h = 0; h < 8; ++h) {
    gl[(size_t)h * 3072 + k] = f2bf(igl[(size_t)k * 8 + h]);
    gl[(size_t)(8 + h) * 3072 + k] = f2bf(fgl[(size_t)k * 8 + h]);
  }
}

// ======================= bf16 MFMA GEMM: C[M,N] = A[M,Kd] @ BT[N,Kd]^T + bias (+C) ========
// BMx128 tile, BK=64, 4 waves, swizzled LDS, global_load_lds staging.
template <int BM, int RESID, typename TO>
__global__ __launch_bounds__(256) void gemm_mfma_kernel(
    const unsigned short* __restrict__ A, const unsigned short* __restrict__ BT,
    const float* __restrict__ bias, TO* __restrict__ C, int N, int Kd) {
  constexpr int A_ISS = BM / 8;             // A staging issues (1 KB each)
  constexpr int PER_W = (A_ISS + 16) / 4;   // issues per wave
  constexpr int MR = BM / 32;               // per-wave M fragments
  __shared__ __align__(16) char As[BM * 128];
  __shared__ __align__(16) char Bs[16384];
  int tid = threadIdx.x, w = tid >> 6, l = tid & 63;
  int lr = l & 15, lg = l >> 4;
  int bm = blockIdx.y, bn = blockIdx.x;
  int wrow = (w >> 1) * (BM / 2), wcol = (w & 1) * 64;
  f32x4 acc[MR][4] = {};
  for (int kt = 0; kt < Kd; kt += 64) {
    __syncthreads();
#pragma unroll
    for (int j = 0; j < PER_W; ++j) {
      int g = w * PER_W + j;
      bool isA = g < A_ISS;
      int ii = isA ? g : g - A_ISS;
      int row = ii * 8 + (l >> 3);
      int chunk = (l & 7) ^ (row & 7);
      const unsigned short* src = isA
          ? A + ((size_t)(bm * BM + row) * Kd + kt) + chunk * 8
          : BT + ((size_t)(bn * 128 + row) * Kd + kt) + chunk * 8;
      char* dst = (isA ? As : Bs) + ii * 1024;
      gload16(src, dst);
    }
    __syncthreads();
#pragma unroll
    for (int kk = 0; kk < 2; ++kk) {
      bf16x8 af[MR], bfr[4];
#pragma unroll
      for (int m = 0; m < MR; ++m) {
        int row = wrow + m * 16 + lr;
        int ch = (kk * 4 + lg) ^ (row & 7);
        af[m] = *(const bf16x8*)(As + row * 128 + ch * 16);
      }
#pragma unroll
      for (int n = 0; n < 4; ++n) {
        int row = wcol + n * 16 + lr;
        int ch = (kk * 4 + lg) ^ (row & 7);
        bfr[n] = *(const bf16x8*)(Bs + row * 128 + ch * 16);
      }
#pragma unroll
      for (int m = 0; m < MR; ++m)
#pragma unroll
        for (int n = 0; n < 4; ++n)
          acc[m][n] = MFMA_BF16(af[m], bfr[n], acc[m][n]);
    }
  }
#pragma unroll
  for (int n = 0; n < 4; ++n) {
    int col = bn * 128 + wcol + n * 16 + lr;
    float bv = bias[col];
#pragma unroll
    for (int m = 0; m < MR; ++m)
#pragma unroll
      for (int i = 0; i < 4; ++i) {
        int row = bm * BM + wrow + m * 16 + lg * 4 + i;
        float v = acc[m][n][i] + bv;
        if constexpr (sizeof(TO) == 2) {
          C[(size_t)row * N + col] = (TO)f2bf(v);
        } else {
          if (RESID) v += C[(size_t)row * N + col];
          C[(size_t)row * N + col] = v;
        }
      }
  }
}

// ============ fused causal conv(K=4)+silu + headwise q,k,v (register-only) ============
__global__ __launch_bounds__(256) void convhead_kernel(
    const unsigned short* __restrict__ u, const float* __restrict__ cw,
    const float* __restrict__ cb,
    const float* __restrict__ Wq, const float* __restrict__ Wk, const float* __restrict__ Wv,
    unsigned short* __restrict__ xcb, unsigned short* __restrict__ qb,
    unsigned short* __restrict__ kb, unsigned short* __restrict__ vb) {
  int m = blockIdx.x;
  int b = m >> 9, s = m & 511;
  int n = threadIdx.x;  // channels n*4 .. n*4+3
  float xm[4][4];
#pragma unroll
  for (int j = 0; j < 4; ++j) {
    int sp = s - 3 + j;
    if (sp >= 0) {
      unsigned long long raw = *(const unsigned long long*)&u[((size_t)(b * kS + sp)) * (2 * kI) + n * 4];
#pragma unroll
      for (int i = 0; i < 4; ++i) xm[j][i] = bf2f((unsigned short)(raw >> (i * 16)));
    } else {
#pragma unroll
      for (int i = 0; i < 4; ++i) xm[j][i] = 0.f;
    }
  }
  float xc[4];
  unsigned long long xcv = 0;
#pragma unroll
  for (int i = 0; i < 4; ++i) {
    int c = n * 4 + i;
    float acc = cb[c];
#pragma unroll
    for (int j = 0; j < 4; ++j) acc += xm[j][i] * cw[c * 4 + j];
    xc[i] = acc / (1.f + __expf(-acc));
    xcv |= (unsigned long long)f2bf(xc[i]) << (i * 16);
  }
  *(unsigned long long*)&xcb[(size_t)m * kI + n * 4] = xcv;
  const float* wq = Wq + n * 16;
  const float* wk = Wk + n * 16;
  const float* wv = Wv + n * 16;
  unsigned long long qv = 0, kv = 0, vv = 0;
#pragma unroll
  for (int o = 0; o < 4; ++o) {
    float aq = 0, ak = 0, av = 0;
#pragma unroll
    for (int i = 0; i < 4; ++i) {
      aq += xc[i] * wq[o * 4 + i];
      ak += xc[i] * wk[o * 4 + i];
      av += xm[3][i] * wv[o * 4 + i];
    }
    qv |= (unsigned long long)f2bf(aq) << (o * 16);
    kv |= (unsigned long long)f2bf(ak) << (o * 16);
    vv |= (unsigned long long)f2bf(av) << (o * 16);
  }
  size_t base = ((size_t)(b * 8 + (n >> 5)) * kS + s) * kDH + (n & 31) * 4;
  *(unsigned long long*)&qb[base] = qv;
  *(unsigned long long*)&kb[base] = kv;
  *(unsigned long long*)&vb[base] = vv;
}

// ============ gates via MFMA, split by source: partial[src] = rows @ W_src ============
__global__ __launch_bounds__(256) void gates_mfma_kernel(
    const unsigned short* __restrict__ qb, const unsigned short* __restrict__ kb,
    const unsigned short* __restrict__ vb, const unsigned short* __restrict__ gWT,
    float* __restrict__ IGp, float* __restrict__ FGp) {
  int blk = blockIdx.x;
  int src = blockIdx.y;
  int b = blk >> 3, s0 = (blk & 7) * 64;
  int tid = threadIdx.x, w = tid >> 6, l = tid & 63;
  int lr = l & 15, lg = l >> 4;
  __shared__ __align__(16) char Ts[16384];  // [64 s][128 k] bf16, RB=256, swizzled
  const unsigned short* srcb = (src == 0) ? qb : (src == 1) ? kb : vb;
  f32x4 acc = {};
  for (int kc8 = 0; kc8 < 8; ++kc8) {
    const unsigned short* srcbase = srcb + ((size_t)(b * 8 + kc8) * kS + s0) * kDH;
    __syncthreads();
#pragma unroll
    for (int j = 0; j < 4; ++j) {
      int issue = w * 4 + j;
      int row = issue * 4 + (l >> 4);
      int chunk = (l & 15) ^ (row & 7);
      gload16(srcbase + row * 128 + chunk * 8, Ts + issue * 1024);
    }
    __syncthreads();
#pragma unroll
    for (int kk = 0; kk < 4; ++kk) {
      int arow = w * 16 + lr;
      int ch = (kk * 4 + lg) ^ (arow & 7);
      bf16x8 af = *(const bf16x8*)(Ts + arow * 256 + ch * 16);
      bf16x8 bfv = *(const bf16x8*)(gWT + (size_t)lr * 3072 + (src * 8 + kc8) * 128 + kk * 32 + lg * 8);
      acc = MFMA_BF16(af, bfv, acc);
    }
  }
  float* IGo = IGp + (size_t)src * 64 * kS;
  float* FGo = FGp + (size_t)src * 64 * kS;
#pragma unroll
  for (int i = 0; i < 4; ++i) {
    int s = s0 + w * 16 + lg * 4 + i;
    if (lr < 8) IGo[((size_t)(b * 8) + lr) * kS + s] = acc[i];
    else FGo[((size_t)(b * 8) + lr - 8) * kS + s] = acc[i];
  }
}

// ======================= per-(b,nh) scan: sum partials + bias, inc, a, pmax ==============
__global__ __launch_bounds__(512) void scan_kernel(
    const float* __restrict__ IGp, const float* __restrict__ FGp,
    const float* __restrict__ igb, const float* __restrict__ fgb,
    float* __restrict__ inc, float* __restrict__ a, float* __restrict__ pmax) {
  int bh = blockIdx.x;
  int h = bh & 7;
  int t = threadIdx.x;
  const size_t ss = (size_t)64 * kS;
  size_t o = (size_t)bh * kS + t;
  float igv = IGp[o] + IGp[ss + o] + IGp[2 * ss + o] + igb[h];
  float fgv = FGp[o] + FGp[ss + o] + FGp[2 * ss + o] + fgb[h];
  __shared__ float buf[512];
  float lf = fminf(fgv, 0.f) - log1pf(expf(-fabsf(fgv)));  // log_sigmoid
  buf[t] = lf;
  __syncthreads();
  for (int off = 1; off < 512; off <<= 1) {
    float p = (t >= off) ? buf[t - off] : 0.f;
    __syncthreads();
    buf[t] += p;
    __syncthreads();
  }
  float inct = buf[t];
  inc[o] = inct;
  float av = igv - inct;
  a[o] = av;
  buf[t] = av;
  __syncthreads();
  for (int off = 1; off < 512; off <<= 1) {
    float p = (t >= off) ? buf[t - off] : -1e30f;
    __syncthreads();
    buf[t] = fmaxf(buf[t], p);
    __syncthreads();
  }
  pmax[o] = buf[t];
}

// ======================= V transpose: vb[bh][s][d] -> vt[bh][d][s] (bf16) ================
__global__ __launch_bounds__(256) void tpose_v_kernel(
    const unsigned short* __restrict__ vb, unsigned short* __restrict__ vt) {
  int bh = blockIdx.y, s0 = blockIdx.x * 64;
  __shared__ unsigned short t[64][130];
  int tid = threadIdx.x;
  for (int idx = tid; idx < 64 * 128; idx += 256) {
    int sl = idx >> 7, d = idx & 127;
    t[sl][d] = vb[((size_t)bh * kS + s0 + sl) * kDH + d];
  }
  __syncthreads();
  for (int idx = tid; idx < 64 * 128; idx += 256) {
    int dl = idx >> 6, sl = idx & 63;
    vt[((size_t)bh * kDH + dl) * kS + s0 + sl] = t[sl][dl];
  }
}

// ======================= mLSTM parallel via MFMA + fused mh_norm/skip/gate ===============
// grid 256, 8 waves/block. Waves 0-3 compute row-tile rtA=7-pr, waves 4-7 rtB=pr,
// sharing one double-buffered K/V staging stream (ct = 0..rtA). XCD-swizzled.
__global__ __launch_bounds__(512) void mlstm_mfma_kernel(
    const unsigned short* __restrict__ qb, const unsigned short* __restrict__ kb,
    const unsigned short* __restrict__ vt,
    const float* __restrict__ INC, const float* __restrict__ AV, const float* __restrict__ PM,
    const unsigned short* __restrict__ u, const unsigned short* __restrict__ xcb,
    const float* __restrict__ onw, const float* __restrict__ skw,
    unsigned short* __restrict__ hhb) {
  int id = blockIdx.x;
  int bh = (id & 7) * 8 + ((id >> 3) & 7);  // each XCD sees only 8 heads
  int pr = id >> 6;                          // 0..3
  int rtA = 7 - pr, rtB = pr;
  int b = bh >> 3, nh = bh & 7;
  int tid = threadIdx.x, w = tid >> 6, l = tid & 63;
  int g = w >> 2, wl = w & 3;
  int rt = (g == 0) ? rtA : rtB;
  int lr = l & 15, lg = l >> 4;
  __shared__ __align__(16) char Ks[2][16384];  // [64 s][128 d] bf16, RB=256
  __shared__ __align__(16) char Vs[2][16384];  // [128 d][64 s] bf16, RB=128
  __shared__ __align__(16) char Ps[8][2048];   // per-wave [16][64] bf16, RB=128

  const unsigned short* kbh = kb + (size_t)bh * kS * kDH;
  const unsigned short* vbh = vt + (size_t)bh * kDH * kS;

  bf16x8 qf[4];
  int qrow = rt * 64 + wl * 16 + lr;
  const unsigned short* qrp = qb + ((size_t)bh * kS + qrow) * kDH + lg * 8;
#pragma unroll
  for (int kk = 0; kk < 4; ++kk) qf[kk] = *(const bf16x8*)(qrp + kk * 32);

  float pm_r[4];
#pragma unroll
  for (int i = 0; i < 4; ++i)
    pm_r[i] = PM[(size_t)bh * kS + rt * 64 + wl * 16 + lg * 4 + i];

  f32x4 oacc[8] = {};
  float rsum[4] = {};

  // prologue: stage tile 0 into buffer 0 (all 8 waves: 2 K-issues + 2 V-issues each)
#pragma unroll
  for (int j = 0; j < 2; ++j) {
    int issue = w * 2 + j;
    int row = issue * 4 + (l >> 4);
    int chunk = (l & 15) ^ (row & 7);
    gload16(kbh + row * 128 + chunk * 8, Ks[0] + issue * 1024);
  }
#pragma unroll
  for (int j = 0; j < 2; ++j) {
    int vi = w * 2 + j;
    int row = vi * 8 + (l >> 3);
    int chunk = (l & 7) ^ (row & 7);
    gload16(vbh + (size_t)row * kS + chunk * 8, Vs[0] + vi * 1024);
  }
  __syncthreads();

  int cur = 0;
#pragma unroll 1
  for (int ct = 0; ct <= rtA; ++ct) {
    // issue next-tile staging into the other buffer (hidden under compute)
    if (ct < rtA) {
      const unsigned short* kbase = kbh + (size_t)(ct + 1) * 64 * kDH;
      const unsigned short* vbase = vbh + (size_t)(ct + 1) * 64;
#pragma unroll
      for (int j = 0; j < 2; ++j) {
        int issue = w * 2 + j;
        int row = issue * 4 + (l >> 4);
        int chunk = (l & 15) ^ (row & 7);
        gload16(kbase + row * 128 + chunk * 8, Ks[cur ^ 1] + issue * 1024);
      }
#pragma unroll
      for (int j = 0; j < 2; ++j) {
        int vi = w * 2 + j;
        int row = vi * 8 + (l >> 3);
        int chunk = (l & 7) ^ (row & 7);
        gload16(vbase + (size_t)row * kS + chunk * 8, Vs[cur ^ 1] + vi * 1024);
      }
    }
    if (ct <= rt) {
      // QK^T
      f32x4 sacc[4] = {};
#pragma unroll
      for (int n = 0; n < 4; ++n) {
#pragma unroll
        for (int kk = 0; kk < 4; ++kk) {
          int krow = n * 16 + lr;
          int ch = (kk * 4 + lg) ^ (krow & 7);
          bf16x8 kf = *(const bf16x8*)(Ks[cur] + krow * 256 + ch * 16);
          sacc[n] = MFMA_BF16(qf[kk], kf, sacc[n]);
        }
      }
      // transform scores -> P (bf16 in per-wave LDS), accumulate row sums
#pragma unroll
      for (int n = 0; n < 4; ++n) {
        float av = AV[(size_t)bh * kS + ct * 64 + n * 16 + lr];
        int cg = ct * 64 + n * 16 + lr;
#pragma unroll
        for (int i = 0; i < 4; ++i) {
          int rg = rt * 64 + wl * 16 + lg * 4 + i;
          float s = 0.f;
          if (ct < rt || cg <= rg)
            s = sacc[n][i] * 0.08838834764831845f * __expf(av - pm_r[i]);
          rsum[i] += s;
          int prow = lg * 4 + i, pcol = n * 16 + lr;
          int byte = prow * 128 + ((((pcol >> 3) ^ (prow & 7))) << 4) + (pcol & 7) * 2;
          *(unsigned short*)(Ps[w] + byte) = f2bf(s);
        }
      }
      // PV
#pragma unroll
      for (int kk = 0; kk < 2; ++kk) {
        int prow = lr;
        int pch = (kk * 4 + lg) ^ (prow & 7);
        bf16x8 pf = *(const bf16x8*)(Ps[w] + prow * 128 + pch * 16);
#pragma unroll
        for (int nb = 0; nb < 8; ++nb) {
          int vrow = nb * 16 + lr;
          int vch = (kk * 4 + lg) ^ (vrow & 7);
          bf16x8 vf = *(const bf16x8*)(Vs[cur] + vrow * 128 + vch * 16);
          oacc[nb] = MFMA_BF16(pf, vf, oacc[nb]);
        }
      }
    }
    __syncthreads();  // drains staging DMA + protects buffer swap
    cur ^= 1;
  }

#pragma unroll
  for (int i = 0; i < 4; ++i)
#pragma unroll
    for (int off = 1; off < 16; off <<= 1) rsum[i] += __shfl_xor(rsum[i], off, 16);
  float ninv[4];
#pragma unroll
  for (int i = 0; i < 4; ++i) {
    int rg = rt * 64 + wl * 16 + lg * 4 + i;
    float e0 = __expf(-INC[(size_t)bh * kS + rg] - pm_r[i]);
    float nn = fmaxf(fabsf(rsum[i]), e0);
    ninv[i] = 1.f / (nn + 1e-6f);
  }
  // ---- fused mh_norm (LN over DH=128 within 16-lane groups) + skip + output gate ----
  float val[8][4];
  float s1[4] = {}, s2[4] = {};
#pragma unroll
  for (int nb = 0; nb < 8; ++nb)
#pragma unroll
    for (int i = 0; i < 4; ++i) {
      float v = oacc[nb][i] * ninv[i];
      val[nb][i] = v;
      s1[i] += v; s2[i] += v * v;
    }
#pragma unroll
  for (int i = 0; i < 4; ++i) {
#pragma unroll
    for (int off = 1; off < 16; off <<= 1) {
      s1[i] += __shfl_xor(s1[i], off, 16);
      s2[i] += __shfl_xor(s2[i], off, 16);
    }
  }
#pragma unroll
  for (int i = 0; i < 4; ++i) {
    int rg = rt * 64 + wl * 16 + lg * 4 + i;
    float mu = s1[i] * (1.f / 128.f);
    float var = s2[i] * (1.f / 128.f) - mu * mu;
    float rstd = rsqrtf(var + 1e-5f);
    size_t rowbase = (size_t)(b * kS + rg);
#pragma unroll
    for (int nb = 0; nb < 8; ++nb) {
      int c = nh * kDH + nb * 16 + lr;
      float nv = (val[nb][i] - mu) * rstd * onw[c];
      float z = bf2f(u[rowbase * (2 * kI) + kI + c]);
      float sz = z / (1.f + __expf(-z));
      float xcv = bf2f(xcb[rowbase * kI + c]);
      hhb[rowbase * kI + c] = f2bf((nv + skw[c] * xcv) * sz);
    }
  }
}

// ======================= post-norm + head projection (last 96 rows/batch) =======================
__global__ __launch_bounds__(256) void head_kernel(
    const float* __restrict__ x, const float* __restrict__ pw,
    const float* __restrict__ hW, const float* __restrict__ hb, float* __restrict__ out) {
  int row = blockIdx.x;  // 0..767
  int b = row / kPRED, p = row % kPRED;
  int m = b * kS + (kS - kPRED) + p;
  int tid = threadIdx.x;
  float v0 = x[(size_t)m * kD + tid];
  float v1 = x[(size_t)m * kD + 256 + tid];
  float s1 = v0 + v1, s2 = v0 * v0 + v1 * v1;
#pragma unroll
  for (int o = 1; o < 64; o <<= 1) { s1 += __shfl_xor(s1, o, 64); s2 += __shfl_xor(s2, o, 64); }
  __shared__ float a1[4], a2[4];
  if ((tid & 63) == 0) { a1[tid >> 6] = s1; a2[tid >> 6] = s2; }
  __syncthreads();
  float t1 = a1[0] + a1[1] + a1[2] + a1[3];
  float t2 = a2[0] + a2[1] + a2[2] + a2[3];
  float mu = t1 * (1.f / kD);
  float var = t2 * (1.f / kD) - mu * mu;
  float rs = rsqrtf(var + 1e-5f);
  __shared__ float buf[512];
  buf[tid] = (v0 - mu) * rs * pw[tid];
  buf[256 + tid] = (v1 - mu) * rs * pw[256 + tid];
  __syncthreads();
  float acc[7] = {};
  for (int kk = tid; kk < 512; kk += 256) {
    float g = buf[kk];
#pragma unroll
    for (int n = 0; n < 7; ++n) acc[n] += g * hW[kk * 7 + n];
  }
  __shared__ float red[256 * 9];
#pragma unroll
  for (int n = 0; n < 7; ++n) red[tid * 9 + n] = acc[n];
  __syncthreads();
  for (int off = 128; off >= 1; off >>= 1) {
    if (tid < off) {
#pragma unroll
      for (int n = 0; n < 7; ++n) red[tid * 9 + n] += red[(tid + off) * 9 + n];
    }
    __syncthreads();
  }
  if (tid < 7) out[(size_t)row * 7 + tid] = red[tid] + hb[tid];
}

// ======================= host launch =======================
extern "C" void kernel_launch(void* const* d_in, const int* in_sizes, int n_in,
                              void* d_out, int out_size, void* d_ws, size_t ws_size,
                              hipStream_t stream) {
  const float* x_enc    = (const float*)d_in[0];
  const float* x_mark   = (const float*)d_in[1];
  const float* emb_W    = (const float*)d_in[4];
  const float* emb_b    = (const float*)d_in[5];
  const float* blk_ln_w = (const float*)d_in[6];
  const float* up_W     = (const float*)d_in[7];
  const float* up_b     = (const float*)d_in[8];
  const float* conv_w   = (const float*)d_in[9];
  const float* conv_b   = (const float*)d_in[10];
  const float* Wq       = (const float*)d_in[11];
  const float* Wk       = (const float*)d_in[12];
  const float* Wv       = (const float*)d_in[13];
  const float* ig_W     = (const float*)d_in[14];
  const float* ig_b     = (const float*)d_in[15];
  const float* fg_W     = (const float*)d_in[16];
  const float* fg_b     = (const float*)d_in[17];
  const float* onorm_w  = (const float*)d_in[18];
  const float* skip_w   = (const float*)d_in[19];
  const float* down_W   = (const float*)d_in[20];
  const float* down_b   = (const float*)d_in[21];
  const float* post_w   = (const float*)d_in[22];
  const float* head_W   = (const float*)d_in[23];
  const float* head_b   = (const float*)d_in[24];
  float* out = (float*)d_out;

  char* ws = (char*)d_ws;
  float* X  = (float*)ws;                     ws += (size_t)kM * kD * 4;        // 8 MB
  unsigned short* U    = (unsigned short*)ws; ws += (size_t)kM * 2 * kI * 2;    // 16 MB
  unsigned short* XCb  = (unsigned short*)ws; ws += (size_t)kM * kI * 2;        // 8 MB
  unsigned short* Hb   = (unsigned short*)ws; ws += (size_t)kM * kD * 2;        // 4 MB
  unsigned short* HHb  = (unsigned short*)ws; ws += (size_t)kM * kI * 2;        // 8 MB
  unsigned short* qb   = (unsigned short*)ws; ws += (size_t)kM * kI * 2;        // 8 MB
  unsigned short* kbuf = (unsigned short*)ws; ws += (size_t)kM * kI * 2;        // 8 MB
  unsigned short* vb   = (unsigned short*)ws; ws += (size_t)kM * kI * 2;        // 8 MB
  unsigned short* vt   = (unsigned short*)ws; ws += (size_t)kM * kI * 2;        // 8 MB
  unsigned short* upWT = (unsigned short*)ws; ws += (size_t)kL * 2 * kI * kD * 2; // 8 MB
  unsigned short* dnWT = (unsigned short*)ws; ws += (size_t)kL * kD * kI * 2;   // 4 MB
  unsigned short* gWT  = (unsigned short*)ws; ws += (size_t)kL * 16 * 3072 * 2; // 384 KB
  float* IGp = (float*)ws; ws += (size_t)3 * 64 * kS * 4;
  float* FGp = (float*)ws; ws += (size_t)3 * 64 * kS * 4;
  float* INC = (float*)ws; ws += (size_t)64 * kS * 4;
  float* AV  = (float*)ws; ws += (size_t)64 * kS * 4;
  float* PM  = (float*)ws; ws += (size_t)64 * kS * 4;

  embed_kernel<<<kM, 256, 0, stream>>>(x_enc, x_mark, emb_W, emb_b, X);
  tpose_w_kernel<<<dim3(32, 8, 4), 256, 0, stream>>>(up_W, upWT, 2 * kI, kD);
  tpose_w_kernel<<<dim3(8, 16, 4), 256, 0, stream>>>(down_W, dnWT, kD, kI);
  tpose_gates_kernel<<<dim3(12, 4), 256, 0, stream>>>(ig_W, fg_W, gWT);

  for (int l = 0; l < kL; ++l) {
    const float* lnw  = blk_ln_w + (size_t)l * kD;
    const float* upbl = up_b + (size_t)l * 2 * kI;
    const float* cwl  = conv_w + (size_t)l * kI * 4;
    const float* cbl  = conv_b + (size_t)l * kI;
    const float* wql  = Wq + (size_t)l * 256 * 16;
    const float* wkl  = Wk + (size_t)l * 256 * 16;
    const float* wvl  = Wv + (size_t)l * 256 * 16;
    const float* igbl = ig_b + (size_t)l * kNH;
    const float* fgbl = fg_b + (size_t)l * kNH;
    const float* onwl = onorm_w + (size_t)l * kI;
    const float* skwl = skip_w + (size_t)l * kI;
    const float* dbl  = down_b + (size_t)l * kD;
    const unsigned short* upWTl = upWT + (size_t)l * 2 * kI * kD;
    const unsigned short* dnWTl = dnWT + (size_t)l * kD * kI;
    const unsigned short* gWTl  = gWT + (size_t)l * 16 * 3072;

    ln_kernel<<<kM, 256, 0, stream>>>(X, lnw, Hb);
    gemm_mfma_kernel<128, 0, unsigned short><<<dim3(16, 32), 256, 0, stream>>>(
        Hb, upWTl, upbl, U, 2 * kI, kD);
    convhead_kernel<<<kM, 256, 0, stream>>>(U, cwl, cbl, wql, wkl, wvl, XCb, qb, kbuf, vb);
    gates_mfma_kernel<<<dim3(64, 3), 256, 0, stream>>>(qb, kbuf, vb, gWTl, IGp, FGp);
    scan_kernel<<<64, 512, 0, stream>>>(IGp, FGp, igbl, fgbl, INC, AV, PM);
    tpose_v_kernel<<<dim3(8, 64), 256, 0, stream>>>(vb, vt);
    mlstm_mfma_kernel<<<256, 512, 0, stream>>>(
        qb, kbuf, vt, INC, AV, PM, U, XCb, onwl, skwl, HHb);
    gemm_mfma_kernel<64, 1, float><<<dim3(4, 64), 256, 0, stream>>>(
        HHb, dnWTl, dbl, X, kD, kI);
  }

  head_kernel<<<kB * kPRED, 256, 0, stream>>>(X, post_w, head_W, head_b, out);
}

// Round 7
// 471.311 us; speedup vs baseline: 4.8342x; 1.0218x over previous
//
#include <hip/hip_runtime.h>
#include <math.h>

// ---- dims ----
static constexpr int kB = 8, kS = 512;
static constexpr int kD = 512, kI = 1024, kNH = 8, kDH = 128;
static constexpr int kL = 4, kPRED = 96, kCOUT = 7;
static constexpr int kM = kB * kS; // 4096 rows

typedef __bf16 bf16x8 __attribute__((ext_vector_type(8)));
typedef float f32x4 __attribute__((ext_vector_type(4)));

#define MFMA_BF16(a, b, c) __builtin_amdgcn_mfma_f32_16x16x32_bf16((a), (b), (c), 0, 0, 0)

typedef __attribute__((address_space(1))) const unsigned char* as1cp;
typedef __attribute__((address_space(3))) unsigned char* as3p;
__device__ __forceinline__ void gload16(const void* g, void* l) {
  __builtin_amdgcn_global_load_lds((as1cp)g, (as3p)l, 16, 0, 0);
}

__device__ __forceinline__ unsigned short f2bf(float f) {
  union { float f; unsigned u; } v; v.f = f;
  unsigned r = v.u + 0x7fffu + ((v.u >> 16) & 1u);
  return (unsigned short)(r >> 16);
}
__device__ __forceinline__ float bf2f(unsigned short h) {
  union { unsigned u; float f; } v; v.u = (unsigned)h << 16; return v.f;
}

// ======================= embedding + layer-0 pre-norm (fused) =======================
__global__ __launch_bounds__(256) void embed_ln_kernel(
    const float* __restrict__ xe, const float* __restrict__ xme,
    const float* __restrict__ W, const float* __restrict__ bias,
    const float* __restrict__ lnw,
    float* __restrict__ x, unsigned short* __restrict__ h) {
  int m = blockIdx.x;
  int tid = threadIdx.x;
  __shared__ float f[11];
  if (tid < 7) f[tid] = xe[m * 7 + tid];
  else if (tid < 11) f[tid] = xme[m * 4 + (tid - 7)];
  __syncthreads();
  float v0 = bias[tid], v1 = bias[256 + tid];
#pragma unroll
  for (int e = 0; e < 11; ++e) {
    v0 += f[e] * W[e * kD + tid];
    v1 += f[e] * W[e * kD + 256 + tid];
  }
  x[(size_t)m * kD + tid] = v0;
  x[(size_t)m * kD + 256 + tid] = v1;
  float s1 = v0 + v1, s2 = v0 * v0 + v1 * v1;
#pragma unroll
  for (int o = 1; o < 64; o <<= 1) { s1 += __shfl_xor(s1, o, 64); s2 += __shfl_xor(s2, o, 64); }
  __shared__ float a1[4], a2[4];
  if ((tid & 63) == 0) { a1[tid >> 6] = s1; a2[tid >> 6] = s2; }
  __syncthreads();
  float t1 = a1[0] + a1[1] + a1[2] + a1[3];
  float t2 = a2[0] + a2[1] + a2[2] + a2[3];
  float mu = t1 * (1.f / kD);
  float var = t2 * (1.f / kD) - mu * mu;
  float rs = rsqrtf(var + 1e-5f);
  h[(size_t)m * kD + tid] = f2bf((v0 - mu) * rs * lnw[tid]);
  h[(size_t)m * kD + 256 + tid] = f2bf((v1 - mu) * rs * lnw[256 + tid]);
}

// ======================= layernorm (D=512, scale only) -> bf16 =======================
__global__ __launch_bounds__(256) void ln_kernel(
    const float* __restrict__ x, const float* __restrict__ w, unsigned short* __restrict__ h) {
  int m = blockIdx.x, tid = threadIdx.x;
  float v0 = x[(size_t)m * kD + tid];
  float v1 = x[(size_t)m * kD + 256 + tid];
  float s1 = v0 + v1, s2 = v0 * v0 + v1 * v1;
#pragma unroll
  for (int o = 1; o < 64; o <<= 1) { s1 += __shfl_xor(s1, o, 64); s2 += __shfl_xor(s2, o, 64); }
  __shared__ float a1[4], a2[4];
  if ((tid & 63) == 0) { a1[tid >> 6] = s1; a2[tid >> 6] = s2; }
  __syncthreads();
  float t1 = a1[0] + a1[1] + a1[2] + a1[3];
  float t2 = a2[0] + a2[1] + a2[2] + a2[3];
  float mu = t1 * (1.f / kD);
  float var = t2 * (1.f / kD) - mu * mu;
  float rs = rsqrtf(var + 1e-5f);
  h[(size_t)m * kD + tid] = f2bf((v0 - mu) * rs * w[tid]);
  h[(size_t)m * kD + 256 + tid] = f2bf((v1 - mu) * rs * w[256 + tid]);
}

// ============ weight transpose+cast (all layers): W[l][Kd][N] f32 -> WT[l][N][Kd] bf16 ====
__global__ __launch_bounds__(256) void tpose_w_kernel(
    const float* __restrict__ W, unsigned short* __restrict__ WT, int N, int Kd) {
  int l = blockIdx.z;
  const float* Wl = W + (size_t)l * N * Kd;
  unsigned short* WTl = WT + (size_t)l * N * Kd;
  int n0 = blockIdx.x * 64, k0 = blockIdx.y * 64;
  __shared__ float t[64][65];
  int tid = threadIdx.x;
  for (int idx = tid; idx < 4096; idx += 256) {
    int r = idx >> 6, c = idx & 63;
    t[r][c] = Wl[(size_t)(k0 + r) * N + n0 + c];
  }
  __syncthreads();
  for (int idx = tid; idx < 4096; idx += 256) {
    int r = idx >> 6, c = idx & 63;
    WTl[(size_t)(n0 + r) * Kd + k0 + c] = f2bf(t[c][r]);
  }
}

// ===== gate weight transpose (all layers): [l][3072][8]x2 -> gWT[l][16][3072] bf16 ======
__global__ __launch_bounds__(256) void tpose_gates_kernel(
    const float* __restrict__ igW, const float* __restrict__ fgW,
    unsigned short* __restrict__ gWT) {
  int l = blockIdx.y;
  int k = blockIdx.x * 256 + threadIdx.x;
  const float* igl = igW + (size_t)l * 3072 * 8;
  const float* fgl = fgW + (size_t)l * 3072 * 8;
  unsigned short* gl = gWT + (size_t)l * 16 * 3072;
#pragma unroll
  for (int h = 0; h < 8; ++h) {
    gl[(size_t)h * 3072 + k] = f2bf(igl[(size_t)k * 8 + h]);
    gl[(size_t)(8 + h) * 3072 + k] = f2bf(fgl[(size_t)k * 8 + h]);
  }
}

// ======================= bf16 MFMA GEMM: C[M,N] = A[M,Kd] @ BT[N,Kd]^T + bias (+C) ========
// BMx128 tile, BK=64, 4 waves, swizzled LDS, global_load_lds staging.
// 1-D grid, XCD-bijective swizzle (bm-contiguous per XCD for A-panel L2 reuse).
template <int BM, int NBN, int RESID, typename TO>
__global__ __launch_bounds__(256) void gemm_mfma_kernel(
    const unsigned short* __restrict__ A, const unsigned short* __restrict__ BT,
    const float* __restrict__ bias, TO* __restrict__ C, int N, int Kd, int nwg) {
  constexpr int A_ISS = BM / 8;             // A staging issues (1 KB each)
  constexpr int PER_W = (A_ISS + 16) / 4;   // issues per wave
  constexpr int MR = BM / 32;               // per-wave M fragments
  __shared__ __align__(16) char As[BM * 128];
  __shared__ __align__(16) char Bs[16384];
  int tid = threadIdx.x, w = tid >> 6, l = tid & 63;
  int lr = l & 15, lg = l >> 4;
  // bijective XCD swizzle: xcd = id%8 gets a contiguous chunk of wg ids
  int id = blockIdx.x;
  int q = nwg >> 3, r = nwg & 7;
  int xcd = id & 7, pos = id >> 3;
  int wg = (xcd < r ? xcd * (q + 1) : r * (q + 1) + (xcd - r) * q) + pos;
  int bn = wg % NBN, bm = wg / NBN;
  int wrow = (w >> 1) * (BM / 2), wcol = (w & 1) * 64;
  f32x4 acc[MR][4] = {};
  for (int kt = 0; kt < Kd; kt += 64) {
    __syncthreads();
#pragma unroll
    for (int j = 0; j < PER_W; ++j) {
      int g = w * PER_W + j;
      bool isA = g < A_ISS;
      int ii = isA ? g : g - A_ISS;
      int row = ii * 8 + (l >> 3);
      int chunk = (l & 7) ^ (row & 7);
      const unsigned short* src = isA
          ? A + ((size_t)(bm * BM + row) * Kd + kt) + chunk * 8
          : BT + ((size_t)(bn * 128 + row) * Kd + kt) + chunk * 8;
      char* dst = (isA ? As : Bs) + ii * 1024;
      gload16(src, dst);
    }
    __syncthreads();
#pragma unroll
    for (int kk = 0; kk < 2; ++kk) {
      bf16x8 af[MR], bfr[4];
#pragma unroll
      for (int m = 0; m < MR; ++m) {
        int row = wrow + m * 16 + lr;
        int ch = (kk * 4 + lg) ^ (row & 7);
        af[m] = *(const bf16x8*)(As + row * 128 + ch * 16);
      }
#pragma unroll
      for (int n = 0; n < 4; ++n) {
        int row = wcol + n * 16 + lr;
        int ch = (kk * 4 + lg) ^ (row & 7);
        bfr[n] = *(const bf16x8*)(Bs + row * 128 + ch * 16);
      }
      __builtin_amdgcn_s_setprio(1);
#pragma unroll
      for (int m = 0; m < MR; ++m)
#pragma unroll
        for (int n = 0; n < 4; ++n)
          acc[m][n] = MFMA_BF16(af[m], bfr[n], acc[m][n]);
      __builtin_amdgcn_s_setprio(0);
    }
  }
#pragma unroll
  for (int n = 0; n < 4; ++n) {
    int col = bn * 128 + wcol + n * 16 + lr;
    float bv = bias[col];
#pragma unroll
    for (int m = 0; m < MR; ++m)
#pragma unroll
      for (int i = 0; i < 4; ++i) {
        int row = bm * BM + wrow + m * 16 + lg * 4 + i;
        float v = acc[m][n][i] + bv;
        if constexpr (sizeof(TO) == 2) {
          C[(size_t)row * N + col] = (TO)f2bf(v);
        } else {
          if (RESID) v += C[(size_t)row * N + col];
          C[(size_t)row * N + col] = v;
        }
      }
  }
}

// ============ fused causal conv(K=4)+silu + headwise q,k,v (register-only) ============
__global__ __launch_bounds__(256) void convhead_kernel(
    const unsigned short* __restrict__ u, const float* __restrict__ cw,
    const float* __restrict__ cb,
    const float* __restrict__ Wq, const float* __restrict__ Wk, const float* __restrict__ Wv,
    unsigned short* __restrict__ xcb, unsigned short* __restrict__ qb,
    unsigned short* __restrict__ kb, unsigned short* __restrict__ vb) {
  int m = blockIdx.x;
  int b = m >> 9, s = m & 511;
  int n = threadIdx.x;  // channels n*4 .. n*4+3
  float xm[4][4];
#pragma unroll
  for (int j = 0; j < 4; ++j) {
    int sp = s - 3 + j;
    if (sp >= 0) {
      unsigned long long raw = *(const unsigned long long*)&u[((size_t)(b * kS + sp)) * (2 * kI) + n * 4];
#pragma unroll
      for (int i = 0; i < 4; ++i) xm[j][i] = bf2f((unsigned short)(raw >> (i * 16)));
    } else {
#pragma unroll
      for (int i = 0; i < 4; ++i) xm[j][i] = 0.f;
    }
  }
  float xc[4];
  unsigned long long xcv = 0;
  float4 cb4 = *(const float4*)&cb[n * 4];
  const float* cbp = &cb4.x;
#pragma unroll
  for (int i = 0; i < 4; ++i) {
    int c = n * 4 + i;
    float4 cw4 = *(const float4*)&cw[c * 4];
    float acc = cbp[i] + xm[0][i] * cw4.x + xm[1][i] * cw4.y + xm[2][i] * cw4.z + xm[3][i] * cw4.w;
    xc[i] = acc / (1.f + __expf(-acc));
    xcv |= (unsigned long long)f2bf(xc[i]) << (i * 16);
  }
  *(unsigned long long*)&xcb[(size_t)m * kI + n * 4] = xcv;
  const float* wq = Wq + n * 16;
  const float* wk = Wk + n * 16;
  const float* wv = Wv + n * 16;
  unsigned long long qv = 0, kv = 0, vv = 0;
#pragma unroll
  for (int o = 0; o < 4; ++o) {
    float aq = 0, ak = 0, av = 0;
#pragma unroll
    for (int i = 0; i < 4; ++i) {
      aq += xc[i] * wq[o * 4 + i];
      ak += xc[i] * wk[o * 4 + i];
      av += xm[3][i] * wv[o * 4 + i];
    }
    qv |= (unsigned long long)f2bf(aq) << (o * 16);
    kv |= (unsigned long long)f2bf(ak) << (o * 16);
    vv |= (unsigned long long)f2bf(av) << (o * 16);
  }
  size_t base = ((size_t)(b * 8 + (n >> 5)) * kS + s) * kDH + (n & 31) * 4;
  *(unsigned long long*)&qb[base] = qv;
  *(unsigned long long*)&kb[base] = kv;
  *(unsigned long long*)&vb[base] = vv;
}

// ============ gates via MFMA, split by source: partial[src] = rows @ W_src ============
__global__ __launch_bounds__(256) void gates_mfma_kernel(
    const unsigned short* __restrict__ qb, const unsigned short* __restrict__ kb,
    const unsigned short* __restrict__ vb, const unsigned short* __restrict__ gWT,
    float* __restrict__ IGp, float* __restrict__ FGp) {
  int blk = blockIdx.x;
  int src = blockIdx.y;
  int b = blk >> 3, s0 = (blk & 7) * 64;
  int tid = threadIdx.x, w = tid >> 6, l = tid & 63;
  int lr = l & 15, lg = l >> 4;
  __shared__ __align__(16) char Ts[16384];  // [64 s][128 k] bf16, RB=256, swizzled
  const unsigned short* srcb = (src == 0) ? qb : (src == 1) ? kb : vb;
  f32x4 acc = {};
  for (int kc8 = 0; kc8 < 8; ++kc8) {
    const unsigned short* srcbase = srcb + ((size_t)(b * 8 + kc8) * kS + s0) * kDH;
    __syncthreads();
#pragma unroll
    for (int j = 0; j < 4; ++j) {
      int issue = w * 4 + j;
      int row = issue * 4 + (l >> 4);
      int chunk = (l & 15) ^ (row & 7);
      gload16(srcbase + row * 128 + chunk * 8, Ts + issue * 1024);
    }
    __syncthreads();
#pragma unroll
    for (int kk = 0; kk < 4; ++kk) {
      int arow = w * 16 + lr;
      int ch = (kk * 4 + lg) ^ (arow & 7);
      bf16x8 af = *(const bf16x8*)(Ts + arow * 256 + ch * 16);
      bf16x8 bfv = *(const bf16x8*)(gWT + (size_t)lr * 3072 + (src * 8 + kc8) * 128 + kk * 32 + lg * 8);
      acc = MFMA_BF16(af, bfv, acc);
    }
  }
  float* IGo = IGp + (size_t)src * 64 * kS;
  float* FGo = FGp + (size_t)src * 64 * kS;
#pragma unroll
  for (int i = 0; i < 4; ++i) {
    int s = s0 + w * 16 + lg * 4 + i;
    if (lr < 8) IGo[((size_t)(b * 8) + lr) * kS + s] = acc[i];
    else FGo[((size_t)(b * 8) + lr - 8) * kS + s] = acc[i];
  }
}

// ======================= per-(b,nh) scan: sum partials + bias, inc, a, pmax ==============
__global__ __launch_bounds__(512) void scan_kernel(
    const float* __restrict__ IGp, const float* __restrict__ FGp,
    const float* __restrict__ igb, const float* __restrict__ fgb,
    float* __restrict__ inc, float* __restrict__ a, float* __restrict__ pmax) {
  int bh = blockIdx.x;
  int h = bh & 7;
  int t = threadIdx.x;
  const size_t ss = (size_t)64 * kS;
  size_t o = (size_t)bh * kS + t;
  float igv = IGp[o] + IGp[ss + o] + IGp[2 * ss + o] + igb[h];
  float fgv = FGp[o] + FGp[ss + o] + FGp[2 * ss + o] + fgb[h];
  __shared__ float buf[512];
  float lf = fminf(fgv, 0.f) - log1pf(expf(-fabsf(fgv)));  // log_sigmoid
  buf[t] = lf;
  __syncthreads();
  for (int off = 1; off < 512; off <<= 1) {
    float p = (t >= off) ? buf[t - off] : 0.f;
    __syncthreads();
    buf[t] += p;
    __syncthreads();
  }
  float inct = buf[t];
  inc[o] = inct;
  float av = igv - inct;
  a[o] = av;
  buf[t] = av;
  __syncthreads();
  for (int off = 1; off < 512; off <<= 1) {
    float p = (t >= off) ? buf[t - off] : -1e30f;
    __syncthreads();
    buf[t] = fmaxf(buf[t], p);
    __syncthreads();
  }
  pmax[o] = buf[t];
}

// ======================= V transpose: vb[bh][s][d] -> vt[bh][d][s] (bf16) ================
__global__ __launch_bounds__(256) void tpose_v_kernel(
    const unsigned short* __restrict__ vb, unsigned short* __restrict__ vt) {
  int bh = blockIdx.y, s0 = blockIdx.x * 64;
  __shared__ unsigned short t[64][130];
  int tid = threadIdx.x;
  for (int idx = tid; idx < 64 * 128; idx += 256) {
    int sl = idx >> 7, d = idx & 127;
    t[sl][d] = vb[((size_t)bh * kS + s0 + sl) * kDH + d];
  }
  __syncthreads();
  for (int idx = tid; idx < 64 * 128; idx += 256) {
    int dl = idx >> 6, sl = idx & 63;
    vt[((size_t)bh * kDH + dl) * kS + s0 + sl] = t[sl][dl];
  }
}

// ======================= mLSTM parallel via MFMA + fused mh_norm/skip/gate ===============
// grid 256, 8 waves/block. Waves 0-3 compute row-tile rtA=7-pr, waves 4-7 rtB=pr,
// sharing one double-buffered K/V staging stream (ct = 0..rtA). XCD-swizzled.
__global__ __launch_bounds__(512) void mlstm_mfma_kernel(
    const unsigned short* __restrict__ qb, const unsigned short* __restrict__ kb,
    const unsigned short* __restrict__ vt,
    const float* __restrict__ INC, const float* __restrict__ AV, const float* __restrict__ PM,
    const unsigned short* __restrict__ u, const unsigned short* __restrict__ xcb,
    const float* __restrict__ onw, const float* __restrict__ skw,
    unsigned short* __restrict__ hhb) {
  int id = blockIdx.x;
  int bh = (id & 7) * 8 + ((id >> 3) & 7);  // each XCD sees only 8 heads
  int pr = id >> 6;                          // 0..3
  int rtA = 7 - pr, rtB = pr;
  int b = bh >> 3, nh = bh & 7;
  int tid = threadIdx.x, w = tid >> 6, l = tid & 63;
  int g = w >> 2, wl = w & 3;
  int rt = (g == 0) ? rtA : rtB;
  int lr = l & 15, lg = l >> 4;
  __shared__ __align__(16) char Ks[2][16384];  // [64 s][128 d] bf16, RB=256
  __shared__ __align__(16) char Vs[2][16384];  // [128 d][64 s] bf16, RB=128
  __shared__ __align__(16) char Ps[8][2048];   // per-wave [16][64] bf16, RB=128
  __shared__ float avs[512];

  const unsigned short* kbh = kb + (size_t)bh * kS * kDH;
  const unsigned short* vbh = vt + (size_t)bh * kDH * kS;

  // preload decay vector for this head into LDS (one load per thread)
  avs[tid] = AV[(size_t)bh * kS + tid];

  bf16x8 qf[4];
  int qrow = rt * 64 + wl * 16 + lr;
  const unsigned short* qrp = qb + ((size_t)bh * kS + qrow) * kDH + lg * 8;
#pragma unroll
  for (int kk = 0; kk < 4; ++kk) qf[kk] = *(const bf16x8*)(qrp + kk * 32);

  float pm_r[4];
#pragma unroll
  for (int i = 0; i < 4; ++i)
    pm_r[i] = PM[(size_t)bh * kS + rt * 64 + wl * 16 + lg * 4 + i];

  f32x4 oacc[8] = {};
  float rsum[4] = {};

  // prologue: stage tile 0 into buffer 0 (all 8 waves: 2 K-issues + 2 V-issues each)
#pragma unroll
  for (int j = 0; j < 2; ++j) {
    int issue = w * 2 + j;
    int row = issue * 4 + (l >> 4);
    int chunk = (l & 15) ^ (row & 7);
    gload16(kbh + row * 128 + chunk * 8, Ks[0] + issue * 1024);
  }
#pragma unroll
  for (int j = 0; j < 2; ++j) {
    int vi = w * 2 + j;
    int row = vi * 8 + (l >> 3);
    int chunk = (l & 7) ^ (row & 7);
    gload16(vbh + (size_t)row * kS + chunk * 8, Vs[0] + vi * 1024);
  }
  __syncthreads();

  int cur = 0;
#pragma unroll 1
  for (int ct = 0; ct <= rtA; ++ct) {
    // issue next-tile staging into the other buffer (hidden under compute)
    if (ct < rtA) {
      const unsigned short* kbase = kbh + (size_t)(ct + 1) * 64 * kDH;
      const unsigned short* vbase = vbh + (size_t)(ct + 1) * 64;
#pragma unroll
      for (int j = 0; j < 2; ++j) {
        int issue = w * 2 + j;
        int row = issue * 4 + (l >> 4);
        int chunk = (l & 15) ^ (row & 7);
        gload16(kbase + row * 128 + chunk * 8, Ks[cur ^ 1] + issue * 1024);
      }
#pragma unroll
      for (int j = 0; j < 2; ++j) {
        int vi = w * 2 + j;
        int row = vi * 8 + (l >> 3);
        int chunk = (l & 7) ^ (row & 7);
        gload16(vbase + (size_t)row * kS + chunk * 8, Vs[cur ^ 1] + vi * 1024);
      }
    }
    if (ct <= rt) {
      // QK^T
      f32x4 sacc[4] = {};
      __builtin_amdgcn_s_setprio(1);
#pragma unroll
      for (int n = 0; n < 4; ++n) {
#pragma unroll
        for (int kk = 0; kk < 4; ++kk) {
          int krow = n * 16 + lr;
          int ch = (kk * 4 + lg) ^ (krow & 7);
          bf16x8 kf = *(const bf16x8*)(Ks[cur] + krow * 256 + ch * 16);
          sacc[n] = MFMA_BF16(qf[kk], kf, sacc[n]);
        }
      }
      __builtin_amdgcn_s_setprio(0);
      // transform scores -> P (bf16 in per-wave LDS), accumulate row sums
#pragma unroll
      for (int n = 0; n < 4; ++n) {
        float av = avs[ct * 64 + n * 16 + lr];
        int cg = ct * 64 + n * 16 + lr;
#pragma unroll
        for (int i = 0; i < 4; ++i) {
          int rg = rt * 64 + wl * 16 + lg * 4 + i;
          float s = 0.f;
          if (ct < rt || cg <= rg)
            s = sacc[n][i] * 0.08838834764831845f * __expf(av - pm_r[i]);
          rsum[i] += s;
          int prow = lg * 4 + i, pcol = n * 16 + lr;
          int byte = prow * 128 + ((((pcol >> 3) ^ (prow & 7))) << 4) + (pcol & 7) * 2;
          *(unsigned short*)(Ps[w] + byte) = f2bf(s);
        }
      }
      // PV
      __builtin_amdgcn_s_setprio(1);
#pragma unroll
      for (int kk = 0; kk < 2; ++kk) {
        int prow = lr;
        int pch = (kk * 4 + lg) ^ (prow & 7);
        bf16x8 pf = *(const bf16x8*)(Ps[w] + prow * 128 + pch * 16);
#pragma unroll
        for (int nb = 0; nb < 8; ++nb) {
          int vrow = nb * 16 + lr;
          int vch = (kk * 4 + lg) ^ (vrow & 7);
          bf16x8 vf = *(const bf16x8*)(Vs[cur] + vrow * 128 + vch * 16);
          oacc[nb] = MFMA_BF16(pf, vf, oacc[nb]);
        }
      }
      __builtin_amdgcn_s_setprio(0);
    }
    __syncthreads();  // drains staging DMA + protects buffer swap
    cur ^= 1;
  }

#pragma unroll
  for (int i = 0; i < 4; ++i)
#pragma unroll
    for (int off = 1; off < 16; off <<= 1) rsum[i] += __shfl_xor(rsum[i], off, 16);
  float ninv[4];
#pragma unroll
  for (int i = 0; i < 4; ++i) {
    int rg = rt * 64 + wl * 16 + lg * 4 + i;
    float e0 = __expf(-INC[(size_t)bh * kS + rg] - pm_r[i]);
    float nn = fmaxf(fabsf(rsum[i]), e0);
    ninv[i] = 1.f / (nn + 1e-6f);
  }
  // ---- fused mh_norm (LN over DH=128 within 16-lane groups) + skip + output gate ----
  float val[8][4];
  float s1[4] = {}, s2[4] = {};
#pragma unroll
  for (int nb = 0; nb < 8; ++nb)
#pragma unroll
    for (int i = 0; i < 4; ++i) {
      float v = oacc[nb][i] * ninv[i];
      val[nb][i] = v;
      s1[i] += v; s2[i] += v * v;
    }
#pragma unroll
  for (int i = 0; i < 4; ++i) {
#pragma unroll
    for (int off = 1; off < 16; off <<= 1) {
      s1[i] += __shfl_xor(s1[i], off, 16);
      s2[i] += __shfl_xor(s2[i], off, 16);
    }
  }
#pragma unroll
  for (int i = 0; i < 4; ++i) {
    int rg = rt * 64 + wl * 16 + lg * 4 + i;
    float mu = s1[i] * (1.f / 128.f);
    float var = s2[i] * (1.f / 128.f) - mu * mu;
    float rstd = rsqrtf(var + 1e-5f);
    size_t rowbase = (size_t)(b * kS + rg);
#pragma unroll
    for (int nb = 0; nb < 8; ++nb) {
      int c = nh * kDH + nb * 16 + lr;
      float nv = (val[nb][i] - mu) * rstd * onw[c];
      float z = bf2f(u[rowbase * (2 * kI) + kI + c]);
      float sz = z / (1.f + __expf(-z));
      float xcv = bf2f(xcb[rowbase * kI + c]);
      hhb[rowbase * kI + c] = f2bf((nv + skw[c] * xcv) * sz);
    }
  }
}

// ======================= post-norm + head projection (last 96 rows/batch) =======================
__global__ __launch_bounds__(256) void head_kernel(
    const float* __restrict__ x, const float* __restrict__ pw,
    const float* __restrict__ hW, const float* __restrict__ hb, float* __restrict__ out) {
  int row = blockIdx.x;  // 0..767
  int b = row / kPRED, p = row % kPRED;
  int m = b * kS + (kS - kPRED) + p;
  int tid = threadIdx.x;
  float v0 = x[(size_t)m * kD + tid];
  float v1 = x[(size_t)m * kD + 256 + tid];
  float s1 = v0 + v1, s2 = v0 * v0 + v1 * v1;
#pragma unroll
  for (int o = 1; o < 64; o <<= 1) { s1 += __shfl_xor(s1, o, 64); s2 += __shfl_xor(s2, o, 64); }
  __shared__ float a1[4], a2[4];
  if ((tid & 63) == 0) { a1[tid >> 6] = s1; a2[tid >> 6] = s2; }
  __syncthreads();
  float t1 = a1[0] + a1[1] + a1[2] + a1[3];
  float t2 = a2[0] + a2[1] + a2[2] + a2[3];
  float mu = t1 * (1.f / kD);
  float var = t2 * (1.f / kD) - mu * mu;
  float rs = rsqrtf(var + 1e-5f);
  __shared__ float buf[512];
  buf[tid] = (v0 - mu) * rs * pw[tid];
  buf[256 + tid] = (v1 - mu) * rs * pw[256 + tid];
  __syncthreads();
  float acc[7] = {};
  for (int kk = tid; kk < 512; kk += 256) {
    float g = buf[kk];
#pragma unroll
    for (int n = 0; n < 7; ++n) acc[n] += g * hW[kk * 7 + n];
  }
  __shared__ float red[256 * 9];
#pragma unroll
  for (int n = 0; n < 7; ++n) red[tid * 9 + n] = acc[n];
  __syncthreads();
  for (int off = 128; off >= 1; off >>= 1) {
    if (tid < off) {
#pragma unroll
      for (int n = 0; n < 7; ++n) red[tid * 9 + n] += red[(tid + off) * 9 + n];
    }
    __syncthreads();
  }
  if (tid < 7) out[(size_t)row * 7 + tid] = red[tid] + hb[tid];
}

// ======================= host launch =======================
extern "C" void kernel_launch(void* const* d_in, const int* in_sizes, int n_in,
                              void* d_out, int out_size, void* d_ws, size_t ws_size,
                              hipStream_t stream) {
  const float* x_enc    = (const float*)d_in[0];
  const float* x_mark   = (const float*)d_in[1];
  const float* emb_W    = (const float*)d_in[4];
  const float* emb_b    = (const float*)d_in[5];
  const float* blk_ln_w = (const float*)d_in[6];
  const float* up_W     = (const float*)d_in[7];
  const float* up_b     = (const float*)d_in[8];
  const float* conv_w   = (const float*)d_in[9];
  const float* conv_b   = (const float*)d_in[10];
  const float* Wq       = (const float*)d_in[11];
  const float* Wk       = (const float*)d_in[12];
  const float* Wv       = (const float*)d_in[13];
  const float* ig_W     = (const float*)d_in[14];
  const float* ig_b     = (const float*)d_in[15];
  const float* fg_W     = (const float*)d_in[16];
  const float* fg_b     = (const float*)d_in[17];
  const float* onorm_w  = (const float*)d_in[18];
  const float* skip_w   = (const float*)d_in[19];
  const float* down_W   = (const float*)d_in[20];
  const float* down_b   = (const float*)d_in[21];
  const float* post_w   = (const float*)d_in[22];
  const float* head_W   = (const float*)d_in[23];
  const float* head_b   = (const float*)d_in[24];
  float* out = (float*)d_out;

  char* ws = (char*)d_ws;
  float* X  = (float*)ws;                     ws += (size_t)kM * kD * 4;        // 8 MB
  unsigned short* U    = (unsigned short*)ws; ws += (size_t)kM * 2 * kI * 2;    // 16 MB
  unsigned short* XCb  = (unsigned short*)ws; ws += (size_t)kM * kI * 2;        // 8 MB
  unsigned short* Hb   = (unsigned short*)ws; ws += (size_t)kM * kD * 2;        // 4 MB
  unsigned short* HHb  = (unsigned short*)ws; ws += (size_t)kM * kI * 2;        // 8 MB
  unsigned short* qb   = (unsigned short*)ws; ws += (size_t)kM * kI * 2;        // 8 MB
  unsigned short* kbuf = (unsigned short*)ws; ws += (size_t)kM * kI * 2;        // 8 MB
  unsigned short* vb   = (unsigned short*)ws; ws += (size_t)kM * kI * 2;        // 8 MB
  unsigned short* vt   = (unsigned short*)ws; ws += (size_t)kM * kI * 2;        // 8 MB
  unsigned short* upWT = (unsigned short*)ws; ws += (size_t)kL * 2 * kI * kD * 2; // 8 MB
  unsigned short* dnWT = (unsigned short*)ws; ws += (size_t)kL * kD * kI * 2;   // 4 MB
  unsigned short* gWT  = (unsigned short*)ws; ws += (size_t)kL * 16 * 3072 * 2; // 384 KB
  float* IGp = (float*)ws; ws += (size_t)3 * 64 * kS * 4;
  float* FGp = (float*)ws; ws += (size_t)3 * 64 * kS * 4;
  float* INC = (float*)ws; ws += (size_t)64 * kS * 4;
  float* AV  = (float*)ws; ws += (size_t)64 * kS * 4;
  float* PM  = (float*)ws; ws += (size_t)64 * kS * 4;

  embed_ln_kernel<<<kM, 256, 0, stream>>>(x_enc, x_mark, emb_W, emb_b, blk_ln_w, X, Hb);
  tpose_w_kernel<<<dim3(32, 8, 4), 256, 0, stream>>>(up_W, upWT, 2 * kI, kD);
  tpose_w_kernel<<<dim3(8, 16, 4), 256, 0, stream>>>(down_W, dnWT, kD, kI);
  tpose_gates_kernel<<<dim3(12, 4), 256, 0, stream>>>(ig_W, fg_W, gWT);

  for (int l = 0; l < kL; ++l) {
    const float* lnw  = blk_ln_w + (size_t)l * kD;
    const float* upbl = up_b + (size_t)l * 2 * kI;
    const float* cwl  = conv_w + (size_t)l * kI * 4;
    const float* cbl  = conv_b + (size_t)l * kI;
    const float* wql  = Wq + (size_t)l * 256 * 16;
    const float* wkl  = Wk + (size_t)l * 256 * 16;
    const float* wvl  = Wv + (size_t)l * 256 * 16;
    const float* igbl = ig_b + (size_t)l * kNH;
    const float* fgbl = fg_b + (size_t)l * kNH;
    const float* onwl = onorm_w + (size_t)l * kI;
    const float* skwl = skip_w + (size_t)l * kI;
    const float* dbl  = down_b + (size_t)l * kD;
    const unsigned short* upWTl = upWT + (size_t)l * 2 * kI * kD;
    const unsigned short* dnWTl = dnWT + (size_t)l * kD * kI;
    const unsigned short* gWTl  = gWT + (size_t)l * 16 * 3072;

    if (l > 0) ln_kernel<<<kM, 256, 0, stream>>>(X, lnw, Hb);
    gemm_mfma_kernel<128, 16, 0, unsigned short><<<512, 256, 0, stream>>>(
        Hb, upWTl, upbl, U, 2 * kI, kD, 512);
    convhead_kernel<<<kM, 256, 0, stream>>>(U, cwl, cbl, wql, wkl, wvl, XCb, qb, kbuf, vb);
    gates_mfma_kernel<<<dim3(64, 3), 256, 0, stream>>>(qb, kbuf, vb, gWTl, IGp, FGp);
    scan_kernel<<<64, 512, 0, stream>>>(IGp, FGp, igbl, fgbl, INC, AV, PM);
    tpose_v_kernel<<<dim3(8, 64), 256, 0, stream>>>(vb, vt);
    mlstm_mfma_kernel<<<256, 512, 0, stream>>>(
        qb, kbuf, vt, INC, AV, PM, U, XCb, onwl, skwl, HHb);
    gemm_mfma_kernel<64, 4, 1, float><<<256, 256, 0, stream>>>(
        HHb, dnWTl, dbl, X, kD, kI, 256);
  }

  head_kernel<<<kB * kPRED, 256, 0, stream>>>(X, post_w, head_W, head_b, out);
}

// Round 8
// 444.186 us; speedup vs baseline: 5.1294x; 1.0611x over previous
//
#include <hip/hip_runtime.h>
#include <math.h>

// ---- dims ----
static constexpr int kB = 8, kS = 512;
static constexpr int kD = 512, kI = 1024, kNH = 8, kDH = 128;
static constexpr int kL = 4, kPRED = 96, kCOUT = 7;
static constexpr int kM = kB * kS; // 4096 rows

typedef __bf16 bf16x8 __attribute__((ext_vector_type(8)));
typedef float f32x4 __attribute__((ext_vector_type(4)));

#define MFMA_BF16(a, b, c) __builtin_amdgcn_mfma_f32_16x16x32_bf16((a), (b), (c), 0, 0, 0)

typedef __attribute__((address_space(1))) const unsigned char* as1cp;
typedef __attribute__((address_space(3))) unsigned char* as3p;
__device__ __forceinline__ void gload16(const void* g, void* l) {
  __builtin_amdgcn_global_load_lds((as1cp)g, (as3p)l, 16, 0, 0);
}

__device__ __forceinline__ unsigned short f2bf(float f) {
  union { float f; unsigned u; } v; v.f = f;
  unsigned r = v.u + 0x7fffu + ((v.u >> 16) & 1u);
  return (unsigned short)(r >> 16);
}
__device__ __forceinline__ float bf2f(unsigned short h) {
  union { unsigned u; float f; } v; v.u = (unsigned)h << 16; return v.f;
}

// ======================= embedding + layer-0 pre-norm (fused) =======================
__global__ __launch_bounds__(256) void embed_ln_kernel(
    const float* __restrict__ xe, const float* __restrict__ xme,
    const float* __restrict__ W, const float* __restrict__ bias,
    const float* __restrict__ lnw,
    float* __restrict__ x, unsigned short* __restrict__ h) {
  int m = blockIdx.x;
  int tid = threadIdx.x;
  __shared__ float f[11];
  if (tid < 7) f[tid] = xe[m * 7 + tid];
  else if (tid < 11) f[tid] = xme[m * 4 + (tid - 7)];
  __syncthreads();
  float v0 = bias[tid], v1 = bias[256 + tid];
#pragma unroll
  for (int e = 0; e < 11; ++e) {
    v0 += f[e] * W[e * kD + tid];
    v1 += f[e] * W[e * kD + 256 + tid];
  }
  x[(size_t)m * kD + tid] = v0;
  x[(size_t)m * kD + 256 + tid] = v1;
  float s1 = v0 + v1, s2 = v0 * v0 + v1 * v1;
#pragma unroll
  for (int o = 1; o < 64; o <<= 1) { s1 += __shfl_xor(s1, o, 64); s2 += __shfl_xor(s2, o, 64); }
  __shared__ float a1[4], a2[4];
  if ((tid & 63) == 0) { a1[tid >> 6] = s1; a2[tid >> 6] = s2; }
  __syncthreads();
  float t1 = a1[0] + a1[1] + a1[2] + a1[3];
  float t2 = a2[0] + a2[1] + a2[2] + a2[3];
  float mu = t1 * (1.f / kD);
  float var = t2 * (1.f / kD) - mu * mu;
  float rs = rsqrtf(var + 1e-5f);
  h[(size_t)m * kD + tid] = f2bf((v0 - mu) * rs * lnw[tid]);
  h[(size_t)m * kD + 256 + tid] = f2bf((v1 - mu) * rs * lnw[256 + tid]);
}

// ======================= layernorm (D=512, scale only) -> bf16 =======================
__global__ __launch_bounds__(256) void ln_kernel(
    const float* __restrict__ x, const float* __restrict__ w, unsigned short* __restrict__ h) {
  int m = blockIdx.x, tid = threadIdx.x;
  float v0 = x[(size_t)m * kD + tid];
  float v1 = x[(size_t)m * kD + 256 + tid];
  float s1 = v0 + v1, s2 = v0 * v0 + v1 * v1;
#pragma unroll
  for (int o = 1; o < 64; o <<= 1) { s1 += __shfl_xor(s1, o, 64); s2 += __shfl_xor(s2, o, 64); }
  __shared__ float a1[4], a2[4];
  if ((tid & 63) == 0) { a1[tid >> 6] = s1; a2[tid >> 6] = s2; }
  __syncthreads();
  float t1 = a1[0] + a1[1] + a1[2] + a1[3];
  float t2 = a2[0] + a2[1] + a2[2] + a2[3];
  float mu = t1 * (1.f / kD);
  float var = t2 * (1.f / kD) - mu * mu;
  float rs = rsqrtf(var + 1e-5f);
  h[(size_t)m * kD + tid] = f2bf((v0 - mu) * rs * w[tid]);
  h[(size_t)m * kD + 256 + tid] = f2bf((v1 - mu) * rs * w[256 + tid]);
}

// ============ weight transpose+cast (all layers): W[l][Kd][N] f32 -> WT[l][N][Kd] bf16 ====
__global__ __launch_bounds__(256) void tpose_w_kernel(
    const float* __restrict__ W, unsigned short* __restrict__ WT, int N, int Kd) {
  int l = blockIdx.z;
  const float* Wl = W + (size_t)l * N * Kd;
  unsigned short* WTl = WT + (size_t)l * N * Kd;
  int n0 = blockIdx.x * 64, k0 = blockIdx.y * 64;
  __shared__ float t[64][65];
  int tid = threadIdx.x;
  for (int idx = tid; idx < 4096; idx += 256) {
    int r = idx >> 6, c = idx & 63;
    t[r][c] = Wl[(size_t)(k0 + r) * N + n0 + c];
  }
  __syncthreads();
  for (int idx = tid; idx < 4096; idx += 256) {
    int r = idx >> 6, c = idx & 63;
    WTl[(size_t)(n0 + r) * Kd + k0 + c] = f2bf(t[c][r]);
  }
}

// ===== gate weight transpose (all layers): [l][3072][8]x2 -> gWT[l][16][3072] bf16 ======
__global__ __launch_bounds__(256) void tpose_gates_kernel(
    const float* __restrict__ igW, const float* __restrict__ fgW,
    unsigned short* __restrict__ gWT) {
  int l = blockIdx.y;
  int k = blockIdx.x * 256 + threadIdx.x;
  const float* igl = igW + (size_t)l * 3072 * 8;
  const float* fgl = fgW + (size_t)l * 3072 * 8;
  unsigned short* gl = gWT + (size_t)l * 16 * 3072;
#pragma unroll
  for (int h = 0; h < 8; ++h) {
    gl[(size_t)h * 3072 + k] = f2bf(igl[(size_t)k * 8 + h]);
    gl[(size_t)(8 + h) * 3072 + k] = f2bf(fgl[(size_t)k * 8 + h]);
  }
}

// ======================= bf16 MFMA GEMM: C[M,N] = A[M,Kd] @ BT[N,Kd]^T + bias (+C) ========
// BMx128 tile, BK=64, 4 waves, swizzled LDS, global_load_lds staging.
// 1-D grid, XCD-bijective swizzle (bm-contiguous per XCD for A-panel L2 reuse).
template <int BM, int NBN, int RESID, typename TO>
__global__ __launch_bounds__(256) void gemm_mfma_kernel(
    const unsigned short* __restrict__ A, const unsigned short* __restrict__ BT,
    const float* __restrict__ bias, TO* __restrict__ C, int N, int Kd, int nwg) {
  constexpr int A_ISS = BM / 8;             // A staging issues (1 KB each)
  constexpr int PER_W = (A_ISS + 16) / 4;   // issues per wave
  constexpr int MR = BM / 32;               // per-wave M fragments
  __shared__ __align__(16) char As[BM * 128];
  __shared__ __align__(16) char Bs[16384];
  int tid = threadIdx.x, w = tid >> 6, l = tid & 63;
  int lr = l & 15, lg = l >> 4;
  int id = blockIdx.x;
  int q = nwg >> 3, r = nwg & 7;
  int xcd = id & 7, pos = id >> 3;
  int wg = (xcd < r ? xcd * (q + 1) : r * (q + 1) + (xcd - r) * q) + pos;
  int bn = wg % NBN, bm = wg / NBN;
  int wrow = (w >> 1) * (BM / 2), wcol = (w & 1) * 64;
  f32x4 acc[MR][4] = {};
  for (int kt = 0; kt < Kd; kt += 64) {
    __syncthreads();
#pragma unroll
    for (int j = 0; j < PER_W; ++j) {
      int g = w * PER_W + j;
      bool isA = g < A_ISS;
      int ii = isA ? g : g - A_ISS;
      int row = ii * 8 + (l >> 3);
      int chunk = (l & 7) ^ (row & 7);
      const unsigned short* src = isA
          ? A + ((size_t)(bm * BM + row) * Kd + kt) + chunk * 8
          : BT + ((size_t)(bn * 128 + row) * Kd + kt) + chunk * 8;
      char* dst = (isA ? As : Bs) + ii * 1024;
      gload16(src, dst);
    }
    __syncthreads();
#pragma unroll
    for (int kk = 0; kk < 2; ++kk) {
      bf16x8 af[MR], bfr[4];
#pragma unroll
      for (int m = 0; m < MR; ++m) {
        int row = wrow + m * 16 + lr;
        int ch = (kk * 4 + lg) ^ (row & 7);
        af[m] = *(const bf16x8*)(As + row * 128 + ch * 16);
      }
#pragma unroll
      for (int n = 0; n < 4; ++n) {
        int row = wcol + n * 16 + lr;
        int ch = (kk * 4 + lg) ^ (row & 7);
        bfr[n] = *(const bf16x8*)(Bs + row * 128 + ch * 16);
      }
      __builtin_amdgcn_s_setprio(1);
#pragma unroll
      for (int m = 0; m < MR; ++m)
#pragma unroll
        for (int n = 0; n < 4; ++n)
          acc[m][n] = MFMA_BF16(af[m], bfr[n], acc[m][n]);
      __builtin_amdgcn_s_setprio(0);
    }
  }
#pragma unroll
  for (int n = 0; n < 4; ++n) {
    int col = bn * 128 + wcol + n * 16 + lr;
    float bv = bias[col];
#pragma unroll
    for (int m = 0; m < MR; ++m)
#pragma unroll
      for (int i = 0; i < 4; ++i) {
        int row = bm * BM + wrow + m * 16 + lg * 4 + i;
        float v = acc[m][n][i] + bv;
        if constexpr (sizeof(TO) == 2) {
          C[(size_t)row * N + col] = (TO)f2bf(v);
        } else {
          if (RESID) v += C[(size_t)row * N + col];
          C[(size_t)row * N + col] = v;
        }
      }
  }
}

// ============ fused causal conv(K=4)+silu + headwise q,k,v (register-only) ============
__global__ __launch_bounds__(256) void convhead_kernel(
    const unsigned short* __restrict__ u, const float* __restrict__ cw,
    const float* __restrict__ cb,
    const float* __restrict__ Wq, const float* __restrict__ Wk, const float* __restrict__ Wv,
    unsigned short* __restrict__ xcb, unsigned short* __restrict__ qb,
    unsigned short* __restrict__ kb, unsigned short* __restrict__ vb) {
  int m = blockIdx.x;
  int b = m >> 9, s = m & 511;
  int n = threadIdx.x;  // channels n*4 .. n*4+3
  float xm[4][4];
#pragma unroll
  for (int j = 0; j < 4; ++j) {
    int sp = s - 3 + j;
    if (sp >= 0) {
      unsigned long long raw = *(const unsigned long long*)&u[((size_t)(b * kS + sp)) * (2 * kI) + n * 4];
#pragma unroll
      for (int i = 0; i < 4; ++i) xm[j][i] = bf2f((unsigned short)(raw >> (i * 16)));
    } else {
#pragma unroll
      for (int i = 0; i < 4; ++i) xm[j][i] = 0.f;
    }
  }
  float xc[4];
  unsigned long long xcv = 0;
  float4 cb4 = *(const float4*)&cb[n * 4];
  const float* cbp = &cb4.x;
#pragma unroll
  for (int i = 0; i < 4; ++i) {
    int c = n * 4 + i;
    float4 cw4 = *(const float4*)&cw[c * 4];
    float acc = cbp[i] + xm[0][i] * cw4.x + xm[1][i] * cw4.y + xm[2][i] * cw4.z + xm[3][i] * cw4.w;
    xc[i] = acc / (1.f + __expf(-acc));
    xcv |= (unsigned long long)f2bf(xc[i]) << (i * 16);
  }
  *(unsigned long long*)&xcb[(size_t)m * kI + n * 4] = xcv;
  const float* wq = Wq + n * 16;
  const float* wk = Wk + n * 16;
  const float* wv = Wv + n * 16;
  unsigned long long qv = 0, kv = 0, vv = 0;
#pragma unroll
  for (int o = 0; o < 4; ++o) {
    float aq = 0, ak = 0, av = 0;
#pragma unroll
    for (int i = 0; i < 4; ++i) {
      aq += xc[i] * wq[o * 4 + i];
      ak += xc[i] * wk[o * 4 + i];
      av += xm[3][i] * wv[o * 4 + i];
    }
    qv |= (unsigned long long)f2bf(aq) << (o * 16);
    kv |= (unsigned long long)f2bf(ak) << (o * 16);
    vv |= (unsigned long long)f2bf(av) << (o * 16);
  }
  size_t base = ((size_t)(b * 8 + (n >> 5)) * kS + s) * kDH + (n & 31) * 4;
  *(unsigned long long*)&qb[base] = qv;
  *(unsigned long long*)&kb[base] = kv;
  *(unsigned long long*)&vb[base] = vv;
}

// ============ merged prep: gates MFMA (blocks 0..191) + V transpose (blocks 192..703) ====
__global__ __launch_bounds__(256) void prep_kernel(
    const unsigned short* __restrict__ qb, const unsigned short* __restrict__ kb,
    const unsigned short* __restrict__ vb, const unsigned short* __restrict__ gWT,
    float* __restrict__ IGp, float* __restrict__ FGp, unsigned short* __restrict__ vt) {
  __shared__ __align__(16) char smem[16640];
  int id = blockIdx.x;
  int tid = threadIdx.x;
  if (id < 192) {
    // ---- gates: partial[src] = rows @ W_src ----
    int src = id >> 6;       // 0..2
    int blk = id & 63;
    int b = blk >> 3, s0 = (blk & 7) * 64;
    int w = tid >> 6, l = tid & 63;
    int lr = l & 15, lg = l >> 4;
    char* Ts = smem;  // [64 s][128 k] bf16, RB=256, swizzled
    const unsigned short* srcb = (src == 0) ? qb : (src == 1) ? kb : vb;
    f32x4 acc = {};
    for (int kc8 = 0; kc8 < 8; ++kc8) {
      const unsigned short* srcbase = srcb + ((size_t)(b * 8 + kc8) * kS + s0) * kDH;
      __syncthreads();
#pragma unroll
      for (int j = 0; j < 4; ++j) {
        int issue = w * 4 + j;
        int row = issue * 4 + (l >> 4);
        int chunk = (l & 15) ^ (row & 7);
        gload16(srcbase + row * 128 + chunk * 8, Ts + issue * 1024);
      }
      __syncthreads();
#pragma unroll
      for (int kk = 0; kk < 4; ++kk) {
        int arow = w * 16 + lr;
        int ch = (kk * 4 + lg) ^ (arow & 7);
        bf16x8 af = *(const bf16x8*)(Ts + arow * 256 + ch * 16);
        bf16x8 bfv = *(const bf16x8*)(gWT + (size_t)lr * 3072 + (src * 8 + kc8) * 128 + kk * 32 + lg * 8);
        acc = MFMA_BF16(af, bfv, acc);
      }
    }
    float* IGo = IGp + (size_t)src * 64 * kS;
    float* FGo = FGp + (size_t)src * 64 * kS;
#pragma unroll
    for (int i = 0; i < 4; ++i) {
      int s = s0 + w * 16 + lg * 4 + i;
      if (lr < 8) IGo[((size_t)(b * 8) + lr) * kS + s] = acc[i];
      else FGo[((size_t)(b * 8) + lr - 8) * kS + s] = acc[i];
    }
  } else {
    // ---- V transpose: vb[bh][s][d] -> vt[bh][d][s] ----
    int t = id - 192;
    int bh = t >> 3, s0 = (t & 7) * 64;
    unsigned short (*tt)[130] = (unsigned short(*)[130])smem;
    for (int idx = tid; idx < 64 * 128; idx += 256) {
      int sl = idx >> 7, d = idx & 127;
      tt[sl][d] = vb[((size_t)bh * kS + s0 + sl) * kDH + d];
    }
    __syncthreads();
    for (int idx = tid; idx < 64 * 128; idx += 256) {
      int dl = idx >> 6, sl = idx & 63;
      vt[((size_t)bh * kDH + dl) * kS + s0 + sl] = tt[sl][dl];
    }
  }
}

// ======================= per-(b,nh) scan: sum partials + bias, inc, a, pmax ==============
// wave __shfl_up scans + cross-wave LDS combine (2 barriers per scan)
__global__ __launch_bounds__(512) void scan_kernel(
    const float* __restrict__ IGp, const float* __restrict__ FGp,
    const float* __restrict__ igb, const float* __restrict__ fgb,
    float* __restrict__ inc, float* __restrict__ a, float* __restrict__ pmax) {
  int bh = blockIdx.x;
  int h = bh & 7;
  int t = threadIdx.x;
  int lane = t & 63, wid = t >> 6;
  const size_t ss = (size_t)64 * kS;
  size_t o = (size_t)bh * kS + t;
  float igv = IGp[o] + IGp[ss + o] + IGp[2 * ss + o] + igb[h];
  float fgv = FGp[o] + FGp[ss + o] + FGp[2 * ss + o] + fgb[h];
  float lf = fminf(fgv, 0.f) - log1pf(__expf(-fabsf(fgv)));  // log_sigmoid
  // wave inclusive sum-scan
  float x = lf;
#pragma unroll
  for (int off = 1; off < 64; off <<= 1) {
    float v = __shfl_up(x, off, 64);
    if (lane >= off) x += v;
  }
  __shared__ float wsum[8], wmax[8];
  if (lane == 63) wsum[wid] = x;
  __syncthreads();
  float base = 0.f;
  for (int i = 0; i < wid; ++i) base += wsum[i];
  float inct = x + base;
  inc[o] = inct;
  float av = igv - inct;
  a[o] = av;
  // wave inclusive max-scan
  float y = av;
#pragma unroll
  for (int off = 1; off < 64; off <<= 1) {
    float v = __shfl_up(y, off, 64);
    if (lane >= off) y = fmaxf(y, v);
  }
  if (lane == 63) wmax[wid] = y;
  __syncthreads();
  float mb = y;
  for (int i = 0; i < wid; ++i) mb = fmaxf(mb, wmax[i]);
  pmax[o] = mb;
}

// ======================= mLSTM parallel via MFMA + fused mh_norm/skip/gate ===============
// grid 256, 8 waves/block. Waves 0-3 compute row-tile rtA=7-pr, waves 4-7 rtB=pr,
// sharing one double-buffered K/V staging stream (ct = 0..rtA). XCD-swizzled.
// Decay applied in exp-domain: avs[t] = scale*exp(a[t]); epm[i] = exp(-pmax_i).
__global__ __launch_bounds__(512) void mlstm_mfma_kernel(
    const unsigned short* __restrict__ qb, const unsigned short* __restrict__ kb,
    const unsigned short* __restrict__ vt,
    const float* __restrict__ INC, const float* __restrict__ AV, const float* __restrict__ PM,
    const unsigned short* __restrict__ u, const unsigned short* __restrict__ xcb,
    const float* __restrict__ onw, const float* __restrict__ skw,
    unsigned short* __restrict__ hhb) {
  int id = blockIdx.x;
  int bh = (id & 7) * 8 + ((id >> 3) & 7);  // each XCD sees only 8 heads
  int pr = id >> 6;                          // 0..3
  int rtA = 7 - pr, rtB = pr;
  int b = bh >> 3, nh = bh & 7;
  int tid = threadIdx.x, w = tid >> 6, l = tid & 63;
  int g = w >> 2, wl = w & 3;
  int rt = (g == 0) ? rtA : rtB;
  int lr = l & 15, lg = l >> 4;
  __shared__ __align__(16) char Ks[2][16384];  // [64 s][128 d] bf16, RB=256
  __shared__ __align__(16) char Vs[2][16384];  // [128 d][64 s] bf16, RB=128
  __shared__ __align__(16) char Ps[8][2048];   // per-wave [16][64] bf16, RB=128
  __shared__ float avs[512];

  const unsigned short* kbh = kb + (size_t)bh * kS * kDH;
  const unsigned short* vbh = vt + (size_t)bh * kDH * kS;

  // preload scale*exp(a[t]) for this head (one exp per thread, hoisted)
  avs[tid] = 0.08838834764831845f * __expf(AV[(size_t)bh * kS + tid]);

  bf16x8 qf[4];
  int qrow = rt * 64 + wl * 16 + lr;
  const unsigned short* qrp = qb + ((size_t)bh * kS + qrow) * kDH + lg * 8;
#pragma unroll
  for (int kk = 0; kk < 4; ++kk) qf[kk] = *(const bf16x8*)(qrp + kk * 32);

  float pm_r[4], epm[4];
#pragma unroll
  for (int i = 0; i < 4; ++i) {
    pm_r[i] = PM[(size_t)bh * kS + rt * 64 + wl * 16 + lg * 4 + i];
    epm[i] = __expf(-pm_r[i]);
  }

  f32x4 oacc[8] = {};
  float rsum[4] = {};

  // prologue: stage tile 0 into buffer 0 (all 8 waves: 2 K-issues + 2 V-issues each)
#pragma unroll
  for (int j = 0; j < 2; ++j) {
    int issue = w * 2 + j;
    int row = issue * 4 + (l >> 4);
    int chunk = (l & 15) ^ (row & 7);
    gload16(kbh + row * 128 + chunk * 8, Ks[0] + issue * 1024);
  }
#pragma unroll
  for (int j = 0; j < 2; ++j) {
    int vi = w * 2 + j;
    int row = vi * 8 + (l >> 3);
    int chunk = (l & 7) ^ (row & 7);
    gload16(vbh + (size_t)row * kS + chunk * 8, Vs[0] + vi * 1024);
  }
  __syncthreads();

  int cur = 0;
#pragma unroll 1
  for (int ct = 0; ct <= rtA; ++ct) {
    // issue next-tile staging into the other buffer (hidden under compute)
    if (ct < rtA) {
      const unsigned short* kbase = kbh + (size_t)(ct + 1) * 64 * kDH;
      const unsigned short* vbase = vbh + (size_t)(ct + 1) * 64;
#pragma unroll
      for (int j = 0; j < 2; ++j) {
        int issue = w * 2 + j;
        int row = issue * 4 + (l >> 4);
        int chunk = (l & 15) ^ (row & 7);
        gload16(kbase + row * 128 + chunk * 8, Ks[cur ^ 1] + issue * 1024);
      }
#pragma unroll
      for (int j = 0; j < 2; ++j) {
        int vi = w * 2 + j;
        int row = vi * 8 + (l >> 3);
        int chunk = (l & 7) ^ (row & 7);
        gload16(vbase + (size_t)row * kS + chunk * 8, Vs[cur ^ 1] + vi * 1024);
      }
    }
    if (ct <= rt) {
      // QK^T
      f32x4 sacc[4] = {};
      __builtin_amdgcn_s_setprio(1);
#pragma unroll
      for (int n = 0; n < 4; ++n) {
#pragma unroll
        for (int kk = 0; kk < 4; ++kk) {
          int krow = n * 16 + lr;
          int ch = (kk * 4 + lg) ^ (krow & 7);
          bf16x8 kf = *(const bf16x8*)(Ks[cur] + krow * 256 + ch * 16);
          sacc[n] = MFMA_BF16(qf[kk], kf, sacc[n]);
        }
      }
      __builtin_amdgcn_s_setprio(0);
      // transform scores -> P (bf16 in per-wave LDS), accumulate row sums
#pragma unroll
      for (int n = 0; n < 4; ++n) {
        float eav = avs[ct * 64 + n * 16 + lr];
        int cg = ct * 64 + n * 16 + lr;
#pragma unroll
        for (int i = 0; i < 4; ++i) {
          int rg = rt * 64 + wl * 16 + lg * 4 + i;
          float s = 0.f;
          if (ct < rt || cg <= rg)
            s = sacc[n][i] * (eav * epm[i]);
          rsum[i] += s;
          int prow = lg * 4 + i, pcol = n * 16 + lr;
          int byte = prow * 128 + ((((pcol >> 3) ^ (prow & 7))) << 4) + (pcol & 7) * 2;
          *(unsigned short*)(Ps[w] + byte) = f2bf(s);
        }
      }
      // PV
      __builtin_amdgcn_s_setprio(1);
#pragma unroll
      for (int kk = 0; kk < 2; ++kk) {
        int prow = lr;
        int pch = (kk * 4 + lg) ^ (prow & 7);
        bf16x8 pf = *(const bf16x8*)(Ps[w] + prow * 128 + pch * 16);
#pragma unroll
        for (int nb = 0; nb < 8; ++nb) {
          int vrow = nb * 16 + lr;
          int vch = (kk * 4 + lg) ^ (vrow & 7);
          bf16x8 vf = *(const bf16x8*)(Vs[cur] + vrow * 128 + vch * 16);
          oacc[nb] = MFMA_BF16(pf, vf, oacc[nb]);
        }
      }
      __builtin_amdgcn_s_setprio(0);
    }
    __syncthreads();  // drains staging DMA + protects buffer swap
    cur ^= 1;
  }

#pragma unroll
  for (int i = 0; i < 4; ++i)
#pragma unroll
    for (int off = 1; off < 16; off <<= 1) rsum[i] += __shfl_xor(rsum[i], off, 16);
  float ninv[4];
#pragma unroll
  for (int i = 0; i < 4; ++i) {
    int rg = rt * 64 + wl * 16 + lg * 4 + i;
    float e0 = __expf(-INC[(size_t)bh * kS + rg] - pm_r[i]);
    float nn = fmaxf(fabsf(rsum[i]), e0);
    ninv[i] = 1.f / (nn + 1e-6f);
  }
  // ---- fused mh_norm (LN over DH=128 within 16-lane groups) + skip + output gate ----
  float val[8][4];
  float s1[4] = {}, s2[4] = {};
#pragma unroll
  for (int nb = 0; nb < 8; ++nb)
#pragma unroll
    for (int i = 0; i < 4; ++i) {
      float v = oacc[nb][i] * ninv[i];
      val[nb][i] = v;
      s1[i] += v; s2[i] += v * v;
    }
#pragma unroll
  for (int i = 0; i < 4; ++i) {
#pragma unroll
    for (int off = 1; off < 16; off <<= 1) {
      s1[i] += __shfl_xor(s1[i], off, 16);
      s2[i] += __shfl_xor(s2[i], off, 16);
    }
  }
#pragma unroll
  for (int i = 0; i < 4; ++i) {
    int rg = rt * 64 + wl * 16 + lg * 4 + i;
    float mu = s1[i] * (1.f / 128.f);
    float var = s2[i] * (1.f / 128.f) - mu * mu;
    float rstd = rsqrtf(var + 1e-5f);
    size_t rowbase = (size_t)(b * kS + rg);
#pragma unroll
    for (int nb = 0; nb < 8; ++nb) {
      int c = nh * kDH + nb * 16 + lr;
      float nv = (val[nb][i] - mu) * rstd * onw[c];
      float z = bf2f(u[rowbase * (2 * kI) + kI + c]);
      float sz = z / (1.f + __expf(-z));
      float xcv = bf2f(xcb[rowbase * kI + c]);
      hhb[rowbase * kI + c] = f2bf((nv + skw[c] * xcv) * sz);
    }
  }
}

// ======================= post-norm + head projection (last 96 rows/batch) =======================
__global__ __launch_bounds__(256) void head_kernel(
    const float* __restrict__ x, const float* __restrict__ pw,
    const float* __restrict__ hW, const float* __restrict__ hb, float* __restrict__ out) {
  int row = blockIdx.x;  // 0..767
  int b = row / kPRED, p = row % kPRED;
  int m = b * kS + (kS - kPRED) + p;
  int tid = threadIdx.x;
  float v0 = x[(size_t)m * kD + tid];
  float v1 = x[(size_t)m * kD + 256 + tid];
  float s1 = v0 + v1, s2 = v0 * v0 + v1 * v1;
#pragma unroll
  for (int o = 1; o < 64; o <<= 1) { s1 += __shfl_xor(s1, o, 64); s2 += __shfl_xor(s2, o, 64); }
  __shared__ float a1[4], a2[4];
  if ((tid & 63) == 0) { a1[tid >> 6] = s1; a2[tid >> 6] = s2; }
  __syncthreads();
  float t1 = a1[0] + a1[1] + a1[2] + a1[3];
  float t2 = a2[0] + a2[1] + a2[2] + a2[3];
  float mu = t1 * (1.f / kD);
  float var = t2 * (1.f / kD) - mu * mu;
  float rs = rsqrtf(var + 1e-5f);
  __shared__ float buf[512];
  buf[tid] = (v0 - mu) * rs * pw[tid];
  buf[256 + tid] = (v1 - mu) * rs * pw[256 + tid];
  __syncthreads();
  float acc[7] = {};
  for (int kk = tid; kk < 512; kk += 256) {
    float g = buf[kk];
#pragma unroll
    for (int n = 0; n < 7; ++n) acc[n] += g * hW[kk * 7 + n];
  }
  __shared__ float red[256 * 9];
#pragma unroll
  for (int n = 0; n < 7; ++n) red[tid * 9 + n] = acc[n];
  __syncthreads();
  for (int off = 128; off >= 1; off >>= 1) {
    if (tid < off) {
#pragma unroll
      for (int n = 0; n < 7; ++n) red[tid * 9 + n] += red[(tid + off) * 9 + n];
    }
    __syncthreads();
  }
  if (tid < 7) out[(size_t)row * 7 + tid] = red[tid] + hb[tid];
}

// ======================= host launch =======================
extern "C" void kernel_launch(void* const* d_in, const int* in_sizes, int n_in,
                              void* d_out, int out_size, void* d_ws, size_t ws_size,
                              hipStream_t stream) {
  const float* x_enc    = (const float*)d_in[0];
  const float* x_mark   = (const float*)d_in[1];
  const float* emb_W    = (const float*)d_in[4];
  const float* emb_b    = (const float*)d_in[5];
  const float* blk_ln_w = (const float*)d_in[6];
  const float* up_W     = (const float*)d_in[7];
  const float* up_b     = (const float*)d_in[8];
  const float* conv_w   = (const float*)d_in[9];
  const float* conv_b   = (const float*)d_in[10];
  const float* Wq       = (const float*)d_in[11];
  const float* Wk       = (const float*)d_in[12];
  const float* Wv       = (const float*)d_in[13];
  const float* ig_W     = (const float*)d_in[14];
  const float* ig_b     = (const float*)d_in[15];
  const float* fg_W     = (const float*)d_in[16];
  const float* fg_b     = (const float*)d_in[17];
  const float* onorm_w  = (const float*)d_in[18];
  const float* skip_w   = (const float*)d_in[19];
  const float* down_W   = (const float*)d_in[20];
  const float* down_b   = (const float*)d_in[21];
  const float* post_w   = (const float*)d_in[22];
  const float* head_W   = (const float*)d_in[23];
  const float* head_b   = (const float*)d_in[24];
  float* out = (float*)d_out;

  char* ws = (char*)d_ws;
  float* X  = (float*)ws;                     ws += (size_t)kM * kD * 4;        // 8 MB
  unsigned short* U    = (unsigned short*)ws; ws += (size_t)kM * 2 * kI * 2;    // 16 MB
  unsigned short* XCb  = (unsigned short*)ws; ws += (size_t)kM * kI * 2;        // 8 MB
  unsigned short* Hb   = (unsigned short*)ws; ws += (size_t)kM * kD * 2;        // 4 MB
  unsigned short* HHb  = (unsigned short*)ws; ws += (size_t)kM * kI * 2;        // 8 MB
  unsigned short* qb   = (unsigned short*)ws; ws += (size_t)kM * kI * 2;        // 8 MB
  unsigned short* kbuf = (unsigned short*)ws; ws += (size_t)kM * kI * 2;        // 8 MB
  unsigned short* vb   = (unsigned short*)ws; ws += (size_t)kM * kI * 2;        // 8 MB
  unsigned short* vt   = (unsigned short*)ws; ws += (size_t)kM * kI * 2;        // 8 MB
  unsigned short* upWT = (unsigned short*)ws; ws += (size_t)kL * 2 * kI * kD * 2; // 8 MB
  unsigned short* dnWT = (unsigned short*)ws; ws += (size_t)kL * kD * kI * 2;   // 4 MB
  unsigned short* gWT  = (unsigned short*)ws; ws += (size_t)kL * 16 * 3072 * 2; // 384 KB
  float* IGp = (float*)ws; ws += (size_t)3 * 64 * kS * 4;
  float* FGp = (float*)ws; ws += (size_t)3 * 64 * kS * 4;
  float* INC = (float*)ws; ws += (size_t)64 * kS * 4;
  float* AV  = (float*)ws; ws += (size_t)64 * kS * 4;
  float* PM  = (float*)ws; ws += (size_t)64 * kS * 4;

  embed_ln_kernel<<<kM, 256, 0, stream>>>(x_enc, x_mark, emb_W, emb_b, blk_ln_w, X, Hb);
  tpose_w_kernel<<<dim3(32, 8, 4), 256, 0, stream>>>(up_W, upWT, 2 * kI, kD);
  tpose_w_kernel<<<dim3(8, 16, 4), 256, 0, stream>>>(down_W, dnWT, kD, kI);
  tpose_gates_kernel<<<dim3(12, 4), 256, 0, stream>>>(ig_W, fg_W, gWT);

  for (int l = 0; l < kL; ++l) {
    const float* lnw  = blk_ln_w + (size_t)l * kD;
    const float* upbl = up_b + (size_t)l * 2 * kI;
    const float* cwl  = conv_w + (size_t)l * kI * 4;
    const float* cbl  = conv_b + (size_t)l * kI;
    const float* wql  = Wq + (size_t)l * 256 * 16;
    const float* wkl  = Wk + (size_t)l * 256 * 16;
    const float* wvl  = Wv + (size_t)l * 256 * 16;
    const float* igbl = ig_b + (size_t)l * kNH;
    const float* fgbl = fg_b + (size_t)l * kNH;
    const float* onwl = onorm_w + (size_t)l * kI;
    const float* skwl = skip_w + (size_t)l * kI;
    const float* dbl  = down_b + (size_t)l * kD;
    const unsigned short* upWTl = upWT + (size_t)l * 2 * kI * kD;
    const unsigned short* dnWTl = dnWT + (size_t)l * kD * kI;
    const unsigned short* gWTl  = gWT + (size_t)l * 16 * 3072;

    if (l > 0) ln_kernel<<<kM, 256, 0, stream>>>(X, lnw, Hb);
    gemm_mfma_kernel<128, 16, 0, unsigned short><<<512, 256, 0, stream>>>(
        Hb, upWTl, upbl, U, 2 * kI, kD, 512);
    convhead_kernel<<<kM, 256, 0, stream>>>(U, cwl, cbl, wql, wkl, wvl, XCb, qb, kbuf, vb);
    prep_kernel<<<704, 256, 0, stream>>>(qb, kbuf, vb, gWTl, IGp, FGp, vt);
    scan_kernel<<<64, 512, 0, stream>>>(IGp, FGp, igbl, fgbl, INC, AV, PM);
    mlstm_mfma_kernel<<<256, 512, 0, stream>>>(
        qb, kbuf, vt, INC, AV, PM, U, XCb, onwl, skwl, HHb);
    gemm_mfma_kernel<64, 4, 1, float><<<256, 256, 0, stream>>>(
        HHb, dnWTl, dbl, X, kD, kI, 256);
  }

  head_kernel<<<kB * kPRED, 256, 0, stream>>>(X, post_w, head_W, head_b, out);
}

// Round 9
// 388.434 us; speedup vs baseline: 5.8656x; 1.1435x over previous
//
#include <hip/hip_runtime.h>
#include <math.h>

// ---- dims ----
static constexpr int kB = 8, kS = 512;
static constexpr int kD = 512, kI = 1024, kNH = 8, kDH = 128;
static constexpr int kL = 4, kPRED = 96, kCOUT = 7;
static constexpr int kM = kB * kS; // 4096 rows

typedef __bf16 bf16x8 __attribute__((ext_vector_type(8)));
typedef float f32x4 __attribute__((ext_vector_type(4)));

#define MFMA_BF16(a, b, c) __builtin_amdgcn_mfma_f32_16x16x32_bf16((a), (b), (c), 0, 0, 0)

typedef __attribute__((address_space(1))) const unsigned char* as1cp;
typedef __attribute__((address_space(3))) unsigned char* as3p;
__device__ __forceinline__ void gload16(const void* g, void* l) {
  __builtin_amdgcn_global_load_lds((as1cp)g, (as3p)l, 16, 0, 0);
}

__device__ __forceinline__ unsigned short f2bf(float f) {
  union { float f; unsigned u; } v; v.f = f;
  unsigned r = v.u + 0x7fffu + ((v.u >> 16) & 1u);
  return (unsigned short)(r >> 16);
}
__device__ __forceinline__ float bf2f(unsigned short h) {
  union { unsigned u; float f; } v; v.u = (unsigned)h << 16; return v.f;
}

// ======================= embedding + layer-0 pre-norm (fused) =======================
__global__ __launch_bounds__(256) void embed_ln_kernel(
    const float* __restrict__ xe, const float* __restrict__ xme,
    const float* __restrict__ W, const float* __restrict__ bias,
    const float* __restrict__ lnw,
    float* __restrict__ x, unsigned short* __restrict__ h) {
  int m = blockIdx.x;
  int tid = threadIdx.x;
  __shared__ float f[11];
  if (tid < 7) f[tid] = xe[m * 7 + tid];
  else if (tid < 11) f[tid] = xme[m * 4 + (tid - 7)];
  __syncthreads();
  float v0 = bias[tid], v1 = bias[256 + tid];
#pragma unroll
  for (int e = 0; e < 11; ++e) {
    v0 += f[e] * W[e * kD + tid];
    v1 += f[e] * W[e * kD + 256 + tid];
  }
  x[(size_t)m * kD + tid] = v0;
  x[(size_t)m * kD + 256 + tid] = v1;
  float s1 = v0 + v1, s2 = v0 * v0 + v1 * v1;
#pragma unroll
  for (int o = 1; o < 64; o <<= 1) { s1 += __shfl_xor(s1, o, 64); s2 += __shfl_xor(s2, o, 64); }
  __shared__ float a1[4], a2[4];
  if ((tid & 63) == 0) { a1[tid >> 6] = s1; a2[tid >> 6] = s2; }
  __syncthreads();
  float t1 = a1[0] + a1[1] + a1[2] + a1[3];
  float t2 = a2[0] + a2[1] + a2[2] + a2[3];
  float mu = t1 * (1.f / kD);
  float var = t2 * (1.f / kD) - mu * mu;
  float rs = rsqrtf(var + 1e-5f);
  h[(size_t)m * kD + tid] = f2bf((v0 - mu) * rs * lnw[tid]);
  h[(size_t)m * kD + 256 + tid] = f2bf((v1 - mu) * rs * lnw[256 + tid]);
}

// ======================= layernorm (D=512, scale only) -> bf16 =======================
__global__ __launch_bounds__(256) void ln_kernel(
    const float* __restrict__ x, const float* __restrict__ w, unsigned short* __restrict__ h) {
  int m = blockIdx.x, tid = threadIdx.x;
  float v0 = x[(size_t)m * kD + tid];
  float v1 = x[(size_t)m * kD + 256 + tid];
  float s1 = v0 + v1, s2 = v0 * v0 + v1 * v1;
#pragma unroll
  for (int o = 1; o < 64; o <<= 1) { s1 += __shfl_xor(s1, o, 64); s2 += __shfl_xor(s2, o, 64); }
  __shared__ float a1[4], a2[4];
  if ((tid & 63) == 0) { a1[tid >> 6] = s1; a2[tid >> 6] = s2; }
  __syncthreads();
  float t1 = a1[0] + a1[1] + a1[2] + a1[3];
  float t2 = a2[0] + a2[1] + a2[2] + a2[3];
  float mu = t1 * (1.f / kD);
  float var = t2 * (1.f / kD) - mu * mu;
  float rs = rsqrtf(var + 1e-5f);
  h[(size_t)m * kD + tid] = f2bf((v0 - mu) * rs * w[tid]);
  h[(size_t)m * kD + 256 + tid] = f2bf((v1 - mu) * rs * w[256 + tid]);
}

// ============ merged one-time weight prep: up-T (0..1023), dn-T (1024..1535), gates (1536..1583)
__global__ __launch_bounds__(256) void tpose_all_kernel(
    const float* __restrict__ upW, const float* __restrict__ dnW,
    const float* __restrict__ igW, const float* __restrict__ fgW,
    unsigned short* __restrict__ upWT, unsigned short* __restrict__ dnWT,
    unsigned short* __restrict__ gWT) {
  __shared__ float t[64][65];
  int id = blockIdx.x, tid = threadIdx.x;
  if (id < 1024) {
    int l = id >> 8, rem = id & 255;
    int n0 = (rem >> 3) * 64, k0 = (rem & 7) * 64;
    const float* Wl = upW + (size_t)l * 2048 * 512;
    unsigned short* WTl = upWT + (size_t)l * 2048 * 512;
    for (int idx = tid; idx < 4096; idx += 256) {
      int r = idx >> 6, c = idx & 63;
      t[r][c] = Wl[(size_t)(k0 + r) * 2048 + n0 + c];
    }
    __syncthreads();
    for (int idx = tid; idx < 4096; idx += 256) {
      int r = idx >> 6, c = idx & 63;
      WTl[(size_t)(n0 + r) * 512 + k0 + c] = f2bf(t[c][r]);
    }
  } else if (id < 1536) {
    int tt = id - 1024;
    int l = tt >> 7, rem = tt & 127;
    int n0 = (rem >> 4) * 64, k0 = (rem & 15) * 64;
    const float* Wl = dnW + (size_t)l * 512 * 1024;
    unsigned short* WTl = dnWT + (size_t)l * 512 * 1024;
    for (int idx = tid; idx < 4096; idx += 256) {
      int r = idx >> 6, c = idx & 63;
      t[r][c] = Wl[(size_t)(k0 + r) * 512 + n0 + c];
    }
    __syncthreads();
    for (int idx = tid; idx < 4096; idx += 256) {
      int r = idx >> 6, c = idx & 63;
      WTl[(size_t)(n0 + r) * 1024 + k0 + c] = f2bf(t[c][r]);
    }
  } else {
    int tt = id - 1536;
    int l = tt / 12, kc = tt % 12;
    int k = kc * 256 + tid;
    const float* igl = igW + (size_t)l * 3072 * 8;
    const float* fgl = fgW + (size_t)l * 3072 * 8;
    unsigned short* gl = gWT + (size_t)l * 16 * 3072;
#pragma unroll
    for (int h = 0; h < 8; ++h) {
      gl[(size_t)h * 3072 + k] = f2bf(igl[(size_t)k * 8 + h]);
      gl[(size_t)(8 + h) * 3072 + k] = f2bf(fgl[(size_t)k * 8 + h]);
    }
  }
}

// ======================= bf16 MFMA GEMM: C[M,N] = A[M,Kd] @ BT[N,Kd]^T + bias (+C) ========
template <int BM, int NBN, int RESID, typename TO>
__global__ __launch_bounds__(256) void gemm_mfma_kernel(
    const unsigned short* __restrict__ A, const unsigned short* __restrict__ BT,
    const float* __restrict__ bias, TO* __restrict__ C, int N, int Kd, int nwg) {
  constexpr int A_ISS = BM / 8;
  constexpr int PER_W = (A_ISS + 16) / 4;
  constexpr int MR = BM / 32;
  __shared__ __align__(16) char As[BM * 128];
  __shared__ __align__(16) char Bs[16384];
  int tid = threadIdx.x, w = tid >> 6, l = tid & 63;
  int lr = l & 15, lg = l >> 4;
  int id = blockIdx.x;
  int q = nwg >> 3, r = nwg & 7;
  int xcd = id & 7, pos = id >> 3;
  int wg = (xcd < r ? xcd * (q + 1) : r * (q + 1) + (xcd - r) * q) + pos;
  int bn = wg % NBN, bm = wg / NBN;
  int wrow = (w >> 1) * (BM / 2), wcol = (w & 1) * 64;
  f32x4 acc[MR][4] = {};
  for (int kt = 0; kt < Kd; kt += 64) {
    __syncthreads();
#pragma unroll
    for (int j = 0; j < PER_W; ++j) {
      int g = w * PER_W + j;
      bool isA = g < A_ISS;
      int ii = isA ? g : g - A_ISS;
      int row = ii * 8 + (l >> 3);
      int chunk = (l & 7) ^ (row & 7);
      const unsigned short* src = isA
          ? A + ((size_t)(bm * BM + row) * Kd + kt) + chunk * 8
          : BT + ((size_t)(bn * 128 + row) * Kd + kt) + chunk * 8;
      char* dst = (isA ? As : Bs) + ii * 1024;
      gload16(src, dst);
    }
    __syncthreads();
#pragma unroll
    for (int kk = 0; kk < 2; ++kk) {
      bf16x8 af[MR], bfr[4];
#pragma unroll
      for (int m = 0; m < MR; ++m) {
        int row = wrow + m * 16 + lr;
        int ch = (kk * 4 + lg) ^ (row & 7);
        af[m] = *(const bf16x8*)(As + row * 128 + ch * 16);
      }
#pragma unroll
      for (int n = 0; n < 4; ++n) {
        int row = wcol + n * 16 + lr;
        int ch = (kk * 4 + lg) ^ (row & 7);
        bfr[n] = *(const bf16x8*)(Bs + row * 128 + ch * 16);
      }
      __builtin_amdgcn_s_setprio(1);
#pragma unroll
      for (int m = 0; m < MR; ++m)
#pragma unroll
        for (int n = 0; n < 4; ++n)
          acc[m][n] = MFMA_BF16(af[m], bfr[n], acc[m][n]);
      __builtin_amdgcn_s_setprio(0);
    }
  }
#pragma unroll
  for (int n = 0; n < 4; ++n) {
    int col = bn * 128 + wcol + n * 16 + lr;
    float bv = bias[col];
#pragma unroll
    for (int m = 0; m < MR; ++m)
#pragma unroll
      for (int i = 0; i < 4; ++i) {
        int row = bm * BM + wrow + m * 16 + lg * 4 + i;
        float v = acc[m][n][i] + bv;
        if constexpr (sizeof(TO) == 2) {
          C[(size_t)row * N + col] = (TO)f2bf(v);
        } else {
          if (RESID) v += C[(size_t)row * N + col];
          C[(size_t)row * N + col] = v;
        }
      }
  }
}

// ==== fused causal conv(K=4)+silu + headwise q,k,v; 4 consecutive s per block ====
__global__ __launch_bounds__(256) void convhead_kernel(
    const unsigned short* __restrict__ u, const float* __restrict__ cw,
    const float* __restrict__ cb,
    const float* __restrict__ Wq, const float* __restrict__ Wk, const float* __restrict__ Wv,
    unsigned short* __restrict__ xcb, unsigned short* __restrict__ qb,
    unsigned short* __restrict__ kb, unsigned short* __restrict__ vb) {
  int mb = blockIdx.x;
  int b = mb >> 7, sq = (mb & 127) * 4;
  int n = threadIdx.x;  // channels n*4 .. n*4+3
  float xm[7][4];
#pragma unroll
  for (int j = 0; j < 7; ++j) {
    int sp = sq - 3 + j;
    if (sp >= 0) {
      unsigned long long raw = *(const unsigned long long*)&u[((size_t)(b * kS + sp)) * (2 * kI) + n * 4];
#pragma unroll
      for (int i = 0; i < 4; ++i) xm[j][i] = bf2f((unsigned short)(raw >> (i * 16)));
    } else {
#pragma unroll
      for (int i = 0; i < 4; ++i) xm[j][i] = 0.f;
    }
  }
  float4 cb4 = *(const float4*)&cb[n * 4];
  const float* cbp = &cb4.x;
  float cwv[4][4];
#pragma unroll
  for (int i = 0; i < 4; ++i) *(float4*)cwv[i] = *(const float4*)&cw[(n * 4 + i) * 4];
  float wqv[16], wkv[16], wvv[16];
#pragma unroll
  for (int o2 = 0; o2 < 4; ++o2) {
    *(float4*)&wqv[o2 * 4] = *(const float4*)&Wq[n * 16 + o2 * 4];
    *(float4*)&wkv[o2 * 4] = *(const float4*)&Wk[n * 16 + o2 * 4];
    *(float4*)&wvv[o2 * 4] = *(const float4*)&Wv[n * 16 + o2 * 4];
  }
#pragma unroll
  for (int t = 0; t < 4; ++t) {
    int s = sq + t;
    float xc[4];
    unsigned long long xcv = 0;
#pragma unroll
    for (int i = 0; i < 4; ++i) {
      float acc = cbp[i] + xm[t][i] * cwv[i][0] + xm[t + 1][i] * cwv[i][1] +
                  xm[t + 2][i] * cwv[i][2] + xm[t + 3][i] * cwv[i][3];
      xc[i] = acc / (1.f + __expf(-acc));
      xcv |= (unsigned long long)f2bf(xc[i]) << (i * 16);
    }
    *(unsigned long long*)&xcb[((size_t)(b * kS + s)) * kI + n * 4] = xcv;
    unsigned long long qv = 0, kv = 0, vv = 0;
#pragma unroll
    for (int o = 0; o < 4; ++o) {
      float aq = 0, ak = 0, av = 0;
#pragma unroll
      for (int i = 0; i < 4; ++i) {
        aq += xc[i] * wqv[o * 4 + i];
        ak += xc[i] * wkv[o * 4 + i];
        av += xm[t + 3][i] * wvv[o * 4 + i];
      }
      qv |= (unsigned long long)f2bf(aq) << (o * 16);
      kv |= (unsigned long long)f2bf(ak) << (o * 16);
      vv |= (unsigned long long)f2bf(av) << (o * 16);
    }
    size_t base = ((size_t)(b * 8 + (n >> 5)) * kS + s) * kDH + (n & 31) * 4;
    *(unsigned long long*)&qb[base] = qv;
    *(unsigned long long*)&kb[base] = kv;
    *(unsigned long long*)&vb[base] = vv;
  }
}

// ============ merged prep: gates MFMA (blocks 0..191) + V transpose (blocks 192..703) ====
__global__ __launch_bounds__(256) void prep_kernel(
    const unsigned short* __restrict__ qb, const unsigned short* __restrict__ kb,
    const unsigned short* __restrict__ vb, const unsigned short* __restrict__ gWT,
    float* __restrict__ IGp, float* __restrict__ FGp, unsigned short* __restrict__ vt) {
  __shared__ __align__(16) char smem[16640];
  int id = blockIdx.x;
  int tid = threadIdx.x;
  if (id < 192) {
    int src = id >> 6;
    int blk = id & 63;
    int b = blk >> 3, s0 = (blk & 7) * 64;
    int w = tid >> 6, l = tid & 63;
    int lr = l & 15, lg = l >> 4;
    char* Ts = smem;
    const unsigned short* srcb = (src == 0) ? qb : (src == 1) ? kb : vb;
    f32x4 acc = {};
    for (int kc8 = 0; kc8 < 8; ++kc8) {
      const unsigned short* srcbase = srcb + ((size_t)(b * 8 + kc8) * kS + s0) * kDH;
      __syncthreads();
#pragma unroll
      for (int j = 0; j < 4; ++j) {
        int issue = w * 4 + j;
        int row = issue * 4 + (l >> 4);
        int chunk = (l & 15) ^ (row & 7);
        gload16(srcbase + row * 128 + chunk * 8, Ts + issue * 1024);
      }
      __syncthreads();
#pragma unroll
      for (int kk = 0; kk < 4; ++kk) {
        int arow = w * 16 + lr;
        int ch = (kk * 4 + lg) ^ (arow & 7);
        bf16x8 af = *(const bf16x8*)(Ts + arow * 256 + ch * 16);
        bf16x8 bfv = *(const bf16x8*)(gWT + (size_t)lr * 3072 + (src * 8 + kc8) * 128 + kk * 32 + lg * 8);
        acc = MFMA_BF16(af, bfv, acc);
      }
    }
    float* IGo = IGp + (size_t)src * 64 * kS;
    float* FGo = FGp + (size_t)src * 64 * kS;
#pragma unroll
    for (int i = 0; i < 4; ++i) {
      int s = s0 + w * 16 + lg * 4 + i;
      if (lr < 8) IGo[((size_t)(b * 8) + lr) * kS + s] = acc[i];
      else FGo[((size_t)(b * 8) + lr - 8) * kS + s] = acc[i];
    }
  } else {
    int t = id - 192;
    int bh = t >> 3, s0 = (t & 7) * 64;
    unsigned short (*tt)[130] = (unsigned short(*)[130])smem;
    for (int idx = tid; idx < 64 * 128; idx += 256) {
      int sl = idx >> 7, d = idx & 127;
      tt[sl][d] = vb[((size_t)bh * kS + s0 + sl) * kDH + d];
    }
    __syncthreads();
    for (int idx = tid; idx < 64 * 128; idx += 256) {
      int dl = idx >> 6, sl = idx & 63;
      vt[((size_t)bh * kDH + dl) * kS + s0 + sl] = tt[sl][dl];
    }
  }
}

// ======================= mLSTM parallel via MFMA, fused scan + mh_norm/skip/gate ==========
// grid 256, 8 waves/block. Waves 0-3 compute row-tile rtA=7-pr, waves 4-7 rtB=pr,
// sharing one double-buffered K/V staging stream (ct = 0..rtA). XCD-swizzled.
// Per-head scan (inc/a/pmax) computed in-block from gate partials (hidden under tile-0 DMA).
__global__ __launch_bounds__(512) void mlstm_mfma_kernel(
    const unsigned short* __restrict__ qb, const unsigned short* __restrict__ kb,
    const unsigned short* __restrict__ vt,
    const float* __restrict__ IGp, const float* __restrict__ FGp,
    const float* __restrict__ igb, const float* __restrict__ fgb,
    const unsigned short* __restrict__ u, const unsigned short* __restrict__ xcb,
    const float* __restrict__ onw, const float* __restrict__ skw,
    unsigned short* __restrict__ hhb) {
  int id = blockIdx.x;
  int bh = (id & 7) * 8 + ((id >> 3) & 7);  // each XCD sees only 8 heads
  int pr = id >> 6;                          // 0..3
  int rtA = 7 - pr, rtB = pr;
  int b = bh >> 3, nh = bh & 7;
  int tid = threadIdx.x, w = tid >> 6, l = tid & 63;
  int g = w >> 2, wl = w & 3;
  int rt = (g == 0) ? rtA : rtB;
  int lr = l & 15, lg = l >> 4;
  __shared__ __align__(16) char Ks[2][16384];  // [64 s][128 d] bf16, RB=256
  __shared__ __align__(16) char Vs[2][16384];  // [128 d][64 s] bf16, RB=128
  __shared__ __align__(16) char Ps[8][2048];   // per-wave [16][64] bf16, RB=128
  __shared__ float avs[512], incs[512], pms[512];
  __shared__ float wsum[8], wmax[8];

  const unsigned short* kbh = kb + (size_t)bh * kS * kDH;
  const unsigned short* vbh = vt + (size_t)bh * kDH * kS;

  // prologue: stage tile 0 into buffer 0 (all 8 waves: 2 K-issues + 2 V-issues each)
#pragma unroll
  for (int j = 0; j < 2; ++j) {
    int issue = w * 2 + j;
    int row = issue * 4 + (l >> 4);
    int chunk = (l & 15) ^ (row & 7);
    gload16(kbh + row * 128 + chunk * 8, Ks[0] + issue * 1024);
  }
#pragma unroll
  for (int j = 0; j < 2; ++j) {
    int vi = w * 2 + j;
    int row = vi * 8 + (l >> 3);
    int chunk = (l & 7) ^ (row & 7);
    gload16(vbh + (size_t)row * kS + chunk * 8, Vs[0] + vi * 1024);
  }

  // ---- in-block scan for this head (hidden under tile-0 DMA) ----
  {
    int lane = tid & 63, wid2 = tid >> 6;
    const size_t ss = (size_t)64 * kS;
    size_t o = (size_t)bh * kS + tid;
    float igv = IGp[o] + IGp[ss + o] + IGp[2 * ss + o] + igb[nh];
    float fgv = FGp[o] + FGp[ss + o] + FGp[2 * ss + o] + fgb[nh];
    float lf = fminf(fgv, 0.f) - log1pf(__expf(-fabsf(fgv)));
    float x = lf;
#pragma unroll
    for (int off = 1; off < 64; off <<= 1) {
      float v = __shfl_up(x, off, 64);
      if (lane >= off) x += v;
    }
    if (lane == 63) wsum[wid2] = x;
    __syncthreads();
    float base = 0.f;
    for (int i2 = 0; i2 < wid2; ++i2) base += wsum[i2];
    float inct = x + base;
    incs[tid] = inct;
    float av = igv - inct;
    avs[tid] = 0.08838834764831845f * __expf(av);
    float y = av;
#pragma unroll
    for (int off = 1; off < 64; off <<= 1) {
      float v = __shfl_up(y, off, 64);
      if (lane >= off) y = fmaxf(y, v);
    }
    if (lane == 63) wmax[wid2] = y;
    __syncthreads();
    float mb2 = y;
    for (int i2 = 0; i2 < wid2; ++i2) mb2 = fmaxf(mb2, wmax[i2]);
    pms[tid] = mb2;
  }

  bf16x8 qf[4];
  int qrow = rt * 64 + wl * 16 + lr;
  const unsigned short* qrp = qb + ((size_t)bh * kS + qrow) * kDH + lg * 8;
#pragma unroll
  for (int kk = 0; kk < 4; ++kk) qf[kk] = *(const bf16x8*)(qrp + kk * 32);

  __syncthreads();  // scan results + tile-0 staging visible

  float pm_r[4], epm[4];
#pragma unroll
  for (int i = 0; i < 4; ++i) {
    pm_r[i] = pms[rt * 64 + wl * 16 + lg * 4 + i];
    epm[i] = __expf(-pm_r[i]);
  }

  f32x4 oacc[8] = {};
  float rsum[4] = {};

  int cur = 0;
#pragma unroll 1
  for (int ct = 0; ct <= rtA; ++ct) {
    // issue next-tile staging into the other buffer (hidden under compute)
    if (ct < rtA) {
      const unsigned short* kbase = kbh + (size_t)(ct + 1) * 64 * kDH;
      const unsigned short* vbase = vbh + (size_t)(ct + 1) * 64;
#pragma unroll
      for (int j = 0; j < 2; ++j) {
        int issue = w * 2 + j;
        int row = issue * 4 + (l >> 4);
        int chunk = (l & 15) ^ (row & 7);
        gload16(kbase + row * 128 + chunk * 8, Ks[cur ^ 1] + issue * 1024);
      }
#pragma unroll
      for (int j = 0; j < 2; ++j) {
        int vi = w * 2 + j;
        int row = vi * 8 + (l >> 3);
        int chunk = (l & 7) ^ (row & 7);
        gload16(vbase + (size_t)row * kS + chunk * 8, Vs[cur ^ 1] + vi * 1024);
      }
    }
    if (ct <= rt) {
      // QK^T
      f32x4 sacc[4] = {};
      __builtin_amdgcn_s_setprio(1);
#pragma unroll
      for (int n = 0; n < 4; ++n) {
#pragma unroll
        for (int kk = 0; kk < 4; ++kk) {
          int krow = n * 16 + lr;
          int ch = (kk * 4 + lg) ^ (krow & 7);
          bf16x8 kf = *(const bf16x8*)(Ks[cur] + krow * 256 + ch * 16);
          sacc[n] = MFMA_BF16(qf[kk], kf, sacc[n]);
        }
      }
      __builtin_amdgcn_s_setprio(0);
      // transform scores -> P (bf16 in per-wave LDS), accumulate row sums
#pragma unroll
      for (int n = 0; n < 4; ++n) {
        float eav = avs[ct * 64 + n * 16 + lr];
        int cg = ct * 64 + n * 16 + lr;
#pragma unroll
        for (int i = 0; i < 4; ++i) {
          int rg = rt * 64 + wl * 16 + lg * 4 + i;
          float s = 0.f;
          if (ct < rt || cg <= rg)
            s = sacc[n][i] * (eav * epm[i]);
          rsum[i] += s;
          int prow = lg * 4 + i, pcol = n * 16 + lr;
          int byte = prow * 128 + ((((pcol >> 3) ^ (prow & 7))) << 4) + (pcol & 7) * 2;
          *(unsigned short*)(Ps[w] + byte) = f2bf(s);
        }
      }
      // PV
      __builtin_amdgcn_s_setprio(1);
#pragma unroll
      for (int kk = 0; kk < 2; ++kk) {
        int prow = lr;
        int pch = (kk * 4 + lg) ^ (prow & 7);
        bf16x8 pf = *(const bf16x8*)(Ps[w] + prow * 128 + pch * 16);
#pragma unroll
        for (int nb = 0; nb < 8; ++nb) {
          int vrow = nb * 16 + lr;
          int vch = (kk * 4 + lg) ^ (vrow & 7);
          bf16x8 vf = *(const bf16x8*)(Vs[cur] + vrow * 128 + vch * 16);
          oacc[nb] = MFMA_BF16(pf, vf, oacc[nb]);
        }
      }
      __builtin_amdgcn_s_setprio(0);
    }
    __syncthreads();  // drains staging DMA + protects buffer swap
    cur ^= 1;
  }

#pragma unroll
  for (int i = 0; i < 4; ++i)
#pragma unroll
    for (int off = 1; off < 16; off <<= 1) rsum[i] += __shfl_xor(rsum[i], off, 16);
  float ninv[4];
#pragma unroll
  for (int i = 0; i < 4; ++i) {
    int rg = rt * 64 + wl * 16 + lg * 4 + i;
    float e0 = __expf(-incs[rg] - pm_r[i]);
    float nn = fmaxf(fabsf(rsum[i]), e0);
    ninv[i] = 1.f / (nn + 1e-6f);
  }
  // ---- fused mh_norm (LN over DH=128 within 16-lane groups) + skip + output gate ----
  float val[8][4];
  float s1[4] = {}, s2[4] = {};
#pragma unroll
  for (int nb = 0; nb < 8; ++nb)
#pragma unroll
    for (int i = 0; i < 4; ++i) {
      float v = oacc[nb][i] * ninv[i];
      val[nb][i] = v;
      s1[i] += v; s2[i] += v * v;
    }
#pragma unroll
  for (int i = 0; i < 4; ++i) {
#pragma unroll
    for (int off = 1; off < 16; off <<= 1) {
      s1[i] += __shfl_xor(s1[i], off, 16);
      s2[i] += __shfl_xor(s2[i], off, 16);
    }
  }
#pragma unroll
  for (int i = 0; i < 4; ++i) {
    int rg = rt * 64 + wl * 16 + lg * 4 + i;
    float mu = s1[i] * (1.f / 128.f);
    float var = s2[i] * (1.f / 128.f) - mu * mu;
    float rstd = rsqrtf(var + 1e-5f);
    size_t rowbase = (size_t)(b * kS + rg);
#pragma unroll
    for (int nb = 0; nb < 8; ++nb) {
      int c = nh * kDH + nb * 16 + lr;
      float nv = (val[nb][i] - mu) * rstd * onw[c];
      float z = bf2f(u[rowbase * (2 * kI) + kI + c]);
      float sz = z / (1.f + __expf(-z));
      float xcv = bf2f(xcb[rowbase * kI + c]);
      hhb[rowbase * kI + c] = f2bf((nv + skw[c] * xcv) * sz);
    }
  }
}

// ======================= post-norm + head projection (last 96 rows/batch) =======================
__global__ __launch_bounds__(256) void head_kernel(
    const float* __restrict__ x, const float* __restrict__ pw,
    const float* __restrict__ hW, const float* __restrict__ hb, float* __restrict__ out) {
  int row = blockIdx.x;  // 0..767
  int b = row / kPRED, p = row % kPRED;
  int m = b * kS + (kS - kPRED) + p;
  int tid = threadIdx.x;
  float v0 = x[(size_t)m * kD + tid];
  float v1 = x[(size_t)m * kD + 256 + tid];
  float s1 = v0 + v1, s2 = v0 * v0 + v1 * v1;
#pragma unroll
  for (int o = 1; o < 64; o <<= 1) { s1 += __shfl_xor(s1, o, 64); s2 += __shfl_xor(s2, o, 64); }
  __shared__ float a1[4], a2[4];
  if ((tid & 63) == 0) { a1[tid >> 6] = s1; a2[tid >> 6] = s2; }
  __syncthreads();
  float t1 = a1[0] + a1[1] + a1[2] + a1[3];
  float t2 = a2[0] + a2[1] + a2[2] + a2[3];
  float mu = t1 * (1.f / kD);
  float var = t2 * (1.f / kD) - mu * mu;
  float rs = rsqrtf(var + 1e-5f);
  __shared__ float buf[512];
  buf[tid] = (v0 - mu) * rs * pw[tid];
  buf[256 + tid] = (v1 - mu) * rs * pw[256 + tid];
  __syncthreads();
  float acc[7] = {};
  for (int kk = tid; kk < 512; kk += 256) {
    float g = buf[kk];
#pragma unroll
    for (int n = 0; n < 7; ++n) acc[n] += g * hW[kk * 7 + n];
  }
  __shared__ float red[256 * 9];
#pragma unroll
  for (int n = 0; n < 7; ++n) red[tid * 9 + n] = acc[n];
  __syncthreads();
  for (int off = 128; off >= 1; off >>= 1) {
    if (tid < off) {
#pragma unroll
      for (int n = 0; n < 7; ++n) red[tid * 9 + n] += red[(tid + off) * 9 + n];
    }
    __syncthreads();
  }
  if (tid < 7) out[(size_t)row * 7 + tid] = red[tid] + hb[tid];
}

// ======================= host launch =======================
extern "C" void kernel_launch(void* const* d_in, const int* in_sizes, int n_in,
                              void* d_out, int out_size, void* d_ws, size_t ws_size,
                              hipStream_t stream) {
  const float* x_enc    = (const float*)d_in[0];
  const float* x_mark   = (const float*)d_in[1];
  const float* emb_W    = (const float*)d_in[4];
  const float* emb_b    = (const float*)d_in[5];
  const float* blk_ln_w = (const float*)d_in[6];
  const float* up_W     = (const float*)d_in[7];
  const float* up_b     = (const float*)d_in[8];
  const float* conv_w   = (const float*)d_in[9];
  const float* conv_b   = (const float*)d_in[10];
  const float* Wq       = (const float*)d_in[11];
  const float* Wk       = (const float*)d_in[12];
  const float* Wv       = (const float*)d_in[13];
  const float* ig_W     = (const float*)d_in[14];
  const float* ig_b     = (const float*)d_in[15];
  const float* fg_W     = (const float*)d_in[16];
  const float* fg_b     = (const float*)d_in[17];
  const float* onorm_w  = (const float*)d_in[18];
  const float* skip_w   = (const float*)d_in[19];
  const float* down_W   = (const float*)d_in[20];
  const float* down_b   = (const float*)d_in[21];
  const float* post_w   = (const float*)d_in[22];
  const float* head_W   = (const float*)d_in[23];
  const float* head_b   = (const float*)d_in[24];
  float* out = (float*)d_out;

  char* ws = (char*)d_ws;
  float* X  = (float*)ws;                     ws += (size_t)kM * kD * 4;        // 8 MB
  unsigned short* U    = (unsigned short*)ws; ws += (size_t)kM * 2 * kI * 2;    // 16 MB
  unsigned short* XCb  = (unsigned short*)ws; ws += (size_t)kM * kI * 2;        // 8 MB
  unsigned short* Hb   = (unsigned short*)ws; ws += (size_t)kM * kD * 2;        // 4 MB
  unsigned short* HHb  = (unsigned short*)ws; ws += (size_t)kM * kI * 2;        // 8 MB
  unsigned short* qb   = (unsigned short*)ws; ws += (size_t)kM * kI * 2;        // 8 MB
  unsigned short* kbuf = (unsigned short*)ws; ws += (size_t)kM * kI * 2;        // 8 MB
  unsigned short* vb   = (unsigned short*)ws; ws += (size_t)kM * kI * 2;        // 8 MB
  unsigned short* vt   = (unsigned short*)ws; ws += (size_t)kM * kI * 2;        // 8 MB
  unsigned short* upWT = (unsigned short*)ws; ws += (size_t)kL * 2 * kI * kD * 2; // 8 MB
  unsigned short* dnWT = (unsigned short*)ws; ws += (size_t)kL * kD * kI * 2;   // 4 MB
  unsigned short* gWT  = (unsigned short*)ws; ws += (size_t)kL * 16 * 3072 * 2; // 384 KB
  float* IGp = (float*)ws; ws += (size_t)3 * 64 * kS * 4;
  float* FGp = (float*)ws; ws += (size_t)3 * 64 * kS * 4;

  embed_ln_kernel<<<kM, 256, 0, stream>>>(x_enc, x_mark, emb_W, emb_b, blk_ln_w, X, Hb);
  tpose_all_kernel<<<1584, 256, 0, stream>>>(up_W, down_W, ig_W, fg_W, upWT, dnWT, gWT);

  for (int l = 0; l < kL; ++l) {
    const float* lnw  = blk_ln_w + (size_t)l * kD;
    const float* upbl = up_b + (size_t)l * 2 * kI;
    const float* cwl  = conv_w + (size_t)l * kI * 4;
    const float* cbl  = conv_b + (size_t)l * kI;
    const float* wql  = Wq + (size_t)l * 256 * 16;
    const float* wkl  = Wk + (size_t)l * 256 * 16;
    const float* wvl  = Wv + (size_t)l * 256 * 16;
    const float* igbl = ig_b + (size_t)l * kNH;
    const float* fgbl = fg_b + (size_t)l * kNH;
    const float* onwl = onorm_w + (size_t)l * kI;
    const float* skwl = skip_w + (size_t)l * kI;
    const float* dbl  = down_b + (size_t)l * kD;
    const unsigned short* upWTl = upWT + (size_t)l * 2 * kI * kD;
    const unsigned short* dnWTl = dnWT + (size_t)l * kD * kI;
    const unsigned short* gWTl  = gWT + (size_t)l * 16 * 3072;

    if (l > 0) ln_kernel<<<kM, 256, 0, stream>>>(X, lnw, Hb);
    gemm_mfma_kernel<128, 16, 0, unsigned short><<<512, 256, 0, stream>>>(
        Hb, upWTl, upbl, U, 2 * kI, kD, 512);
    convhead_kernel<<<1024, 256, 0, stream>>>(U, cwl, cbl, wql, wkl, wvl, XCb, qb, kbuf, vb);
    prep_kernel<<<704, 256, 0, stream>>>(qb, kbuf, vb, gWTl, IGp, FGp, vt);
    mlstm_mfma_kernel<<<256, 512, 0, stream>>>(
        qb, kbuf, vt, IGp, FGp, igbl, fgbl, U, XCb, onwl, skwl, HHb);
    gemm_mfma_kernel<64, 4, 1, float><<<256, 256, 0, stream>>>(
        HHb, dnWTl, dbl, X, kD, kI, 256);
  }

  head_kernel<<<kB * kPRED, 256, 0, stream>>>(X, post_w, head_W, head_b, out);
}

// Round 10
// 383.301 us; speedup vs baseline: 5.9441x; 1.0134x over previous
//
#include <hip/hip_runtime.h>
#include <math.h>

// ---- dims ----
static constexpr int kB = 8, kS = 512;
static constexpr int kD = 512, kI = 1024, kNH = 8, kDH = 128;
static constexpr int kL = 4, kPRED = 96, kCOUT = 7;
static constexpr int kM = kB * kS; // 4096 rows

typedef __bf16 bf16x8 __attribute__((ext_vector_type(8)));
typedef float f32x4 __attribute__((ext_vector_type(4)));

#define MFMA_BF16(a, b, c) __builtin_amdgcn_mfma_f32_16x16x32_bf16((a), (b), (c), 0, 0, 0)

typedef __attribute__((address_space(1))) const unsigned char* as1cp;
typedef __attribute__((address_space(3))) unsigned char* as3p;
__device__ __forceinline__ void gload16(const void* g, void* l) {
  __builtin_amdgcn_global_load_lds((as1cp)g, (as3p)l, 16, 0, 0);
}

__device__ __forceinline__ unsigned short f2bf(float f) {
  union { float f; unsigned u; } v; v.f = f;
  unsigned r = v.u + 0x7fffu + ((v.u >> 16) & 1u);
  return (unsigned short)(r >> 16);
}
__device__ __forceinline__ float bf2f(unsigned short h) {
  union { unsigned u; float f; } v; v.u = (unsigned)h << 16; return v.f;
}

// ================== init: embed(+stats) | up-T(gamma-folded) | dn-T | gates-T | colsum ====
// grid: [0,4096) embed; [4096,5120) upT; [5120,5632) dnT; [5632,5680) gates; [5680,5712) colsum
__global__ __launch_bounds__(256) void init_kernel(
    const float* __restrict__ xe, const float* __restrict__ xme,
    const float* __restrict__ embW, const float* __restrict__ embb,
    const float* __restrict__ lnw_all,
    const float* __restrict__ upW, const float* __restrict__ dnW,
    const float* __restrict__ igW, const float* __restrict__ fgW,
    float* __restrict__ x, unsigned short* __restrict__ xb,
    float* __restrict__ st1, float* __restrict__ st2,
    unsigned short* __restrict__ upWT, unsigned short* __restrict__ dnWT,
    unsigned short* __restrict__ gWT, float* __restrict__ colsum) {
  __shared__ float t[64][65];
  __shared__ float f[11], a1[4], a2[4];
  int id = blockIdx.x, tid = threadIdx.x;
  if (id < 4096) {
    int m = id;
    if (tid < 7) f[tid] = xe[m * 7 + tid];
    else if (tid < 11) f[tid] = xme[m * 4 + (tid - 7)];
    __syncthreads();
    float v0 = embb[tid], v1 = embb[256 + tid];
#pragma unroll
    for (int e = 0; e < 11; ++e) {
      v0 += f[e] * embW[e * kD + tid];
      v1 += f[e] * embW[e * kD + 256 + tid];
    }
    x[(size_t)m * kD + tid] = v0;
    x[(size_t)m * kD + 256 + tid] = v1;
    xb[(size_t)m * kD + tid] = f2bf(v0);
    xb[(size_t)m * kD + 256 + tid] = f2bf(v1);
    float s1 = v0 + v1, s2 = v0 * v0 + v1 * v1;
#pragma unroll
    for (int o = 1; o < 64; o <<= 1) { s1 += __shfl_xor(s1, o, 64); s2 += __shfl_xor(s2, o, 64); }
    if ((tid & 63) == 0) { a1[tid >> 6] = s1; a2[tid >> 6] = s2; }
    __syncthreads();
    if (tid == 0) {
      st1[m] = a1[0] + a1[1] + a1[2] + a1[3];
      st2[m] = a2[0] + a2[1] + a2[2] + a2[3];
    } else if (tid < 4) {
      st1[tid * 4096 + m] = 0.f;
      st2[tid * 4096 + m] = 0.f;
    }
  } else if (id < 5120) {
    int tt = id - 4096;
    int l = tt >> 8, rem = tt & 255;
    int n0 = (rem >> 3) * 64, k0 = (rem & 7) * 64;
    const float* Wl = upW + (size_t)l * 2048 * 512;
    const float* lnw = lnw_all + (size_t)l * kD;
    unsigned short* WTl = upWT + (size_t)l * 2048 * 512;
    for (int idx = tid; idx < 4096; idx += 256) {
      int r = idx >> 6, c = idx & 63;
      t[r][c] = Wl[(size_t)(k0 + r) * 2048 + n0 + c];
    }
    __syncthreads();
    for (int idx = tid; idx < 4096; idx += 256) {
      int r = idx >> 6, c = idx & 63;
      WTl[(size_t)(n0 + r) * 512 + k0 + c] = f2bf(lnw[k0 + c] * t[c][r]);
    }
  } else if (id < 5632) {
    int tt = id - 5120;
    int l = tt >> 7, rem = tt & 127;
    int n0 = (rem >> 4) * 64, k0 = (rem & 15) * 64;
    const float* Wl = dnW + (size_t)l * 512 * 1024;
    unsigned short* WTl = dnWT + (size_t)l * 512 * 1024;
    for (int idx = tid; idx < 4096; idx += 256) {
      int r = idx >> 6, c = idx & 63;
      t[r][c] = Wl[(size_t)(k0 + r) * 512 + n0 + c];
    }
    __syncthreads();
    for (int idx = tid; idx < 4096; idx += 256) {
      int r = idx >> 6, c = idx & 63;
      WTl[(size_t)(n0 + r) * 1024 + k0 + c] = f2bf(t[c][r]);
    }
  } else if (id < 5680) {
    int tt = id - 5632;
    int l = tt / 12, kc = tt % 12;
    int k = kc * 256 + tid;
    const float* igl = igW + (size_t)l * 3072 * 8;
    const float* fgl = fgW + (size_t)l * 3072 * 8;
    unsigned short* gl = gWT + (size_t)l * 16 * 3072;
#pragma unroll
    for (int h = 0; h < 8; ++h) {
      gl[(size_t)h * 3072 + k] = f2bf(igl[(size_t)k * 8 + h]);
      gl[(size_t)(8 + h) * 3072 + k] = f2bf(fgl[(size_t)k * 8 + h]);
    }
  } else {
    int tt = id - 5680;
    int l = tt >> 3, n = (tt & 7) * 256 + tid;
    const float* Wl = upW + (size_t)l * 2048 * 512;
    const float* lnw = lnw_all + (size_t)l * kD;
    float cs = 0.f;
    for (int k = 0; k < 512; ++k)
      cs += bf2f(f2bf(lnw[k] * Wl[(size_t)k * 2048 + n]));
    colsum[(size_t)l * 2048 + n] = cs;
  }
}

// ============== up-GEMM: U = LNfactored(X) @ upWT'^T + bias  (BM=128, NBN=16) =============
// C[m][n] = rs_m*(acc - mu_m*colsum[n]) + bias[n], stats from st1/st2 partials [4][4096].
__global__ __launch_bounds__(256) void gemm_up_kernel(
    const unsigned short* __restrict__ A, const unsigned short* __restrict__ BT,
    const float* __restrict__ bias, const float* __restrict__ colsum,
    const float* __restrict__ st1, const float* __restrict__ st2,
    unsigned short* __restrict__ C, int nwg) {
  constexpr int BM = 128, NBN = 16, Kd = 512, N = 2048;
  constexpr int A_ISS = BM / 8, PER_W = (A_ISS + 16) / 4, MR = BM / 32;
  __shared__ __align__(16) char As[BM * 128];
  __shared__ __align__(16) char Bs[16384];
  int tid = threadIdx.x, w = tid >> 6, l = tid & 63;
  int lr = l & 15, lg = l >> 4;
  int id = blockIdx.x;
  int q = nwg >> 3, r = nwg & 7;
  int xcd = id & 7, pos = id >> 3;
  int wg = (xcd < r ? xcd * (q + 1) : r * (q + 1) + (xcd - r) * q) + pos;
  int bn = wg % NBN, bm = wg / NBN;
  int wrow = (w >> 1) * (BM / 2), wcol = (w & 1) * 64;
  f32x4 acc[MR][4] = {};
  for (int kt = 0; kt < Kd; kt += 64) {
    __syncthreads();
#pragma unroll
    for (int j = 0; j < PER_W; ++j) {
      int g = w * PER_W + j;
      bool isA = g < A_ISS;
      int ii = isA ? g : g - A_ISS;
      int row = ii * 8 + (l >> 3);
      int chunk = (l & 7) ^ (row & 7);
      const unsigned short* src = isA
          ? A + ((size_t)(bm * BM + row) * Kd + kt) + chunk * 8
          : BT + ((size_t)(bn * 128 + row) * Kd + kt) + chunk * 8;
      char* dst = (isA ? As : Bs) + ii * 1024;
      gload16(src, dst);
    }
    __syncthreads();
#pragma unroll
    for (int kk = 0; kk < 2; ++kk) {
      bf16x8 af[MR], bfr[4];
#pragma unroll
      for (int m = 0; m < MR; ++m) {
        int row = wrow + m * 16 + lr;
        int ch = (kk * 4 + lg) ^ (row & 7);
        af[m] = *(const bf16x8*)(As + row * 128 + ch * 16);
      }
#pragma unroll
      for (int n = 0; n < 4; ++n) {
        int row = wcol + n * 16 + lr;
        int ch = (kk * 4 + lg) ^ (row & 7);
        bfr[n] = *(const bf16x8*)(Bs + row * 128 + ch * 16);
      }
      __builtin_amdgcn_s_setprio(1);
#pragma unroll
      for (int m = 0; m < MR; ++m)
#pragma unroll
        for (int n = 0; n < 4; ++n)
          acc[m][n] = MFMA_BF16(af[m], bfr[n], acc[m][n]);
      __builtin_amdgcn_s_setprio(0);
    }
  }
  float mu_r[MR][4], rs_r[MR][4];
#pragma unroll
  for (int m = 0; m < MR; ++m)
#pragma unroll
    for (int i = 0; i < 4; ++i) {
      int row = bm * BM + wrow + m * 16 + lg * 4 + i;
      float s1 = st1[row] + st1[4096 + row] + st1[8192 + row] + st1[12288 + row];
      float s2 = st2[row] + st2[4096 + row] + st2[8192 + row] + st2[12288 + row];
      float mu = s1 * (1.f / 512.f);
      float var = s2 * (1.f / 512.f) - mu * mu;
      mu_r[m][i] = mu;
      rs_r[m][i] = rsqrtf(var + 1e-5f);
    }
#pragma unroll
  for (int n = 0; n < 4; ++n) {
    int col = bn * 128 + wcol + n * 16 + lr;
    float bv = bias[col];
    float cs = colsum[col];
#pragma unroll
    for (int m = 0; m < MR; ++m)
#pragma unroll
      for (int i = 0; i < 4; ++i) {
        int row = bm * BM + wrow + m * 16 + lg * 4 + i;
        float v = rs_r[m][i] * (acc[m][n][i] - mu_r[m][i] * cs) + bv;
        C[(size_t)row * N + col] = f2bf(v);
      }
  }
}

// ============== dn-GEMM: X += HHb @ dnWT^T + bias; emits Xb bf16 + row-stats partials ======
// BM=64, NBN=4. Stats: per-block 128-col slice sums -> st1/st2[bn][row].
__global__ __launch_bounds__(256) void gemm_dn_kernel(
    const unsigned short* __restrict__ A, const unsigned short* __restrict__ BT,
    const float* __restrict__ bias, float* __restrict__ X,
    unsigned short* __restrict__ Xb, float* __restrict__ st1, float* __restrict__ st2,
    int nwg) {
  constexpr int BM = 64, NBN = 4, Kd = 1024, N = 512;
  constexpr int A_ISS = BM / 8, PER_W = (A_ISS + 16) / 4, MR = BM / 32;
  __shared__ __align__(16) char As[BM * 128];
  __shared__ __align__(16) char Bs[16384];
  __shared__ float sst[4][32][2];
  int tid = threadIdx.x, w = tid >> 6, l = tid & 63;
  int lr = l & 15, lg = l >> 4;
  int id = blockIdx.x;
  int q = nwg >> 3, r = nwg & 7;
  int xcd = id & 7, pos = id >> 3;
  int wg = (xcd < r ? xcd * (q + 1) : r * (q + 1) + (xcd - r) * q) + pos;
  int bn = wg % NBN, bm = wg / NBN;
  int wrow = (w >> 1) * (BM / 2), wcol = (w & 1) * 64;
  f32x4 acc[MR][4] = {};
  for (int kt = 0; kt < Kd; kt += 64) {
    __syncthreads();
#pragma unroll
    for (int j = 0; j < PER_W; ++j) {
      int g = w * PER_W + j;
      bool isA = g < A_ISS;
      int ii = isA ? g : g - A_ISS;
      int row = ii * 8 + (l >> 3);
      int chunk = (l & 7) ^ (row & 7);
      const unsigned short* src = isA
          ? A + ((size_t)(bm * BM + row) * Kd + kt) + chunk * 8
          : BT + ((size_t)(bn * 128 + row) * Kd + kt) + chunk * 8;
      char* dst = (isA ? As : Bs) + ii * 1024;
      gload16(src, dst);
    }
    __syncthreads();
#pragma unroll
    for (int kk = 0; kk < 2; ++kk) {
      bf16x8 af[MR], bfr[4];
#pragma unroll
      for (int m = 0; m < MR; ++m) {
        int row = wrow + m * 16 + lr;
        int ch = (kk * 4 + lg) ^ (row & 7);
        af[m] = *(const bf16x8*)(As + row * 128 + ch * 16);
      }
#pragma unroll
      for (int n = 0; n < 4; ++n) {
        int row = wcol + n * 16 + lr;
        int ch = (kk * 4 + lg) ^ (row & 7);
        bfr[n] = *(const bf16x8*)(Bs + row * 128 + ch * 16);
      }
      __builtin_amdgcn_s_setprio(1);
#pragma unroll
      for (int m = 0; m < MR; ++m)
#pragma unroll
        for (int n = 0; n < 4; ++n)
          acc[m][n] = MFMA_BF16(af[m], bfr[n], acc[m][n]);
      __builtin_amdgcn_s_setprio(0);
    }
  }
  float ps1[MR][4] = {}, ps2[MR][4] = {};
#pragma unroll
  for (int n = 0; n < 4; ++n) {
    int col = bn * 128 + wcol + n * 16 + lr;
    float bv = bias[col];
#pragma unroll
    for (int m = 0; m < MR; ++m)
#pragma unroll
      for (int i = 0; i < 4; ++i) {
        int row = bm * BM + wrow + m * 16 + lg * 4 + i;
        float v = acc[m][n][i] + bv + X[(size_t)row * N + col];
        X[(size_t)row * N + col] = v;
        Xb[(size_t)row * N + col] = f2bf(v);
        ps1[m][i] += v;
        ps2[m][i] += v * v;
      }
  }
#pragma unroll
  for (int m = 0; m < MR; ++m)
#pragma unroll
    for (int i = 0; i < 4; ++i) {
#pragma unroll
      for (int off = 1; off < 16; off <<= 1) {
        ps1[m][i] += __shfl_xor(ps1[m][i], off, 16);
        ps2[m][i] += __shfl_xor(ps2[m][i], off, 16);
      }
    }
  if (lr == 0) {
#pragma unroll
    for (int m = 0; m < MR; ++m)
#pragma unroll
      for (int i = 0; i < 4; ++i) {
        int lrow = m * 16 + lg * 4 + i;  // 0..31 within wave's row set
        sst[w][lrow][0] = ps1[m][i];
        sst[w][lrow][1] = ps2[m][i];
      }
  }
  __syncthreads();
  if (tid < 64) {
    int lrow = tid & 31, half = tid >> 5;
    int wA = half * 2, wB = half * 2 + 1;
    float s1 = sst[wA][lrow][0] + sst[wB][lrow][0];
    float s2 = sst[wA][lrow][1] + sst[wB][lrow][1];
    int grow = bm * BM + half * 32 + lrow;
    st1[(size_t)bn * 4096 + grow] = s1;
    st2[(size_t)bn * 4096 + grow] = s2;
  }
}

// ==== fused causal conv(K=4)+silu + headwise q,k,v; 4 consecutive s per block ====
__global__ __launch_bounds__(256) void convhead_kernel(
    const unsigned short* __restrict__ u, const float* __restrict__ cw,
    const float* __restrict__ cb,
    const float* __restrict__ Wq, const float* __restrict__ Wk, const float* __restrict__ Wv,
    unsigned short* __restrict__ xcb, unsigned short* __restrict__ qb,
    unsigned short* __restrict__ kb, unsigned short* __restrict__ vb) {
  int mb = blockIdx.x;
  int b = mb >> 7, sq = (mb & 127) * 4;
  int n = threadIdx.x;  // channels n*4 .. n*4+3
  float xm[7][4];
#pragma unroll
  for (int j = 0; j < 7; ++j) {
    int sp = sq - 3 + j;
    if (sp >= 0) {
      unsigned long long raw = *(const unsigned long long*)&u[((size_t)(b * kS + sp)) * (2 * kI) + n * 4];
#pragma unroll
      for (int i = 0; i < 4; ++i) xm[j][i] = bf2f((unsigned short)(raw >> (i * 16)));
    } else {
#pragma unroll
      for (int i = 0; i < 4; ++i) xm[j][i] = 0.f;
    }
  }
  float4 cb4 = *(const float4*)&cb[n * 4];
  const float* cbp = &cb4.x;
  float cwv[4][4];
#pragma unroll
  for (int i = 0; i < 4; ++i) *(float4*)cwv[i] = *(const float4*)&cw[(n * 4 + i) * 4];
  float wqv[16], wkv[16], wvv[16];
#pragma unroll
  for (int o2 = 0; o2 < 4; ++o2) {
    *(float4*)&wqv[o2 * 4] = *(const float4*)&Wq[n * 16 + o2 * 4];
    *(float4*)&wkv[o2 * 4] = *(const float4*)&Wk[n * 16 + o2 * 4];
    *(float4*)&wvv[o2 * 4] = *(const float4*)&Wv[n * 16 + o2 * 4];
  }
#pragma unroll
  for (int t = 0; t < 4; ++t) {
    int s = sq + t;
    float xc[4];
    unsigned long long xcv = 0;
#pragma unroll
    for (int i = 0; i < 4; ++i) {
      float acc = cbp[i] + xm[t][i] * cwv[i][0] + xm[t + 1][i] * cwv[i][1] +
                  xm[t + 2][i] * cwv[i][2] + xm[t + 3][i] * cwv[i][3];
      xc[i] = acc / (1.f + __expf(-acc));
      xcv |= (unsigned long long)f2bf(xc[i]) << (i * 16);
    }
    *(unsigned long long*)&xcb[((size_t)(b * kS + s)) * kI + n * 4] = xcv;
    unsigned long long qv = 0, kv = 0, vv = 0;
#pragma unroll
    for (int o = 0; o < 4; ++o) {
      float aq = 0, ak = 0, av = 0;
#pragma unroll
      for (int i = 0; i < 4; ++i) {
        aq += xc[i] * wqv[o * 4 + i];
        ak += xc[i] * wkv[o * 4 + i];
        av += xm[t + 3][i] * wvv[o * 4 + i];
      }
      qv |= (unsigned long long)f2bf(aq) << (o * 16);
      kv |= (unsigned long long)f2bf(ak) << (o * 16);
      vv |= (unsigned long long)f2bf(av) << (o * 16);
    }
    size_t base = ((size_t)(b * 8 + (n >> 5)) * kS + s) * kDH + (n & 31) * 4;
    *(unsigned long long*)&qb[base] = qv;
    *(unsigned long long*)&kb[base] = kv;
    *(unsigned long long*)&vb[base] = vv;
  }
}

// ============ merged prep: gates MFMA (blocks 0..191) + V transpose (blocks 192..703) ====
__global__ __launch_bounds__(256) void prep_kernel(
    const unsigned short* __restrict__ qb, const unsigned short* __restrict__ kb,
    const unsigned short* __restrict__ vb, const unsigned short* __restrict__ gWT,
    float* __restrict__ IGp, float* __restrict__ FGp, unsigned short* __restrict__ vt) {
  __shared__ __align__(16) char smem[16640];
  int id = blockIdx.x;
  int tid = threadIdx.x;
  if (id < 192) {
    int src = id >> 6;
    int blk = id & 63;
    int b = blk >> 3, s0 = (blk & 7) * 64;
    int w = tid >> 6, l = tid & 63;
    int lr = l & 15, lg = l >> 4;
    char* Ts = smem;
    const unsigned short* srcb = (src == 0) ? qb : (src == 1) ? kb : vb;
    f32x4 acc = {};
    for (int kc8 = 0; kc8 < 8; ++kc8) {
      const unsigned short* srcbase = srcb + ((size_t)(b * 8 + kc8) * kS + s0) * kDH;
      __syncthreads();
#pragma unroll
      for (int j = 0; j < 4; ++j) {
        int issue = w * 4 + j;
        int row = issue * 4 + (l >> 4);
        int chunk = (l & 15) ^ (row & 7);
        gload16(srcbase + row * 128 + chunk * 8, Ts + issue * 1024);
      }
      __syncthreads();
#pragma unroll
      for (int kk = 0; kk < 4; ++kk) {
        int arow = w * 16 + lr;
        int ch = (kk * 4 + lg) ^ (arow & 7);
        bf16x8 af = *(const bf16x8*)(Ts + arow * 256 + ch * 16);
        bf16x8 bfv = *(const bf16x8*)(gWT + (size_t)lr * 3072 + (src * 8 + kc8) * 128 + kk * 32 + lg * 8);
        acc = MFMA_BF16(af, bfv, acc);
      }
    }
    float* IGo = IGp + (size_t)src * 64 * kS;
    float* FGo = FGp + (size_t)src * 64 * kS;
#pragma unroll
    for (int i = 0; i < 4; ++i) {
      int s = s0 + w * 16 + lg * 4 + i;
      if (lr < 8) IGo[((size_t)(b * 8) + lr) * kS + s] = acc[i];
      else FGo[((size_t)(b * 8) + lr - 8) * kS + s] = acc[i];
    }
  } else {
    int t = id - 192;
    int bh = t >> 3, s0 = (t & 7) * 64;
    unsigned short (*tt)[130] = (unsigned short(*)[130])smem;
    for (int idx = tid; idx < 64 * 128; idx += 256) {
      int sl = idx >> 7, d = idx & 127;
      tt[sl][d] = vb[((size_t)bh * kS + s0 + sl) * kDH + d];
    }
    __syncthreads();
    for (int idx = tid; idx < 64 * 128; idx += 256) {
      int dl = idx >> 6, sl = idx & 63;
      vt[((size_t)bh * kDH + dl) * kS + s0 + sl] = tt[sl][dl];
    }
  }
}

// ======================= mLSTM parallel via MFMA, fused scan + mh_norm/skip/gate ==========
__global__ __launch_bounds__(512) void mlstm_mfma_kernel(
    const unsigned short* __restrict__ qb, const unsigned short* __restrict__ kb,
    const unsigned short* __restrict__ vt,
    const float* __restrict__ IGp, const float* __restrict__ FGp,
    const float* __restrict__ igb, const float* __restrict__ fgb,
    const unsigned short* __restrict__ u, const unsigned short* __restrict__ xcb,
    const float* __restrict__ onw, const float* __restrict__ skw,
    unsigned short* __restrict__ hhb) {
  int id = blockIdx.x;
  int bh = (id & 7) * 8 + ((id >> 3) & 7);  // each XCD sees only 8 heads
  int pr = id >> 6;                          // 0..3
  int rtA = 7 - pr, rtB = pr;
  int b = bh >> 3, nh = bh & 7;
  int tid = threadIdx.x, w = tid >> 6, l = tid & 63;
  int g = w >> 2, wl = w & 3;
  int rt = (g == 0) ? rtA : rtB;
  int lr = l & 15, lg = l >> 4;
  __shared__ __align__(16) char Ks[2][16384];  // [64 s][128 d] bf16, RB=256
  __shared__ __align__(16) char Vs[2][16384];  // [128 d][64 s] bf16, RB=128
  __shared__ __align__(16) char Ps[8][2048];   // per-wave [16][64] bf16, RB=128
  __shared__ float avs[512], incs[512], pms[512];
  __shared__ float wsum[8], wmax[8];

  const unsigned short* kbh = kb + (size_t)bh * kS * kDH;
  const unsigned short* vbh = vt + (size_t)bh * kDH * kS;

  // prologue: stage tile 0 into buffer 0 (all 8 waves: 2 K-issues + 2 V-issues each)
#pragma unroll
  for (int j = 0; j < 2; ++j) {
    int issue = w * 2 + j;
    int row = issue * 4 + (l >> 4);
    int chunk = (l & 15) ^ (row & 7);
    gload16(kbh + row * 128 + chunk * 8, Ks[0] + issue * 1024);
  }
#pragma unroll
  for (int j = 0; j < 2; ++j) {
    int vi = w * 2 + j;
    int row = vi * 8 + (l >> 3);
    int chunk = (l & 7) ^ (row & 7);
    gload16(vbh + (size_t)row * kS + chunk * 8, Vs[0] + vi * 1024);
  }

  // ---- in-block scan for this head (hidden under tile-0 DMA) ----
  {
    int lane = tid & 63, wid2 = tid >> 6;
    const size_t ss = (size_t)64 * kS;
    size_t o = (size_t)bh * kS + tid;
    float igv = IGp[o] + IGp[ss + o] + IGp[2 * ss + o] + igb[nh];
    float fgv = FGp[o] + FGp[ss + o] + FGp[2 * ss + o] + fgb[nh];
    float lf = fminf(fgv, 0.f) - log1pf(__expf(-fabsf(fgv)));
    float x = lf;
#pragma unroll
    for (int off = 1; off < 64; off <<= 1) {
      float v = __shfl_up(x, off, 64);
      if (lane >= off) x += v;
    }
    if (lane == 63) wsum[wid2] = x;
    __syncthreads();
    float base = 0.f;
    for (int i2 = 0; i2 < wid2; ++i2) base += wsum[i2];
    float inct = x + base;
    incs[tid] = inct;
    float av = igv - inct;
    avs[tid] = 0.08838834764831845f * __expf(av);
    float y = av;
#pragma unroll
    for (int off = 1; off < 64; off <<= 1) {
      float v = __shfl_up(y, off, 64);
      if (lane >= off) y = fmaxf(y, v);
    }
    if (lane == 63) wmax[wid2] = y;
    __syncthreads();
    float mb2 = y;
    for (int i2 = 0; i2 < wid2; ++i2) mb2 = fmaxf(mb2, wmax[i2]);
    pms[tid] = mb2;
  }

  bf16x8 qf[4];
  int qrow = rt * 64 + wl * 16 + lr;
  const unsigned short* qrp = qb + ((size_t)bh * kS + qrow) * kDH + lg * 8;
#pragma unroll
  for (int kk = 0; kk < 4; ++kk) qf[kk] = *(const bf16x8*)(qrp + kk * 32);

  __syncthreads();  // scan results + tile-0 staging visible

  float pm_r[4], epm[4];
#pragma unroll
  for (int i = 0; i < 4; ++i) {
    pm_r[i] = pms[rt * 64 + wl * 16 + lg * 4 + i];
    epm[i] = __expf(-pm_r[i]);
  }

  f32x4 oacc[8] = {};
  float rsum[4] = {};

  int cur = 0;
#pragma unroll 1
  for (int ct = 0; ct <= rtA; ++ct) {
    if (ct < rtA) {
      const unsigned short* kbase = kbh + (size_t)(ct + 1) * 64 * kDH;
      const unsigned short* vbase = vbh + (size_t)(ct + 1) * 64;
#pragma unroll
      for (int j = 0; j < 2; ++j) {
        int issue = w * 2 + j;
        int row = issue * 4 + (l >> 4);
        int chunk = (l & 15) ^ (row & 7);
        gload16(kbase + row * 128 + chunk * 8, Ks[cur ^ 1] + issue * 1024);
      }
#pragma unroll
      for (int j = 0; j < 2; ++j) {
        int vi = w * 2 + j;
        int row = vi * 8 + (l >> 3);
        int chunk = (l & 7) ^ (row & 7);
        gload16(vbase + (size_t)row * kS + chunk * 8, Vs[cur ^ 1] + vi * 1024);
      }
    }
    if (ct <= rt) {
      // QK^T
      f32x4 sacc[4] = {};
      __builtin_amdgcn_s_setprio(1);
#pragma unroll
      for (int n = 0; n < 4; ++n) {
#pragma unroll
        for (int kk = 0; kk < 4; ++kk) {
          int krow = n * 16 + lr;
          int ch = (kk * 4 + lg) ^ (krow & 7);
          bf16x8 kf = *(const bf16x8*)(Ks[cur] + krow * 256 + ch * 16);
          sacc[n] = MFMA_BF16(qf[kk], kf, sacc[n]);
        }
      }
      __builtin_amdgcn_s_setprio(0);
      // transform scores -> P (bf16 in per-wave LDS), accumulate row sums
#pragma unroll
      for (int n = 0; n < 4; ++n) {
        float eav = avs[ct * 64 + n * 16 + lr];
        int cg = ct * 64 + n * 16 + lr;
#pragma unroll
        for (int i = 0; i < 4; ++i) {
          int rg = rt * 64 + wl * 16 + lg * 4 + i;
          float s = 0.f;
          if (ct < rt || cg <= rg)
            s = sacc[n][i] * (eav * epm[i]);
          rsum[i] += s;
          int prow = lg * 4 + i, pcol = n * 16 + lr;
          int byte = prow * 128 + ((((pcol >> 3) ^ (prow & 7))) << 4) + (pcol & 7) * 2;
          *(unsigned short*)(Ps[w] + byte) = f2bf(s);
        }
      }
      // PV
      __builtin_amdgcn_s_setprio(1);
#pragma unroll
      for (int kk = 0; kk < 2; ++kk) {
        int prow = lr;
        int pch = (kk * 4 + lg) ^ (prow & 7);
        bf16x8 pf = *(const bf16x8*)(Ps[w] + prow * 128 + pch * 16);
#pragma unroll
        for (int nb = 0; nb < 8; ++nb) {
          int vrow = nb * 16 + lr;
          int vch = (kk * 4 + lg) ^ (vrow & 7);
          bf16x8 vf = *(const bf16x8*)(Vs[cur] + vrow * 128 + vch * 16);
          oacc[nb] = MFMA_BF16(pf, vf, oacc[nb]);
        }
      }
      __builtin_amdgcn_s_setprio(0);
    }
    __syncthreads();  // drains staging DMA + protects buffer swap
    cur ^= 1;
  }

#pragma unroll
  for (int i = 0; i < 4; ++i)
#pragma unroll
    for (int off = 1; off < 16; off <<= 1) rsum[i] += __shfl_xor(rsum[i], off, 16);
  float ninv[4];
#pragma unroll
  for (int i = 0; i < 4; ++i) {
    int rg = rt * 64 + wl * 16 + lg * 4 + i;
    float e0 = __expf(-incs[rg] - pm_r[i]);
    float nn = fmaxf(fabsf(rsum[i]), e0);
    ninv[i] = 1.f / (nn + 1e-6f);
  }
  // ---- fused mh_norm (LN over DH=128 within 16-lane groups) + skip + output gate ----
  float val[8][4];
  float s1[4] = {}, s2[4] = {};
#pragma unroll
  for (int nb = 0; nb < 8; ++nb)
#pragma unroll
    for (int i = 0; i < 4; ++i) {
      float v = oacc[nb][i] * ninv[i];
      val[nb][i] = v;
      s1[i] += v; s2[i] += v * v;
    }
#pragma unroll
  for (int i = 0; i < 4; ++i) {
#pragma unroll
    for (int off = 1; off < 16; off <<= 1) {
      s1[i] += __shfl_xor(s1[i], off, 16);
      s2[i] += __shfl_xor(s2[i], off, 16);
    }
  }
#pragma unroll
  for (int i = 0; i < 4; ++i) {
    int rg = rt * 64 + wl * 16 + lg * 4 + i;
    float mu = s1[i] * (1.f / 128.f);
    float var = s2[i] * (1.f / 128.f) - mu * mu;
    float rstd = rsqrtf(var + 1e-5f);
    size_t rowbase = (size_t)(b * kS + rg);
#pragma unroll
    for (int nb = 0; nb < 8; ++nb) {
      int c = nh * kDH + nb * 16 + lr;
      float nv = (val[nb][i] - mu) * rstd * onw[c];
      float z = bf2f(u[rowbase * (2 * kI) + kI + c]);
      float sz = z / (1.f + __expf(-z));
      float xcv = bf2f(xcb[rowbase * kI + c]);
      hhb[rowbase * kI + c] = f2bf((nv + skw[c] * xcv) * sz);
    }
  }
}

// ======================= post-norm + head projection (last 96 rows/batch) =======================
__global__ __launch_bounds__(256) void head_kernel(
    const float* __restrict__ x, const float* __restrict__ pw,
    const float* __restrict__ hW, const float* __restrict__ hb, float* __restrict__ out) {
  int row = blockIdx.x;  // 0..767
  int b = row / kPRED, p = row % kPRED;
  int m = b * kS + (kS - kPRED) + p;
  int tid = threadIdx.x;
  float v0 = x[(size_t)m * kD + tid];
  float v1 = x[(size_t)m * kD + 256 + tid];
  float s1 = v0 + v1, s2 = v0 * v0 + v1 * v1;
#pragma unroll
  for (int o = 1; o < 64; o <<= 1) { s1 += __shfl_xor(s1, o, 64); s2 += __shfl_xor(s2, o, 64); }
  __shared__ float a1[4], a2[4];
  if ((tid & 63) == 0) { a1[tid >> 6] = s1; a2[tid >> 6] = s2; }
  __syncthreads();
  float t1 = a1[0] + a1[1] + a1[2] + a1[3];
  float t2 = a2[0] + a2[1] + a2[2] + a2[3];
  float mu = t1 * (1.f / kD);
  float var = t2 * (1.f / kD) - mu * mu;
  float rs = rsqrtf(var + 1e-5f);
  __shared__ float buf[512];
  buf[tid] = (v0 - mu) * rs * pw[tid];
  buf[256 + tid] = (v1 - mu) * rs * pw[256 + tid];
  __syncthreads();
  float acc[7] = {};
  for (int kk = tid; kk < 512; kk += 256) {
    float g = buf[kk];
#pragma unroll
    for (int n = 0; n < 7; ++n) acc[n] += g * hW[kk * 7 + n];
  }
  __shared__ float red[256 * 9];
#pragma unroll
  for (int n = 0; n < 7; ++n) red[tid * 9 + n] = acc[n];
  __syncthreads();
  for (int off = 128; off >= 1; off >>= 1) {
    if (tid < off) {
#pragma unroll
      for (int n = 0; n < 7; ++n) red[tid * 9 + n] += red[(tid + off) * 9 + n];
    }
    __syncthreads();
  }
  if (tid < 7) out[(size_t)row * 7 + tid] = red[tid] + hb[tid];
}

// ======================= host launch =======================
extern "C" void kernel_launch(void* const* d_in, const int* in_sizes, int n_in,
                              void* d_out, int out_size, void* d_ws, size_t ws_size,
                              hipStream_t stream) {
  const float* x_enc    = (const float*)d_in[0];
  const float* x_mark   = (const float*)d_in[1];
  const float* emb_W    = (const float*)d_in[4];
  const float* emb_b    = (const float*)d_in[5];
  const float* blk_ln_w = (const float*)d_in[6];
  const float* up_W     = (const float*)d_in[7];
  const float* up_b     = (const float*)d_in[8];
  const float* conv_w   = (const float*)d_in[9];
  const float* conv_b   = (const float*)d_in[10];
  const float* Wq       = (const float*)d_in[11];
  const float* Wk       = (const float*)d_in[12];
  const float* Wv       = (const float*)d_in[13];
  const float* ig_W     = (const float*)d_in[14];
  const float* ig_b     = (const float*)d_in[15];
  const float* fg_W     = (const float*)d_in[16];
  const float* fg_b     = (const float*)d_in[17];
  const float* onorm_w  = (const float*)d_in[18];
  const float* skip_w   = (const float*)d_in[19];
  const float* down_W   = (const float*)d_in[20];
  const float* down_b   = (const float*)d_in[21];
  const float* post_w   = (const float*)d_in[22];
  const float* head_W   = (const float*)d_in[23];
  const float* head_b   = (const float*)d_in[24];
  float* out = (float*)d_out;

  char* ws = (char*)d_ws;
  float* X  = (float*)ws;                     ws += (size_t)kM * kD * 4;        // 8 MB
  unsigned short* Xb   = (unsigned short*)ws; ws += (size_t)kM * kD * 2;        // 4 MB
  unsigned short* U    = (unsigned short*)ws; ws += (size_t)kM * 2 * kI * 2;    // 16 MB
  unsigned short* XCb  = (unsigned short*)ws; ws += (size_t)kM * kI * 2;        // 8 MB
  unsigned short* HHb  = (unsigned short*)ws; ws += (size_t)kM * kI * 2;        // 8 MB
  unsigned short* qb   = (unsigned short*)ws; ws += (size_t)kM * kI * 2;        // 8 MB
  unsigned short* kbuf = (unsigned short*)ws; ws += (size_t)kM * kI * 2;        // 8 MB
  unsigned short* vb   = (unsigned short*)ws; ws += (size_t)kM * kI * 2;        // 8 MB
  unsigned short* vt   = (unsigned short*)ws; ws += (size_t)kM * kI * 2;        // 8 MB
  unsigned short* upWT = (unsigned short*)ws; ws += (size_t)kL * 2 * kI * kD * 2; // 8 MB
  unsigned short* dnWT = (unsigned short*)ws; ws += (size_t)kL * kD * kI * 2;   // 4 MB
  unsigned short* gWT  = (unsigned short*)ws; ws += (size_t)kL * 16 * 3072 * 2; // 384 KB
  float* IGp = (float*)ws; ws += (size_t)3 * 64 * kS * 4;
  float* FGp = (float*)ws; ws += (size_t)3 * 64 * kS * 4;
  float* ST1 = (float*)ws; ws += (size_t)4 * kM * 4;                            // 64 KB
  float* ST2 = (float*)ws; ws += (size_t)4 * kM * 4;                            // 64 KB
  float* CSUM = (float*)ws; ws += (size_t)kL * 2 * kI * 4;                      // 32 KB

  init_kernel<<<5712, 256, 0, stream>>>(
      x_enc, x_mark, emb_W, emb_b, blk_ln_w, up_W, down_W, ig_W, fg_W,
      X, Xb, ST1, ST2, upWT, dnWT, gWT, CSUM);

  for (int l = 0; l < kL; ++l) {
    const float* upbl = up_b + (size_t)l * 2 * kI;
    const float* cwl  = conv_w + (size_t)l * kI * 4;
    const float* cbl  = conv_b + (size_t)l * kI;
    const float* wql  = Wq + (size_t)l * 256 * 16;
    const float* wkl  = Wk + (size_t)l * 256 * 16;
    const float* wvl  = Wv + (size_t)l * 256 * 16;
    const float* igbl = ig_b + (size_t)l * kNH;
    const float* fgbl = fg_b + (size_t)l * kNH;
    const float* onwl = onorm_w + (size_t)l * kI;
    const float* skwl = skip_w + (size_t)l * kI;
    const float* dbl  = down_b + (size_t)l * kD;
    const unsigned short* upWTl = upWT + (size_t)l * 2 * kI * kD;
    const unsigned short* dnWTl = dnWT + (size_t)l * kD * kI;
    const unsigned short* gWTl  = gWT + (size_t)l * 16 * 3072;
    const float* csuml = CSUM + (size_t)l * 2 * kI;

    gemm_up_kernel<<<512, 256, 0, stream>>>(Xb, upWTl, upbl, csuml, ST1, ST2, U, 512);
    convhead_kernel<<<1024, 256, 0, stream>>>(U, cwl, cbl, wql, wkl, wvl, XCb, qb, kbuf, vb);
    prep_kernel<<<704, 256, 0, stream>>>(qb, kbuf, vb, gWTl, IGp, FGp, vt);
    mlstm_mfma_kernel<<<256, 512, 0, stream>>>(
        qb, kbuf, vt, IGp, FGp, igbl, fgbl, U, XCb, onwl, skwl, HHb);
    gemm_dn_kernel<<<256, 256, 0, stream>>>(HHb, dnWTl, dbl, X, Xb, ST1, ST2, 256);
  }

  head_kernel<<<kB * kPRED, 256, 0, stream>>>(X, post_w, head_W, head_b, out);
}